// Round 1
// baseline (2335.111 us; speedup 1.0000x reference)
//
#include <hip/hip_runtime.h>
#include <math.h>

#define N_TOK   2048      // B*T
#define SEQ     1024
#define DIMM    1024
#define NH      16
#define NKV     4
#define HD      64
#define HID     2048
#define NEXP    8

// ---------------------------------------------------------------- rmsnorm
__global__ __launch_bounds__(256) void rmsnorm_kernel(const float* __restrict__ x,
    const float* __restrict__ w, float* __restrict__ out)
{
    int row = blockIdx.x;
    const float4* xr = reinterpret_cast<const float4*>(x + (size_t)row * DIMM);
    const float4* wr = reinterpret_cast<const float4*>(w);
    float4 v = xr[threadIdx.x];
    float ss = v.x*v.x + v.y*v.y + v.z*v.z + v.w*v.w;
#pragma unroll
    for (int off = 32; off; off >>= 1) ss += __shfl_xor(ss, off);
    __shared__ float red[4];
    int wid = threadIdx.x >> 6, lane = threadIdx.x & 63;
    if (lane == 0) red[wid] = ss;
    __syncthreads();
    float tot = red[0] + red[1] + red[2] + red[3];
    float inv = rsqrtf(tot * (1.0f/DIMM) + 1e-6f);
    float4 ww = wr[threadIdx.x];
    float4 o;
    o.x = ww.x * v.x * inv;
    o.y = ww.y * v.y * inv;
    o.z = ww.z * v.z * inv;
    o.w = ww.w * v.w * inv;
    reinterpret_cast<float4*>(out + (size_t)row * DIMM)[threadIdx.x] = o;
}

// ---------------------------------------------------------------- generic GEMM  C[M,N] = A[M,K] @ B[N,K]^T (+R)
__global__ __launch_bounds__(256) void gemm_nt(const float* __restrict__ A,
    const float* __restrict__ B, float* __restrict__ C, const float* __restrict__ R,
    int M, int N, int K, int ldc)
{
    __shared__ float As[64][20];
    __shared__ float Bs[64][20];
    int tid = threadIdx.x;
    int tx = tid & 15, ty = tid >> 4;
    int m0 = blockIdx.y * 64, n0 = blockIdx.x * 64;
    float acc[4][4] = {};
    for (int k0 = 0; k0 < K; k0 += 16) {
#pragma unroll
        for (int i = 0; i < 4; i++) {
            int idx = tid + i * 256;
            int r = idx >> 4, c = idx & 15;
            As[r][c] = A[(size_t)(m0 + r) * K + k0 + c];
            Bs[r][c] = B[(size_t)(n0 + r) * K + k0 + c];
        }
        __syncthreads();
#pragma unroll
        for (int kk = 0; kk < 16; kk++) {
            float a[4], b[4];
#pragma unroll
            for (int i = 0; i < 4; i++) a[i] = As[ty + i * 16][kk];
#pragma unroll
            for (int j = 0; j < 4; j++) b[j] = Bs[tx + j * 16][kk];
#pragma unroll
            for (int i = 0; i < 4; i++)
#pragma unroll
                for (int j = 0; j < 4; j++) acc[i][j] += a[i] * b[j];
        }
        __syncthreads();
    }
#pragma unroll
    for (int i = 0; i < 4; i++) {
        int m = m0 + ty + i * 16;
#pragma unroll
        for (int j = 0; j < 4; j++) {
            int n = n0 + tx + j * 16;
            float vv = acc[i][j];
            if (R) vv += R[(size_t)m * ldc + n];
            C[(size_t)m * ldc + n] = vv;
        }
    }
}

// ---------------------------------------------------------------- RoPE (in place)
__global__ __launch_bounds__(256) void rope_kernel(float* __restrict__ buf,
    const float* __restrict__ cs, const float* __restrict__ sn, int nheads)
{
    int gid = blockIdx.x * 256 + threadIdx.x;
    int total = N_TOK * nheads * 32;
    if (gid >= total) return;
    int i = gid & 31;
    int h = (gid >> 5) % nheads;
    int n = gid / (32 * nheads);
    int t = n & (SEQ - 1);
    float* p = buf + (size_t)n * (nheads * HD) + h * HD + 2 * i;
    float xe = p[0], xo = p[1];
    float c = cs[t * 32 + i], s = sn[t * 32 + i];
    p[0] = xe * c - xo * s;
    p[1] = xe * s + xo * c;
}

// ---------------------------------------------------------------- attention (flash-style, thread = one q row)
__global__ __launch_bounds__(256) void attn_fwd(const float* __restrict__ q,
    const float* __restrict__ k, const float* __restrict__ v, float* __restrict__ out)
{
    int b = blockIdx.z, h = blockIdx.y;
    int r = blockIdx.x * 256 + threadIdx.x;   // query row within sequence
    int kvh = h >> 2;
    __shared__ float Ks[64 * 64];
    __shared__ float Vs[64 * 64];
    const float* qp = q + ((size_t)(b * SEQ + r)) * (NH * HD) + h * HD;
    float qreg[64];
#pragma unroll
    for (int d4 = 0; d4 < 16; d4++) {
        float4 t = reinterpret_cast<const float4*>(qp)[d4];
        qreg[d4*4+0] = t.x; qreg[d4*4+1] = t.y; qreg[d4*4+2] = t.z; qreg[d4*4+3] = t.w;
    }
    float o[64];
#pragma unroll
    for (int d = 0; d < 64; d++) o[d] = 0.f;
    float m = -INFINITY, l = 0.f;
    int ntiles = (blockIdx.x * 256 + 256) >> 6;
    for (int kt = 0; kt < ntiles; kt++) {
        int kbase = kt << 6;
        __syncthreads();
        for (int idx = threadIdx.x; idx < 4096; idx += 256) {
            int kk = idx >> 6, d = idx & 63;
            size_t g = ((size_t)(b * SEQ + kbase + kk)) * (NKV * HD) + kvh * HD + d;
            Ks[idx] = k[g];
            Vs[idx] = v[g];
        }
        __syncthreads();
        int rem = r - kbase + 1;
        int kmax = rem > 64 ? 64 : rem;
        for (int kk = 0; kk < kmax; kk++) {
            const float* kr = &Ks[kk << 6];
            float s = 0.f;
#pragma unroll
            for (int d = 0; d < 64; d++) s += qreg[d] * kr[d];
            s *= 0.125f;
            float p;
            if (s > m) {
                float c = __expf(m - s);
                l *= c;
#pragma unroll
                for (int d = 0; d < 64; d++) o[d] *= c;
                m = s;
                p = 1.f;
            } else {
                p = __expf(s - m);
            }
            l += p;
            const float* vr = &Vs[kk << 6];
#pragma unroll
            for (int d = 0; d < 64; d++) o[d] += p * vr[d];
        }
    }
    float inv = 1.f / l;
    float* op = out + ((size_t)(b * SEQ + r)) * (NH * HD) + h * HD;
#pragma unroll
    for (int d4 = 0; d4 < 16; d4++) {
        float4 t;
        t.x = o[d4*4+0] * inv; t.y = o[d4*4+1] * inv;
        t.z = o[d4*4+2] * inv; t.w = o[d4*4+3] * inv;
        reinterpret_cast<float4*>(op)[d4] = t;
    }
}

// ---------------------------------------------------------------- routing
__global__ void init_counts(int* counts, int* pos)
{
    int t = threadIdx.x;
    if (t < NEXP) { counts[t] = 0; pos[t] = 0; }
}

__global__ __launch_bounds__(256) void router_kernel(const float* __restrict__ xn2,
    const float* __restrict__ rw, const float* __restrict__ rb,
    int* __restrict__ top_idx, float* __restrict__ top_w, int* __restrict__ counts)
{
    int wid = threadIdx.x >> 6, lane = threadIdx.x & 63;
    int n = blockIdx.x * 4 + wid;
    if (n >= N_TOK) return;
    const float* xr = xn2 + (size_t)n * DIMM;
    float lg[NEXP];
#pragma unroll
    for (int e = 0; e < NEXP; e++) {
        float p = 0.f;
        for (int d = lane; d < DIMM; d += 64) p += xr[d] * rw[e * DIMM + d];
#pragma unroll
        for (int off = 32; off; off >>= 1) p += __shfl_xor(p, off);
        lg[e] = p + rb[e];
    }
    if (lane == 0) {
        float m = lg[0];
#pragma unroll
        for (int e = 1; e < NEXP; e++) m = fmaxf(m, lg[e]);
        float pe[NEXP], s = 0.f;
#pragma unroll
        for (int e = 0; e < NEXP; e++) { pe[e] = __expf(lg[e] - m); s += pe[e]; }
        int i1 = 0; float v1 = pe[0];
#pragma unroll
        for (int e = 1; e < NEXP; e++) if (pe[e] > v1) { v1 = pe[e]; i1 = e; }
        int i2 = -1; float v2 = -1.f;
#pragma unroll
        for (int e = 0; e < NEXP; e++) if (e != i1 && pe[e] > v2) { v2 = pe[e]; i2 = e; }
        v1 /= s; v2 /= s;
        float den = v1 + v2 + 1e-9f;
        top_idx[2 * n] = i1; top_idx[2 * n + 1] = i2;
        top_w[2 * n] = v1 / den; top_w[2 * n + 1] = v2 / den;
        atomicAdd(&counts[i1], 1);
        atomicAdd(&counts[i2], 1);
    }
}

__global__ void offsets_kernel(const int* counts, int* offs)
{
    if (threadIdx.x == 0) {
        int s = 0;
        for (int e = 0; e < NEXP; e++) { offs[e] = s; s += counts[e]; }
    }
}

__global__ __launch_bounds__(256) void fill_kernel(const int* __restrict__ top_idx,
    const float* __restrict__ top_w, const int* __restrict__ offs, int* __restrict__ pos,
    int* __restrict__ assign_token, float* __restrict__ assign_w)
{
    int n = blockIdx.x * 256 + threadIdx.x;
    if (n >= N_TOK) return;
#pragma unroll
    for (int s = 0; s < 2; s++) {
        int e = top_idx[2 * n + s];
        int p = atomicAdd(&pos[e], 1);
        int r = offs[e] + p;
        assign_token[r] = n;
        assign_w[r] = top_w[2 * n + s];
    }
}

// ---------------------------------------------------------------- MoE gate/up (gathered GEMM + silu*up)
__global__ __launch_bounds__(256) void moe_gateup(const float* __restrict__ xn2,
    const float* __restrict__ wg, const float* __restrict__ wu,
    const int* __restrict__ assign_token, const int* __restrict__ offs,
    const int* __restrict__ counts, float* __restrict__ hbuf)
{
    int e = blockIdx.z;
    int cnt = counts[e];
    int t0 = blockIdx.y * 64;
    if (t0 >= cnt) return;
    int base = offs[e];
    int h0 = blockIdx.x * 64;
    __shared__ float As[64][20], Gs[64][20], Us[64][20];
    __shared__ int toks[64];
    int tid = threadIdx.x;
    if (tid < 64) {
        int a = t0 + tid;
        toks[tid] = (a < cnt) ? assign_token[base + a] : -1;
    }
    __syncthreads();
    int tx = tid & 15, ty = tid >> 4;
    float accg[4][4] = {}, accu[4][4] = {};
    const float* wge = wg + (size_t)e * HID * DIMM;
    const float* wue = wu + (size_t)e * HID * DIMM;
    for (int k0 = 0; k0 < DIMM; k0 += 16) {
#pragma unroll
        for (int i = 0; i < 4; i++) {
            int idx = tid + i * 256;
            int r = idx >> 4, c = idx & 15;
            int tok = toks[r];
            As[r][c] = (tok >= 0) ? xn2[(size_t)tok * DIMM + k0 + c] : 0.f;
            Gs[r][c] = wge[(size_t)(h0 + r) * DIMM + k0 + c];
            Us[r][c] = wue[(size_t)(h0 + r) * DIMM + k0 + c];
        }
        __syncthreads();
#pragma unroll
        for (int kk = 0; kk < 16; kk++) {
            float a[4], g[4], u[4];
#pragma unroll
            for (int i = 0; i < 4; i++) a[i] = As[ty + i * 16][kk];
#pragma unroll
            for (int j = 0; j < 4; j++) { g[j] = Gs[tx + j * 16][kk]; u[j] = Us[tx + j * 16][kk]; }
#pragma unroll
            for (int i = 0; i < 4; i++)
#pragma unroll
                for (int j = 0; j < 4; j++) {
                    accg[i][j] += a[i] * g[j];
                    accu[i][j] += a[i] * u[j];
                }
        }
        __syncthreads();
    }
#pragma unroll
    for (int i = 0; i < 4; i++) {
        int row = ty + i * 16;
        if (t0 + row < cnt) {
#pragma unroll
            for (int j = 0; j < 4; j++) {
                int col = tx + j * 16;
                float g = accg[i][j], u = accu[i][j];
                float hh = (g / (1.f + __expf(-g))) * u;
                hbuf[(size_t)(base + t0 + row) * HID + h0 + col] = hh;
            }
        }
    }
}

// ---------------------------------------------------------------- MoE down proj + weighted scatter-add
__global__ __launch_bounds__(256) void moe_down(const float* __restrict__ hbuf,
    const float* __restrict__ wd, const int* __restrict__ assign_token,
    const float* __restrict__ assign_w, const int* __restrict__ offs,
    const int* __restrict__ counts, float* __restrict__ out)
{
    int e = blockIdx.z;
    int cnt = counts[e];
    int t0 = blockIdx.y * 64;
    if (t0 >= cnt) return;
    int base = offs[e];
    int d0 = blockIdx.x * 64;
    __shared__ float As[64][20], Bs[64][20];
    __shared__ int toks[64];
    __shared__ float rw_[64];
    int tid = threadIdx.x;
    if (tid < 64) {
        int a = t0 + tid;
        toks[tid] = (a < cnt) ? assign_token[base + a] : -1;
        rw_[tid] = (a < cnt) ? assign_w[base + a] : 0.f;
    }
    __syncthreads();
    int tx = tid & 15, ty = tid >> 4;
    float acc[4][4] = {};
    const float* wde = wd + (size_t)e * DIMM * HID;
    for (int k0 = 0; k0 < HID; k0 += 16) {
#pragma unroll
        for (int i = 0; i < 4; i++) {
            int idx = tid + i * 256;
            int r = idx >> 4, c = idx & 15;
            As[r][c] = (t0 + r < cnt) ? hbuf[(size_t)(base + t0 + r) * HID + k0 + c] : 0.f;
            Bs[r][c] = wde[(size_t)(d0 + r) * HID + k0 + c];
        }
        __syncthreads();
#pragma unroll
        for (int kk = 0; kk < 16; kk++) {
            float a[4], b[4];
#pragma unroll
            for (int i = 0; i < 4; i++) a[i] = As[ty + i * 16][kk];
#pragma unroll
            for (int j = 0; j < 4; j++) b[j] = Bs[tx + j * 16][kk];
#pragma unroll
            for (int i = 0; i < 4; i++)
#pragma unroll
                for (int j = 0; j < 4; j++) acc[i][j] += a[i] * b[j];
        }
        __syncthreads();
    }
#pragma unroll
    for (int i = 0; i < 4; i++) {
        int row = ty + i * 16;
        if (t0 + row < cnt) {
            int tok = toks[row];
            float w = rw_[row];
#pragma unroll
            for (int j = 0; j < 4; j++) {
                int col = tx + j * 16;
                atomicAdd(&out[(size_t)tok * DIMM + d0 + col], acc[i][j] * w);
            }
        }
    }
}

// ---------------------------------------------------------------- launch
extern "C" void kernel_launch(void* const* d_in, const int* in_sizes, int n_in,
                              void* d_out, int out_size, void* d_ws, size_t ws_size,
                              hipStream_t stream)
{
    const float* x      = (const float*)d_in[0];
    const float* cs     = (const float*)d_in[1];
    const float* sn     = (const float*)d_in[2];
    const float* w_na   = (const float*)d_in[3];
    const float* wq     = (const float*)d_in[4];
    const float* wk     = (const float*)d_in[5];
    const float* wv     = (const float*)d_in[6];
    const float* wo     = (const float*)d_in[7];
    const float* w_nf   = (const float*)d_in[8];
    const float* rw     = (const float*)d_in[9];
    const float* rb     = (const float*)d_in[10];
    const float* wg     = (const float*)d_in[11];
    const float* wu     = (const float*)d_in[12];
    const float* wd     = (const float*)d_in[13];
    float* out = (float*)d_out;

    float* wsf  = (float*)d_ws;
    float* xn   = wsf;                              // 2M
    float* qb   = wsf + (size_t)2 * 1024 * 1024;    // 2M
    float* kb   = wsf + (size_t)4 * 1024 * 1024;    // 512K
    float* vb   = kb + 512 * 1024;                  // 512K
    float* attn = wsf + (size_t)5 * 1024 * 1024;    // 2M
    float* xn2  = wsf + (size_t)7 * 1024 * 1024;    // 2M
    float* hbuf = wsf + (size_t)9 * 1024 * 1024;    // 8M
    float* tail = wsf + (size_t)17 * 1024 * 1024;
    int*   top_idx      = (int*)tail;               // 4096
    float* top_w        = tail + 4096;              // 4096
    int*   counts       = (int*)(tail + 8192);      // 8
    int*   offs         = (int*)(tail + 8192) + 8;  // 8
    int*   pos          = (int*)(tail + 8192) + 16; // 8
    int*   assign_token = (int*)(tail + 8192) + 32; // 4096
    float* assign_w     = tail + 8192 + 32 + 4096;  // 4096

    // 1. rmsnorm (attn)
    rmsnorm_kernel<<<N_TOK, 256, 0, stream>>>(x, w_na, xn);
    // 2. q/k/v projections
    gemm_nt<<<dim3(16, 32), 256, 0, stream>>>(xn, wq, qb, nullptr, N_TOK, 1024, 1024, 1024);
    gemm_nt<<<dim3(4, 32), 256, 0, stream>>>(xn, wk, kb, nullptr, N_TOK, 256, 1024, 256);
    gemm_nt<<<dim3(4, 32), 256, 0, stream>>>(xn, wv, vb, nullptr, N_TOK, 256, 1024, 256);
    // 3. RoPE
    rope_kernel<<<(N_TOK * NH * 32) / 256, 256, 0, stream>>>(qb, cs, sn, NH);
    rope_kernel<<<(N_TOK * NKV * 32) / 256, 256, 0, stream>>>(kb, cs, sn, NKV);
    // 4. attention
    attn_fwd<<<dim3(4, NH, 2), 256, 0, stream>>>(qb, kb, vb, attn);
    // 5. output projection + residual -> d_out holds x1
    gemm_nt<<<dim3(16, 32), 256, 0, stream>>>(attn, wo, out, x, N_TOK, 1024, 1024, 1024);
    // 6. rmsnorm (ffn)
    rmsnorm_kernel<<<N_TOK, 256, 0, stream>>>(out, w_nf, xn2);
    // 7-10. routing
    init_counts<<<1, 64, 0, stream>>>(counts, pos);
    router_kernel<<<N_TOK / 4, 256, 0, stream>>>(xn2, rw, rb, top_idx, top_w, counts);
    offsets_kernel<<<1, 64, 0, stream>>>(counts, offs);
    fill_kernel<<<N_TOK / 256, 256, 0, stream>>>(top_idx, top_w, offs, pos, assign_token, assign_w);
    // 11. gate/up + silu
    moe_gateup<<<dim3(HID / 64, 32, NEXP), 256, 0, stream>>>(xn2, wg, wu, assign_token, offs, counts, hbuf);
    // 12. down proj + scatter-add into d_out
    moe_down<<<dim3(DIMM / 64, 32, NEXP), 256, 0, stream>>>(hbuf, wd, assign_token, assign_w, offs, counts, out);
}

// Round 3
// 1533.624 us; speedup vs baseline: 1.5226x; 1.5226x over previous
//
#include <hip/hip_runtime.h>
#include <math.h>

#define N_TOK   2048      // B*T
#define SEQ     1024
#define DIMM    1024
#define NH      16
#define NKV     4
#define HD      64
#define HID     2048
#define NEXP    8

typedef __attribute__((ext_vector_type(4))) float f32x4;
typedef __attribute__((ext_vector_type(8))) short s16x8;

__device__ __forceinline__ unsigned short f2bf(float f) {
    union { float f; unsigned u; } v; v.f = f;
    unsigned r = v.u + 0x7fffu + ((v.u >> 16) & 1u);
    return (unsigned short)(r >> 16);
}
__device__ __forceinline__ float bf2f(unsigned short h) {
    union { unsigned u; float f; } v; v.u = ((unsigned)h) << 16;
    return v.f;
}

__device__ __forceinline__ f32x4 mfma16(s16x8 a, s16x8 b, f32x4 c) {
    return __builtin_amdgcn_mfma_f32_16x16x32_bf16(a, b, c, 0, 0, 0);
}

// LDS tile row stride = 64 bf16 = 128 B; XOR-swizzle 16B slot with row&7 (T2)
__device__ __forceinline__ int lds_byte(int row, int byte_in_row, int swz_key) {
    return row * 128 + (byte_in_row ^ ((swz_key & 7) << 4));
}

// load a 16B MFMA fragment (8 bf16) for logical row `row`, k-slice ks (0/1)
__device__ __forceinline__ s16x8 ldfrag(const char* base, int row, int ks, int lane) {
    int b = lds_byte(row, ks * 64 + ((lane >> 4) * 16), row);
    return *(const s16x8*)(base + b);
}

// ---------------------------------------------------------------- rmsnorm
__global__ __launch_bounds__(256) void rmsnorm_kernel(const float* __restrict__ x,
    const float* __restrict__ w, float* __restrict__ out)
{
    int row = blockIdx.x;
    const float4* xr = reinterpret_cast<const float4*>(x + (size_t)row * DIMM);
    const float4* wr = reinterpret_cast<const float4*>(w);
    float4 v = xr[threadIdx.x];
    float ss = v.x*v.x + v.y*v.y + v.z*v.z + v.w*v.w;
#pragma unroll
    for (int off = 32; off; off >>= 1) ss += __shfl_xor(ss, off);
    __shared__ float red[4];
    int wid = threadIdx.x >> 6, lane = threadIdx.x & 63;
    if (lane == 0) red[wid] = ss;
    __syncthreads();
    float tot = red[0] + red[1] + red[2] + red[3];
    float inv = rsqrtf(tot * (1.0f/DIMM) + 1e-6f);
    float4 ww = wr[threadIdx.x];
    float4 o;
    o.x = ww.x * v.x * inv;
    o.y = ww.y * v.y * inv;
    o.z = ww.z * v.z * inv;
    o.w = ww.w * v.w * inv;
    reinterpret_cast<float4*>(out + (size_t)row * DIMM)[threadIdx.x] = o;
}

// ---------------------------------------------------------------- split-bf16 MFMA GEMM (fp32-grade accuracy)
// C[M,N] = A[M,K] @ B[N,K]^T (+R).  acc += Ah*Bh + Ah*Bl + Al*Bh
// BM=128, BN=128, BK=64, 256 thr = 4 waves (2x2), wave tile 64x64
__global__ __launch_bounds__(256) void gemm_split(const float* __restrict__ A,
    const float* __restrict__ B, float* __restrict__ C, const float* __restrict__ R,
    int M, int N, int K, int ldc)
{
    __shared__ __align__(16) char Ah[128 * 128];
    __shared__ __align__(16) char Al[128 * 128];
    __shared__ __align__(16) char Bh[128 * 128];
    __shared__ __align__(16) char Bl[128 * 128];
    int tid = threadIdx.x;
    int m0 = blockIdx.y * 128, n0 = blockIdx.x * 128;
    int lane = tid & 63, wv = tid >> 6;
    int wm = wv >> 1, wn = wv & 1;
    int c4 = tid & 15, r0 = tid >> 4;

    f32x4 acc[4][4];
#pragma unroll
    for (int i = 0; i < 4; i++)
#pragma unroll
        for (int j = 0; j < 4; j++) acc[i][j] = f32x4{0.f, 0.f, 0.f, 0.f};

    for (int k0 = 0; k0 < K; k0 += 64) {
#pragma unroll
        for (int i = 0; i < 8; ++i) {
            int r = r0 + i * 16;
            float4 va = *(const float4*)(A + (size_t)(m0 + r) * K + k0 + c4 * 4);
            float4 vb = *(const float4*)(B + (size_t)(n0 + r) * K + k0 + c4 * 4);
            ushort4 ah, al, bh, bl;
            ah.x = f2bf(va.x); ah.y = f2bf(va.y); ah.z = f2bf(va.z); ah.w = f2bf(va.w);
            al.x = f2bf(va.x - bf2f(ah.x)); al.y = f2bf(va.y - bf2f(ah.y));
            al.z = f2bf(va.z - bf2f(ah.z)); al.w = f2bf(va.w - bf2f(ah.w));
            bh.x = f2bf(vb.x); bh.y = f2bf(vb.y); bh.z = f2bf(vb.z); bh.w = f2bf(vb.w);
            bl.x = f2bf(vb.x - bf2f(bh.x)); bl.y = f2bf(vb.y - bf2f(bh.y));
            bl.z = f2bf(vb.z - bf2f(bh.z)); bl.w = f2bf(vb.w - bf2f(bh.w));
            int byte = lds_byte(r, c4 * 8, r);
            *(ushort4*)(Ah + byte) = ah;
            *(ushort4*)(Al + byte) = al;
            *(ushort4*)(Bh + byte) = bh;
            *(ushort4*)(Bl + byte) = bl;
        }
        __syncthreads();
#pragma unroll
        for (int ks = 0; ks < 2; ++ks) {
            s16x8 afh[4], afl[4], bfh[4], bfl[4];
#pragma unroll
            for (int mi = 0; mi < 4; mi++) {
                int row = wm * 64 + mi * 16 + (lane & 15);
                afh[mi] = ldfrag(Ah, row, ks, lane);
                afl[mi] = ldfrag(Al, row, ks, lane);
            }
#pragma unroll
            for (int nj = 0; nj < 4; nj++) {
                int row = wn * 64 + nj * 16 + (lane & 15);
                bfh[nj] = ldfrag(Bh, row, ks, lane);
                bfl[nj] = ldfrag(Bl, row, ks, lane);
            }
#pragma unroll
            for (int mi = 0; mi < 4; mi++)
#pragma unroll
                for (int nj = 0; nj < 4; nj++) {
                    acc[mi][nj] = mfma16(afl[mi], bfh[nj], acc[mi][nj]);
                    acc[mi][nj] = mfma16(afh[mi], bfl[nj], acc[mi][nj]);
                    acc[mi][nj] = mfma16(afh[mi], bfh[nj], acc[mi][nj]);
                }
        }
        __syncthreads();
    }
#pragma unroll
    for (int mi = 0; mi < 4; mi++)
#pragma unroll
        for (int nj = 0; nj < 4; nj++)
#pragma unroll
            for (int r = 0; r < 4; r++) {
                int m = m0 + wm * 64 + mi * 16 + (lane >> 4) * 4 + r;
                int n = n0 + wn * 64 + nj * 16 + (lane & 15);
                float v = acc[mi][nj][r];
                if (R) v += R[(size_t)m * ldc + n];
                C[(size_t)m * ldc + n] = v;
            }
}

// ---------------------------------------------------------------- RoPE (in place)
__global__ __launch_bounds__(256) void rope_kernel(float* __restrict__ buf,
    const float* __restrict__ cs, const float* __restrict__ sn, int nheads)
{
    int gid = blockIdx.x * 256 + threadIdx.x;
    int total = N_TOK * nheads * 32;
    if (gid >= total) return;
    int i = gid & 31;
    int h = (gid >> 5) % nheads;
    int n = gid / (32 * nheads);
    int t = n & (SEQ - 1);
    float* p = buf + (size_t)n * (nheads * HD) + h * HD + 2 * i;
    float xe = p[0], xo = p[1];
    float c = cs[t * 32 + i], s = sn[t * 32 + i];
    p[0] = xe * c - xo * s;
    p[1] = xe * s + xo * c;
}

// ---------------------------------------------------------------- attention (flash-style, thread = one q row)
__global__ __launch_bounds__(256) void attn_fwd(const float* __restrict__ q,
    const float* __restrict__ k, const float* __restrict__ v, float* __restrict__ out)
{
    int b = blockIdx.z, h = blockIdx.y;
    int r = blockIdx.x * 256 + threadIdx.x;   // query row within sequence
    int kvh = h >> 2;
    __shared__ float Ks[64 * 64];
    __shared__ float Vs[64 * 64];
    const float* qp = q + ((size_t)(b * SEQ + r)) * (NH * HD) + h * HD;
    float qreg[64];
#pragma unroll
    for (int d4 = 0; d4 < 16; d4++) {
        float4 t = reinterpret_cast<const float4*>(qp)[d4];
        qreg[d4*4+0] = t.x; qreg[d4*4+1] = t.y; qreg[d4*4+2] = t.z; qreg[d4*4+3] = t.w;
    }
    float o[64];
#pragma unroll
    for (int d = 0; d < 64; d++) o[d] = 0.f;
    float m = -INFINITY, l = 0.f;
    int ntiles = (blockIdx.x * 256 + 256) >> 6;
    for (int kt = 0; kt < ntiles; kt++) {
        int kbase = kt << 6;
        __syncthreads();
        for (int idx = threadIdx.x; idx < 4096; idx += 256) {
            int kk = idx >> 6, d = idx & 63;
            size_t g = ((size_t)(b * SEQ + kbase + kk)) * (NKV * HD) + kvh * HD + d;
            Ks[idx] = k[g];
            Vs[idx] = v[g];
        }
        __syncthreads();
        int rem = r - kbase + 1;
        int kmax = rem > 64 ? 64 : rem;
        for (int kk = 0; kk < kmax; kk++) {
            const float* kr = &Ks[kk << 6];
            float s = 0.f;
#pragma unroll
            for (int d = 0; d < 64; d++) s += qreg[d] * kr[d];
            s *= 0.125f;
            float p;
            if (s > m) {
                float c = __expf(m - s);
                l *= c;
#pragma unroll
                for (int d = 0; d < 64; d++) o[d] *= c;
                m = s;
                p = 1.f;
            } else {
                p = __expf(s - m);
            }
            l += p;
            const float* vr = &Vs[kk << 6];
#pragma unroll
            for (int d = 0; d < 64; d++) o[d] += p * vr[d];
        }
    }
    float inv = 1.f / l;
    float* op = out + ((size_t)(b * SEQ + r)) * (NH * HD) + h * HD;
#pragma unroll
    for (int d4 = 0; d4 < 16; d4++) {
        float4 t;
        t.x = o[d4*4+0] * inv; t.y = o[d4*4+1] * inv;
        t.z = o[d4*4+2] * inv; t.w = o[d4*4+3] * inv;
        reinterpret_cast<float4*>(op)[d4] = t;
    }
}

// ---------------------------------------------------------------- routing
__global__ void init_counts(int* counts, int* pos)
{
    int t = threadIdx.x;
    if (t < NEXP) { counts[t] = 0; pos[t] = 0; }
}

__global__ __launch_bounds__(256) void router_kernel(const float* __restrict__ xn2,
    const float* __restrict__ rw, const float* __restrict__ rb,
    int* __restrict__ top_idx, float* __restrict__ top_w, int* __restrict__ counts)
{
    int wid = threadIdx.x >> 6, lane = threadIdx.x & 63;
    int n = blockIdx.x * 4 + wid;
    if (n >= N_TOK) return;
    const float* xr = xn2 + (size_t)n * DIMM;
    float lg[NEXP];
#pragma unroll
    for (int e = 0; e < NEXP; e++) {
        float p = 0.f;
        for (int d = lane; d < DIMM; d += 64) p += xr[d] * rw[e * DIMM + d];
#pragma unroll
        for (int off = 32; off; off >>= 1) p += __shfl_xor(p, off);
        lg[e] = p + rb[e];
    }
    if (lane == 0) {
        float m = lg[0];
#pragma unroll
        for (int e = 1; e < NEXP; e++) m = fmaxf(m, lg[e]);
        float pe[NEXP], s = 0.f;
#pragma unroll
        for (int e = 0; e < NEXP; e++) { pe[e] = __expf(lg[e] - m); s += pe[e]; }
        int i1 = 0; float v1 = pe[0];
#pragma unroll
        for (int e = 1; e < NEXP; e++) if (pe[e] > v1) { v1 = pe[e]; i1 = e; }
        int i2 = -1; float v2 = -1.f;
#pragma unroll
        for (int e = 0; e < NEXP; e++) if (e != i1 && pe[e] > v2) { v2 = pe[e]; i2 = e; }
        v1 /= s; v2 /= s;
        float den = v1 + v2 + 1e-9f;
        top_idx[2 * n] = i1; top_idx[2 * n + 1] = i2;
        top_w[2 * n] = v1 / den; top_w[2 * n + 1] = v2 / den;
        atomicAdd(&counts[i1], 1);
        atomicAdd(&counts[i2], 1);
    }
}

__global__ void offsets_kernel(const int* counts, int* offs)
{
    if (threadIdx.x == 0) {
        int s = 0;
        for (int e = 0; e < NEXP; e++) { offs[e] = s; s += counts[e]; }
    }
}

__global__ __launch_bounds__(256) void fill_kernel(const int* __restrict__ top_idx,
    const float* __restrict__ top_w, const int* __restrict__ offs, int* __restrict__ pos,
    int* __restrict__ assign_token, float* __restrict__ assign_w)
{
    int n = blockIdx.x * 256 + threadIdx.x;
    if (n >= N_TOK) return;
#pragma unroll
    for (int s = 0; s < 2; s++) {
        int e = top_idx[2 * n + s];
        int p = atomicAdd(&pos[e], 1);
        int r = offs[e] + p;
        assign_token[r] = n;
        assign_w[r] = top_w[2 * n + s];
    }
}

// ---------------------------------------------------------------- MoE gate/up, MFMA, fused silu
// BM=128 tokens, BN=64 cols of BOTH gate and up, BK=64. 4 waves 2x2, wave tile 64x32 (per matrix)
__global__ __launch_bounds__(256) void moe_gateup(const float* __restrict__ xn2,
    const float* __restrict__ wg, const float* __restrict__ wu,
    const int* __restrict__ assign_token, const int* __restrict__ offs,
    const int* __restrict__ counts, float* __restrict__ hbuf)
{
    int e = blockIdx.z;
    int cnt = counts[e];
    int t0 = blockIdx.y * 128;
    if (t0 >= cnt) return;
    int base = offs[e];
    int h0 = blockIdx.x * 64;
    __shared__ __align__(16) char As[128 * 128];
    __shared__ __align__(16) char Gs[64 * 128];
    __shared__ __align__(16) char Us[64 * 128];
    __shared__ int toks[128];
    int tid = threadIdx.x;
    if (tid < 128) {
        int a = t0 + tid;
        toks[tid] = (a < cnt) ? assign_token[base + a] : -1;
    }
    __syncthreads();
    int lane = tid & 63, wv = tid >> 6;
    int wm = wv >> 1, wn = wv & 1;
    int c4 = tid & 15, r0 = tid >> 4;

    f32x4 accg[4][2], accu[4][2];
#pragma unroll
    for (int i = 0; i < 4; i++)
#pragma unroll
        for (int j = 0; j < 2; j++) { accg[i][j] = f32x4{0,0,0,0}; accu[i][j] = f32x4{0,0,0,0}; }

    const float* wge = wg + (size_t)e * HID * DIMM;
    const float* wue = wu + (size_t)e * HID * DIMM;

    for (int k0 = 0; k0 < DIMM; k0 += 64) {
        // A tile: 128 rows (gathered tokens)
#pragma unroll
        for (int i = 0; i < 8; ++i) {
            int r = r0 + i * 16;
            int tok = toks[r];
            float4 va = (tok >= 0) ? *(const float4*)(xn2 + (size_t)tok * DIMM + k0 + c4 * 4)
                                   : float4{0.f, 0.f, 0.f, 0.f};
            ushort4 ba;
            ba.x = f2bf(va.x); ba.y = f2bf(va.y); ba.z = f2bf(va.z); ba.w = f2bf(va.w);
            *(ushort4*)(As + lds_byte(r, c4 * 8, r)) = ba;
        }
        // B tiles: 64 rows each of gate and up
#pragma unroll
        for (int i = 0; i < 4; ++i) {
            int r = r0 + i * 16;
            float4 vg = *(const float4*)(wge + (size_t)(h0 + r) * DIMM + k0 + c4 * 4);
            float4 vu = *(const float4*)(wue + (size_t)(h0 + r) * DIMM + k0 + c4 * 4);
            ushort4 bg, bu;
            bg.x = f2bf(vg.x); bg.y = f2bf(vg.y); bg.z = f2bf(vg.z); bg.w = f2bf(vg.w);
            bu.x = f2bf(vu.x); bu.y = f2bf(vu.y); bu.z = f2bf(vu.z); bu.w = f2bf(vu.w);
            int byte = lds_byte(r, c4 * 8, r);
            *(ushort4*)(Gs + byte) = bg;
            *(ushort4*)(Us + byte) = bu;
        }
        __syncthreads();
#pragma unroll
        for (int ks = 0; ks < 2; ++ks) {
            s16x8 af[4], gf[2], uf[2];
#pragma unroll
            for (int mi = 0; mi < 4; mi++) af[mi] = ldfrag(As, wm * 64 + mi * 16 + (lane & 15), ks, lane);
#pragma unroll
            for (int nj = 0; nj < 2; nj++) {
                int row = wn * 32 + nj * 16 + (lane & 15);
                gf[nj] = ldfrag(Gs, row, ks, lane);
                uf[nj] = ldfrag(Us, row, ks, lane);
            }
#pragma unroll
            for (int mi = 0; mi < 4; mi++)
#pragma unroll
                for (int nj = 0; nj < 2; nj++) {
                    accg[mi][nj] = mfma16(af[mi], gf[nj], accg[mi][nj]);
                    accu[mi][nj] = mfma16(af[mi], uf[nj], accu[mi][nj]);
                }
        }
        __syncthreads();
    }
#pragma unroll
    for (int mi = 0; mi < 4; mi++)
#pragma unroll
        for (int nj = 0; nj < 2; nj++)
#pragma unroll
            for (int r = 0; r < 4; r++) {
                int row = wm * 64 + mi * 16 + (lane >> 4) * 4 + r;
                if (t0 + row < cnt) {
                    int col = wn * 32 + nj * 16 + (lane & 15);
                    float g = accg[mi][nj][r], u = accu[mi][nj][r];
                    float hh = (g / (1.f + __expf(-g))) * u;
                    hbuf[(size_t)(base + t0 + row) * HID + h0 + col] = hh;
                }
            }
}

// ---------------------------------------------------------------- MoE down proj, MFMA, weighted atomic scatter
// BM=128 slots, BN=128 out-dims, BK=64
__global__ __launch_bounds__(256) void moe_down(const float* __restrict__ hbuf,
    const float* __restrict__ wd, const int* __restrict__ assign_token,
    const float* __restrict__ assign_w, const int* __restrict__ offs,
    const int* __restrict__ counts, float* __restrict__ out)
{
    int e = blockIdx.z;
    int cnt = counts[e];
    int t0 = blockIdx.y * 128;
    if (t0 >= cnt) return;
    int base = offs[e];
    int d0 = blockIdx.x * 128;
    __shared__ __align__(16) char As[128 * 128];
    __shared__ __align__(16) char Bs[128 * 128];
    __shared__ int toks[128];
    __shared__ float rw_[128];
    int tid = threadIdx.x;
    if (tid < 128) {
        int a = t0 + tid;
        toks[tid] = (a < cnt) ? assign_token[base + a] : -1;
        rw_[tid] = (a < cnt) ? assign_w[base + a] : 0.f;
    }
    __syncthreads();
    int lane = tid & 63, wv = tid >> 6;
    int wm = wv >> 1, wn = wv & 1;
    int c4 = tid & 15, r0 = tid >> 4;

    f32x4 acc[4][4];
#pragma unroll
    for (int i = 0; i < 4; i++)
#pragma unroll
        for (int j = 0; j < 4; j++) acc[i][j] = f32x4{0,0,0,0};

    const float* wde = wd + (size_t)e * DIMM * HID;

    for (int k0 = 0; k0 < HID; k0 += 64) {
#pragma unroll
        for (int i = 0; i < 8; ++i) {
            int r = r0 + i * 16;
            float4 va = (t0 + r < cnt) ? *(const float4*)(hbuf + (size_t)(base + t0 + r) * HID + k0 + c4 * 4)
                                       : float4{0.f, 0.f, 0.f, 0.f};
            float4 vb = *(const float4*)(wde + (size_t)(d0 + r) * HID + k0 + c4 * 4);
            ushort4 ba, bb;
            ba.x = f2bf(va.x); ba.y = f2bf(va.y); ba.z = f2bf(va.z); ba.w = f2bf(va.w);
            bb.x = f2bf(vb.x); bb.y = f2bf(vb.y); bb.z = f2bf(vb.z); bb.w = f2bf(vb.w);
            int byte = lds_byte(r, c4 * 8, r);
            *(ushort4*)(As + byte) = ba;
            *(ushort4*)(Bs + byte) = bb;
        }
        __syncthreads();
#pragma unroll
        for (int ks = 0; ks < 2; ++ks) {
            s16x8 af[4], bf[4];
#pragma unroll
            for (int mi = 0; mi < 4; mi++) af[mi] = ldfrag(As, wm * 64 + mi * 16 + (lane & 15), ks, lane);
#pragma unroll
            for (int nj = 0; nj < 4; nj++) bf[nj] = ldfrag(Bs, wn * 64 + nj * 16 + (lane & 15), ks, lane);
#pragma unroll
            for (int mi = 0; mi < 4; mi++)
#pragma unroll
                for (int nj = 0; nj < 4; nj++)
                    acc[mi][nj] = mfma16(af[mi], bf[nj], acc[mi][nj]);
        }
        __syncthreads();
    }
#pragma unroll
    for (int mi = 0; mi < 4; mi++)
#pragma unroll
        for (int r = 0; r < 4; r++) {
            int row = wm * 64 + mi * 16 + (lane >> 4) * 4 + r;
            if (t0 + row < cnt) {
                int tok = toks[row];
                float w = rw_[row];
#pragma unroll
                for (int nj = 0; nj < 4; nj++) {
                    int col = d0 + wn * 64 + nj * 16 + (lane & 15);
                    atomicAdd(&out[(size_t)tok * DIMM + col], acc[mi][nj][r] * w);
                }
            }
        }
}

// ---------------------------------------------------------------- launch
extern "C" void kernel_launch(void* const* d_in, const int* in_sizes, int n_in,
                              void* d_out, int out_size, void* d_ws, size_t ws_size,
                              hipStream_t stream)
{
    const float* x      = (const float*)d_in[0];
    const float* cs     = (const float*)d_in[1];
    const float* sn     = (const float*)d_in[2];
    const float* w_na   = (const float*)d_in[3];
    const float* wq     = (const float*)d_in[4];
    const float* wk     = (const float*)d_in[5];
    const float* wv     = (const float*)d_in[6];
    const float* wo     = (const float*)d_in[7];
    const float* w_nf   = (const float*)d_in[8];
    const float* rw     = (const float*)d_in[9];
    const float* rb     = (const float*)d_in[10];
    const float* wg     = (const float*)d_in[11];
    const float* wu     = (const float*)d_in[12];
    const float* wd     = (const float*)d_in[13];
    float* out = (float*)d_out;

    float* wsf  = (float*)d_ws;
    float* xn   = wsf;                              // 2M
    float* qb   = wsf + (size_t)2 * 1024 * 1024;    // 2M
    float* kb   = wsf + (size_t)4 * 1024 * 1024;    // 512K
    float* vb   = kb + 512 * 1024;                  // 512K
    float* attn = wsf + (size_t)5 * 1024 * 1024;    // 2M
    float* xn2  = wsf + (size_t)7 * 1024 * 1024;    // 2M
    float* hbuf = wsf + (size_t)9 * 1024 * 1024;    // 8M
    float* tail = wsf + (size_t)17 * 1024 * 1024;
    int*   top_idx      = (int*)tail;               // 4096
    float* top_w        = tail + 4096;              // 4096
    int*   counts       = (int*)(tail + 8192);      // 8
    int*   offs         = (int*)(tail + 8192) + 8;  // 8
    int*   pos          = (int*)(tail + 8192) + 16; // 8
    int*   assign_token = (int*)(tail + 8192) + 32; // 4096
    float* assign_w     = tail + 8192 + 32 + 4096;  // 4096

    // 1. rmsnorm (attn)
    rmsnorm_kernel<<<N_TOK, 256, 0, stream>>>(x, w_na, xn);
    // 2. q/k/v projections (split-bf16 MFMA, fp32-grade — feeds routing)
    gemm_split<<<dim3(8, 16), 256, 0, stream>>>(xn, wq, qb, nullptr, N_TOK, 1024, 1024, 1024);
    gemm_split<<<dim3(2, 16), 256, 0, stream>>>(xn, wk, kb, nullptr, N_TOK, 256, 1024, 256);
    gemm_split<<<dim3(2, 16), 256, 0, stream>>>(xn, wv, vb, nullptr, N_TOK, 256, 1024, 256);
    // 3. RoPE
    rope_kernel<<<(N_TOK * NH * 32) / 256, 256, 0, stream>>>(qb, cs, sn, NH);
    rope_kernel<<<(N_TOK * NKV * 32) / 256, 256, 0, stream>>>(kb, cs, sn, NKV);
    // 4. attention
    attn_fwd<<<dim3(4, NH, 2), 256, 0, stream>>>(qb, kb, vb, attn);
    // 5. output projection + residual -> d_out holds x1 (split-bf16, fp32-grade)
    gemm_split<<<dim3(8, 16), 256, 0, stream>>>(attn, wo, out, x, N_TOK, 1024, 1024, 1024);
    // 6. rmsnorm (ffn)
    rmsnorm_kernel<<<N_TOK, 256, 0, stream>>>(out, w_nf, xn2);
    // 7-10. routing
    init_counts<<<1, 64, 0, stream>>>(counts, pos);
    router_kernel<<<N_TOK / 4, 256, 0, stream>>>(xn2, rw, rb, top_idx, top_w, counts);
    offsets_kernel<<<1, 64, 0, stream>>>(counts, offs);
    fill_kernel<<<N_TOK / 256, 256, 0, stream>>>(top_idx, top_w, offs, pos, assign_token, assign_w);
    // 11. gate/up + silu (MFMA bf16)
    moe_gateup<<<dim3(HID / 64, 16, NEXP), 256, 0, stream>>>(xn2, wg, wu, assign_token, offs, counts, hbuf);
    // 12. down proj + scatter-add into d_out (MFMA bf16)
    moe_down<<<dim3(DIMM / 128, 16, NEXP), 256, 0, stream>>>(hbuf, wd, assign_token, assign_w, offs, counts, out);
}

// Round 4
// 1232.316 us; speedup vs baseline: 1.8949x; 1.2445x over previous
//
#include <hip/hip_runtime.h>
#include <math.h>

#define N_TOK   2048      // B*T
#define SEQ     1024
#define DIMM    1024
#define NH      16
#define NKV     4
#define HD      64
#define HID     2048
#define NEXP    8

typedef __attribute__((ext_vector_type(4))) float f32x4;
typedef __attribute__((ext_vector_type(8))) short s16x8;

__device__ __forceinline__ unsigned short f2bf(float f) {
    union { float f; unsigned u; } v; v.f = f;
    unsigned r = v.u + 0x7fffu + ((v.u >> 16) & 1u);
    return (unsigned short)(r >> 16);
}
__device__ __forceinline__ float bf2f(unsigned short h) {
    union { unsigned u; float f; } v; v.u = ((unsigned)h) << 16;
    return v.f;
}

__device__ __forceinline__ f32x4 mfma16(s16x8 a, s16x8 b, f32x4 c) {
    return __builtin_amdgcn_mfma_f32_16x16x32_bf16(a, b, c, 0, 0, 0);
}

// LDS tile row stride = 64 bf16 = 128 B; XOR-swizzle 16B slot with row&7 (T2)
__device__ __forceinline__ int lds_byte(int row, int byte_in_row, int swz_key) {
    return row * 128 + (byte_in_row ^ ((swz_key & 7) << 4));
}

// load a 16B MFMA fragment (8 bf16) for logical row `row`, k-slice ks (0/1)
__device__ __forceinline__ s16x8 ldfrag(const char* base, int row, int ks, int lane) {
    int b = lds_byte(row, ks * 64 + ((lane >> 4) * 16), row);
    return *(const s16x8*)(base + b);
}

// ---------------------------------------------------------------- rmsnorm
__global__ __launch_bounds__(256) void rmsnorm_kernel(const float* __restrict__ x,
    const float* __restrict__ w, float* __restrict__ out)
{
    int row = blockIdx.x;
    const float4* xr = reinterpret_cast<const float4*>(x + (size_t)row * DIMM);
    const float4* wr = reinterpret_cast<const float4*>(w);
    float4 v = xr[threadIdx.x];
    float ss = v.x*v.x + v.y*v.y + v.z*v.z + v.w*v.w;
#pragma unroll
    for (int off = 32; off; off >>= 1) ss += __shfl_xor(ss, off);
    __shared__ float red[4];
    int wid = threadIdx.x >> 6, lane = threadIdx.x & 63;
    if (lane == 0) red[wid] = ss;
    __syncthreads();
    float tot = red[0] + red[1] + red[2] + red[3];
    float inv = rsqrtf(tot * (1.0f/DIMM) + 1e-6f);
    float4 ww = wr[threadIdx.x];
    float4 o;
    o.x = ww.x * v.x * inv;
    o.y = ww.y * v.y * inv;
    o.z = ww.z * v.z * inv;
    o.w = ww.w * v.w * inv;
    reinterpret_cast<float4*>(out + (size_t)row * DIMM)[threadIdx.x] = o;
}

// ---------------------------------------------------------------- split-bf16 MFMA GEMM (fp32-grade accuracy)
// C[M,N] = A[M,K] @ B[N,K]^T (+R).  acc += Ah*Bh + Ah*Bl + Al*Bh
// BM=128, BN=128, BK=64, 256 thr = 4 waves (2x2), wave tile 64x64
__global__ __launch_bounds__(256) void gemm_split(const float* __restrict__ A,
    const float* __restrict__ B, float* __restrict__ C, const float* __restrict__ R,
    int M, int N, int K, int ldc)
{
    __shared__ __align__(16) char Ah[128 * 128];
    __shared__ __align__(16) char Al[128 * 128];
    __shared__ __align__(16) char Bh[128 * 128];
    __shared__ __align__(16) char Bl[128 * 128];
    int tid = threadIdx.x;
    int m0 = blockIdx.y * 128, n0 = blockIdx.x * 128;
    int lane = tid & 63, wv = tid >> 6;
    int wm = wv >> 1, wn = wv & 1;
    int c4 = tid & 15, r0 = tid >> 4;

    f32x4 acc[4][4];
#pragma unroll
    for (int i = 0; i < 4; i++)
#pragma unroll
        for (int j = 0; j < 4; j++) acc[i][j] = f32x4{0.f, 0.f, 0.f, 0.f};

    for (int k0 = 0; k0 < K; k0 += 64) {
#pragma unroll
        for (int i = 0; i < 8; ++i) {
            int r = r0 + i * 16;
            float4 va = *(const float4*)(A + (size_t)(m0 + r) * K + k0 + c4 * 4);
            float4 vb = *(const float4*)(B + (size_t)(n0 + r) * K + k0 + c4 * 4);
            ushort4 ah, al, bh, bl;
            ah.x = f2bf(va.x); ah.y = f2bf(va.y); ah.z = f2bf(va.z); ah.w = f2bf(va.w);
            al.x = f2bf(va.x - bf2f(ah.x)); al.y = f2bf(va.y - bf2f(ah.y));
            al.z = f2bf(va.z - bf2f(ah.z)); al.w = f2bf(va.w - bf2f(ah.w));
            bh.x = f2bf(vb.x); bh.y = f2bf(vb.y); bh.z = f2bf(vb.z); bh.w = f2bf(vb.w);
            bl.x = f2bf(vb.x - bf2f(bh.x)); bl.y = f2bf(vb.y - bf2f(bh.y));
            bl.z = f2bf(vb.z - bf2f(bh.z)); bl.w = f2bf(vb.w - bf2f(bh.w));
            int byte = lds_byte(r, c4 * 8, r);
            *(ushort4*)(Ah + byte) = ah;
            *(ushort4*)(Al + byte) = al;
            *(ushort4*)(Bh + byte) = bh;
            *(ushort4*)(Bl + byte) = bl;
        }
        __syncthreads();
#pragma unroll
        for (int ks = 0; ks < 2; ++ks) {
            s16x8 afh[4], afl[4], bfh[4], bfl[4];
#pragma unroll
            for (int mi = 0; mi < 4; mi++) {
                int row = wm * 64 + mi * 16 + (lane & 15);
                afh[mi] = ldfrag(Ah, row, ks, lane);
                afl[mi] = ldfrag(Al, row, ks, lane);
            }
#pragma unroll
            for (int nj = 0; nj < 4; nj++) {
                int row = wn * 64 + nj * 16 + (lane & 15);
                bfh[nj] = ldfrag(Bh, row, ks, lane);
                bfl[nj] = ldfrag(Bl, row, ks, lane);
            }
#pragma unroll
            for (int mi = 0; mi < 4; mi++)
#pragma unroll
                for (int nj = 0; nj < 4; nj++) {
                    acc[mi][nj] = mfma16(afl[mi], bfh[nj], acc[mi][nj]);
                    acc[mi][nj] = mfma16(afh[mi], bfl[nj], acc[mi][nj]);
                    acc[mi][nj] = mfma16(afh[mi], bfh[nj], acc[mi][nj]);
                }
        }
        __syncthreads();
    }
#pragma unroll
    for (int mi = 0; mi < 4; mi++)
#pragma unroll
        for (int nj = 0; nj < 4; nj++)
#pragma unroll
            for (int r = 0; r < 4; r++) {
                int m = m0 + wm * 64 + mi * 16 + (lane >> 4) * 4 + r;
                int n = n0 + wn * 64 + nj * 16 + (lane & 15);
                float v = acc[mi][nj][r];
                if (R) v += R[(size_t)m * ldc + n];
                C[(size_t)m * ldc + n] = v;
            }
}

// ---------------------------------------------------------------- RoPE (in place)
__global__ __launch_bounds__(256) void rope_kernel(float* __restrict__ buf,
    const float* __restrict__ cs, const float* __restrict__ sn, int nheads)
{
    int gid = blockIdx.x * 256 + threadIdx.x;
    int total = N_TOK * nheads * 32;
    if (gid >= total) return;
    int i = gid & 31;
    int h = (gid >> 5) % nheads;
    int n = gid / (32 * nheads);
    int t = n & (SEQ - 1);
    float* p = buf + (size_t)n * (nheads * HD) + h * HD + 2 * i;
    float xe = p[0], xo = p[1];
    float c = cs[t * 32 + i], s = sn[t * 32 + i];
    p[0] = xe * c - xo * s;
    p[1] = xe * s + xo * c;
}

// ---------------------------------------------------------------- attention (flash-style)
// 4 lanes per q-row (16 dims each), 64 q-rows per 256-thread block
// grid = (SEQ/64, NH, B) = 512 blocks
__global__ __launch_bounds__(256) void attn_fwd(const float* __restrict__ q,
    const float* __restrict__ k, const float* __restrict__ v, float* __restrict__ out)
{
    int b = blockIdx.z, h = blockIdx.y, qt = blockIdx.x;
    int tid = threadIdx.x;
    int r = qt * 64 + (tid >> 2);     // this group's q row
    int dl = (tid & 3) * 16;          // this lane's 16-dim chunk
    int kvh = h >> 2;
    __shared__ float Ks[64][64];
    __shared__ float Vs[64][64];
    const float* qp = q + ((size_t)(b * SEQ + r)) * (NH * HD) + h * HD + dl;
    float qreg[16], o[16];
#pragma unroll
    for (int i = 0; i < 4; i++) {
        float4 t = reinterpret_cast<const float4*>(qp)[i];
        qreg[i*4+0]=t.x; qreg[i*4+1]=t.y; qreg[i*4+2]=t.z; qreg[i*4+3]=t.w;
    }
#pragma unroll
    for (int d = 0; d < 16; d++) o[d] = 0.f;
    float m = -INFINITY, l = 0.f;
    int ntiles = qt + 1;
    for (int kt = 0; kt < ntiles; kt++) {
        int kbase = kt * 64;
        __syncthreads();
        for (int i = tid; i < 1024; i += 256) {
            int row = i >> 4, d4 = (i & 15) * 4;
            size_t g = ((size_t)(b * SEQ + kbase + row)) * (NKV * HD) + kvh * HD + d4;
            *(float4*)&Ks[row][d4] = *(const float4*)(k + g);
            *(float4*)&Vs[row][d4] = *(const float4*)(v + g);
        }
        __syncthreads();
        int kmax = r - kbase + 1;
        if (kmax > 64) kmax = 64;
        for (int kk = 0; kk < kmax; kk++) {
            const float* kr = &Ks[kk][dl];
            float s = 0.f;
#pragma unroll
            for (int d = 0; d < 16; d++) s += qreg[d] * kr[d];
            s += __shfl_xor(s, 1);
            s += __shfl_xor(s, 2);
            s *= 0.125f;
            float p;
            if (s > m) {
                float c = __expf(m - s);
                l *= c;
#pragma unroll
                for (int d = 0; d < 16; d++) o[d] *= c;
                m = s; p = 1.f;
            } else {
                p = __expf(s - m);
            }
            l += p;
            const float* vr = &Vs[kk][dl];
#pragma unroll
            for (int d = 0; d < 16; d++) o[d] += p * vr[d];
        }
    }
    float inv = 1.f / l;
    float* op = out + ((size_t)(b * SEQ + r)) * (NH * HD) + h * HD + dl;
#pragma unroll
    for (int i = 0; i < 4; i++) {
        float4 t;
        t.x = o[i*4+0]*inv; t.y = o[i*4+1]*inv;
        t.z = o[i*4+2]*inv; t.w = o[i*4+3]*inv;
        reinterpret_cast<float4*>(op)[i] = t;
    }
}

// ---------------------------------------------------------------- routing
__global__ void init_counts(int* counts, int* pos)
{
    int t = threadIdx.x;
    if (t < NEXP) { counts[t] = 0; pos[t] = 0; }
}

__global__ __launch_bounds__(256) void router_kernel(const float* __restrict__ xn2,
    const float* __restrict__ rw, const float* __restrict__ rb,
    int* __restrict__ top_idx, float* __restrict__ top_w, int* __restrict__ counts)
{
    int wid = threadIdx.x >> 6, lane = threadIdx.x & 63;
    int n = blockIdx.x * 4 + wid;
    if (n >= N_TOK) return;
    const float* xr = xn2 + (size_t)n * DIMM;
    float lg[NEXP];
#pragma unroll
    for (int e = 0; e < NEXP; e++) {
        float p = 0.f;
        for (int d = lane; d < DIMM; d += 64) p += xr[d] * rw[e * DIMM + d];
#pragma unroll
        for (int off = 32; off; off >>= 1) p += __shfl_xor(p, off);
        lg[e] = p + rb[e];
    }
    if (lane == 0) {
        float m = lg[0];
#pragma unroll
        for (int e = 1; e < NEXP; e++) m = fmaxf(m, lg[e]);
        float pe[NEXP], s = 0.f;
#pragma unroll
        for (int e = 0; e < NEXP; e++) { pe[e] = __expf(lg[e] - m); s += pe[e]; }
        int i1 = 0; float v1 = pe[0];
#pragma unroll
        for (int e = 1; e < NEXP; e++) if (pe[e] > v1) { v1 = pe[e]; i1 = e; }
        int i2 = -1; float v2 = -1.f;
#pragma unroll
        for (int e = 0; e < NEXP; e++) if (e != i1 && pe[e] > v2) { v2 = pe[e]; i2 = e; }
        v1 /= s; v2 /= s;
        float den = v1 + v2 + 1e-9f;
        top_idx[2 * n] = i1; top_idx[2 * n + 1] = i2;
        top_w[2 * n] = v1 / den; top_w[2 * n + 1] = v2 / den;
        atomicAdd(&counts[i1], 1);
        atomicAdd(&counts[i2], 1);
    }
}

__global__ void offsets_kernel(const int* counts, int* offs)
{
    if (threadIdx.x == 0) {
        int s = 0;
        for (int e = 0; e < NEXP; e++) { offs[e] = s; s += counts[e]; }
    }
}

__global__ __launch_bounds__(256) void fill_kernel(const int* __restrict__ top_idx,
    const float* __restrict__ top_w, const int* __restrict__ offs, int* __restrict__ pos,
    int* __restrict__ assign_token, float* __restrict__ assign_w)
{
    int n = blockIdx.x * 256 + threadIdx.x;
    if (n >= N_TOK) return;
#pragma unroll
    for (int s = 0; s < 2; s++) {
        int e = top_idx[2 * n + s];
        int p = atomicAdd(&pos[e], 1);
        int r = offs[e] + p;
        assign_token[r] = n;
        assign_w[r] = top_w[2 * n + s];
    }
}

// ---------------------------------------------------------------- MoE gate/up, MFMA, fused silu
// BM=128 tokens, BN=64 cols of BOTH gate and up, BK=64. 4 waves 2x2, wave tile 64x32 (per matrix)
__global__ __launch_bounds__(256) void moe_gateup(const float* __restrict__ xn2,
    const float* __restrict__ wg, const float* __restrict__ wu,
    const int* __restrict__ assign_token, const int* __restrict__ offs,
    const int* __restrict__ counts, float* __restrict__ hbuf)
{
    int e = blockIdx.z;
    int cnt = counts[e];
    int t0 = blockIdx.y * 128;
    if (t0 >= cnt) return;
    int base = offs[e];
    int h0 = blockIdx.x * 64;
    __shared__ __align__(16) char As[128 * 128];
    __shared__ __align__(16) char Gs[64 * 128];
    __shared__ __align__(16) char Us[64 * 128];
    __shared__ int toks[128];
    int tid = threadIdx.x;
    if (tid < 128) {
        int a = t0 + tid;
        toks[tid] = (a < cnt) ? assign_token[base + a] : -1;
    }
    __syncthreads();
    int lane = tid & 63, wv = tid >> 6;
    int wm = wv >> 1, wn = wv & 1;
    int c4 = tid & 15, r0 = tid >> 4;

    f32x4 accg[4][2], accu[4][2];
#pragma unroll
    for (int i = 0; i < 4; i++)
#pragma unroll
        for (int j = 0; j < 2; j++) { accg[i][j] = f32x4{0,0,0,0}; accu[i][j] = f32x4{0,0,0,0}; }

    const float* wge = wg + (size_t)e * HID * DIMM;
    const float* wue = wu + (size_t)e * HID * DIMM;

    for (int k0 = 0; k0 < DIMM; k0 += 64) {
        // A tile: 128 rows (gathered tokens)
#pragma unroll
        for (int i = 0; i < 8; ++i) {
            int r = r0 + i * 16;
            int tok = toks[r];
            float4 va = (tok >= 0) ? *(const float4*)(xn2 + (size_t)tok * DIMM + k0 + c4 * 4)
                                   : float4{0.f, 0.f, 0.f, 0.f};
            ushort4 ba;
            ba.x = f2bf(va.x); ba.y = f2bf(va.y); ba.z = f2bf(va.z); ba.w = f2bf(va.w);
            *(ushort4*)(As + lds_byte(r, c4 * 8, r)) = ba;
        }
        // B tiles: 64 rows each of gate and up
#pragma unroll
        for (int i = 0; i < 4; ++i) {
            int r = r0 + i * 16;
            float4 vg = *(const float4*)(wge + (size_t)(h0 + r) * DIMM + k0 + c4 * 4);
            float4 vu = *(const float4*)(wue + (size_t)(h0 + r) * DIMM + k0 + c4 * 4);
            ushort4 bg, bu;
            bg.x = f2bf(vg.x); bg.y = f2bf(vg.y); bg.z = f2bf(vg.z); bg.w = f2bf(vg.w);
            bu.x = f2bf(vu.x); bu.y = f2bf(vu.y); bu.z = f2bf(vu.z); bu.w = f2bf(vu.w);
            int byte = lds_byte(r, c4 * 8, r);
            *(ushort4*)(Gs + byte) = bg;
            *(ushort4*)(Us + byte) = bu;
        }
        __syncthreads();
#pragma unroll
        for (int ks = 0; ks < 2; ++ks) {
            s16x8 af[4], gf[2], uf[2];
#pragma unroll
            for (int mi = 0; mi < 4; mi++) af[mi] = ldfrag(As, wm * 64 + mi * 16 + (lane & 15), ks, lane);
#pragma unroll
            for (int nj = 0; nj < 2; nj++) {
                int row = wn * 32 + nj * 16 + (lane & 15);
                gf[nj] = ldfrag(Gs, row, ks, lane);
                uf[nj] = ldfrag(Us, row, ks, lane);
            }
#pragma unroll
            for (int mi = 0; mi < 4; mi++)
#pragma unroll
                for (int nj = 0; nj < 2; nj++) {
                    accg[mi][nj] = mfma16(af[mi], gf[nj], accg[mi][nj]);
                    accu[mi][nj] = mfma16(af[mi], uf[nj], accu[mi][nj]);
                }
        }
        __syncthreads();
    }
#pragma unroll
    for (int mi = 0; mi < 4; mi++)
#pragma unroll
        for (int nj = 0; nj < 2; nj++)
#pragma unroll
            for (int r = 0; r < 4; r++) {
                int row = wm * 64 + mi * 16 + (lane >> 4) * 4 + r;
                if (t0 + row < cnt) {
                    int col = wn * 32 + nj * 16 + (lane & 15);
                    float g = accg[mi][nj][r], u = accu[mi][nj][r];
                    float hh = (g / (1.f + __expf(-g))) * u;
                    hbuf[(size_t)(base + t0 + row) * HID + h0 + col] = hh;
                }
            }
}

// ---------------------------------------------------------------- MoE down proj, MFMA, weighted atomic scatter
// BM=128 slots, BN=128 out-dims, BK=64
__global__ __launch_bounds__(256) void moe_down(const float* __restrict__ hbuf,
    const float* __restrict__ wd, const int* __restrict__ assign_token,
    const float* __restrict__ assign_w, const int* __restrict__ offs,
    const int* __restrict__ counts, float* __restrict__ out)
{
    int e = blockIdx.z;
    int cnt = counts[e];
    int t0 = blockIdx.y * 128;
    if (t0 >= cnt) return;
    int base = offs[e];
    int d0 = blockIdx.x * 128;
    __shared__ __align__(16) char As[128 * 128];
    __shared__ __align__(16) char Bs[128 * 128];
    __shared__ int toks[128];
    __shared__ float rw_[128];
    int tid = threadIdx.x;
    if (tid < 128) {
        int a = t0 + tid;
        toks[tid] = (a < cnt) ? assign_token[base + a] : -1;
        rw_[tid] = (a < cnt) ? assign_w[base + a] : 0.f;
    }
    __syncthreads();
    int lane = tid & 63, wv = tid >> 6;
    int wm = wv >> 1, wn = wv & 1;
    int c4 = tid & 15, r0 = tid >> 4;

    f32x4 acc[4][4];
#pragma unroll
    for (int i = 0; i < 4; i++)
#pragma unroll
        for (int j = 0; j < 4; j++) acc[i][j] = f32x4{0,0,0,0};

    const float* wde = wd + (size_t)e * DIMM * HID;

    for (int k0 = 0; k0 < HID; k0 += 64) {
#pragma unroll
        for (int i = 0; i < 8; ++i) {
            int r = r0 + i * 16;
            float4 va = (t0 + r < cnt) ? *(const float4*)(hbuf + (size_t)(base + t0 + r) * HID + k0 + c4 * 4)
                                       : float4{0.f, 0.f, 0.f, 0.f};
            float4 vb = *(const float4*)(wde + (size_t)(d0 + r) * HID + k0 + c4 * 4);
            ushort4 ba, bb;
            ba.x = f2bf(va.x); ba.y = f2bf(va.y); ba.z = f2bf(va.z); ba.w = f2bf(va.w);
            bb.x = f2bf(vb.x); bb.y = f2bf(vb.y); bb.z = f2bf(vb.z); bb.w = f2bf(vb.w);
            int byte = lds_byte(r, c4 * 8, r);
            *(ushort4*)(As + byte) = ba;
            *(ushort4*)(Bs + byte) = bb;
        }
        __syncthreads();
#pragma unroll
        for (int ks = 0; ks < 2; ++ks) {
            s16x8 af[4], bf[4];
#pragma unroll
            for (int mi = 0; mi < 4; mi++) af[mi] = ldfrag(As, wm * 64 + mi * 16 + (lane & 15), ks, lane);
#pragma unroll
            for (int nj = 0; nj < 4; nj++) bf[nj] = ldfrag(Bs, wn * 64 + nj * 16 + (lane & 15), ks, lane);
#pragma unroll
            for (int mi = 0; mi < 4; mi++)
#pragma unroll
                for (int nj = 0; nj < 4; nj++)
                    acc[mi][nj] = mfma16(af[mi], bf[nj], acc[mi][nj]);
        }
        __syncthreads();
    }
#pragma unroll
    for (int mi = 0; mi < 4; mi++)
#pragma unroll
        for (int r = 0; r < 4; r++) {
            int row = wm * 64 + mi * 16 + (lane >> 4) * 4 + r;
            if (t0 + row < cnt) {
                int tok = toks[row];
                float w = rw_[row];
#pragma unroll
                for (int nj = 0; nj < 4; nj++) {
                    int col = d0 + wn * 64 + nj * 16 + (lane & 15);
                    atomicAdd(&out[(size_t)tok * DIMM + col], acc[mi][nj][r] * w);
                }
            }
        }
}

// ---------------------------------------------------------------- launch
extern "C" void kernel_launch(void* const* d_in, const int* in_sizes, int n_in,
                              void* d_out, int out_size, void* d_ws, size_t ws_size,
                              hipStream_t stream)
{
    const float* x      = (const float*)d_in[0];
    const float* cs     = (const float*)d_in[1];
    const float* sn     = (const float*)d_in[2];
    const float* w_na   = (const float*)d_in[3];
    const float* wq     = (const float*)d_in[4];
    const float* wk     = (const float*)d_in[5];
    const float* wv     = (const float*)d_in[6];
    const float* wo     = (const float*)d_in[7];
    const float* w_nf   = (const float*)d_in[8];
    const float* rw     = (const float*)d_in[9];
    const float* rb     = (const float*)d_in[10];
    const float* wg     = (const float*)d_in[11];
    const float* wu     = (const float*)d_in[12];
    const float* wd     = (const float*)d_in[13];
    float* out = (float*)d_out;

    float* wsf  = (float*)d_ws;
    float* xn   = wsf;                              // 2M
    float* qb   = wsf + (size_t)2 * 1024 * 1024;    // 2M
    float* kb   = wsf + (size_t)4 * 1024 * 1024;    // 512K
    float* vb   = kb + 512 * 1024;                  // 512K
    float* attn = wsf + (size_t)5 * 1024 * 1024;    // 2M
    float* xn2  = wsf + (size_t)7 * 1024 * 1024;    // 2M
    float* hbuf = wsf + (size_t)9 * 1024 * 1024;    // 8M
    float* tail = wsf + (size_t)17 * 1024 * 1024;
    int*   top_idx      = (int*)tail;               // 4096
    float* top_w        = tail + 4096;              // 4096
    int*   counts       = (int*)(tail + 8192);      // 8
    int*   offs         = (int*)(tail + 8192) + 8;  // 8
    int*   pos          = (int*)(tail + 8192) + 16; // 8
    int*   assign_token = (int*)(tail + 8192) + 32; // 4096
    float* assign_w     = tail + 8192 + 32 + 4096;  // 4096

    // 1. rmsnorm (attn)
    rmsnorm_kernel<<<N_TOK, 256, 0, stream>>>(x, w_na, xn);
    // 2. q/k/v projections (split-bf16 MFMA, fp32-grade — feeds routing)
    gemm_split<<<dim3(8, 16), 256, 0, stream>>>(xn, wq, qb, nullptr, N_TOK, 1024, 1024, 1024);
    gemm_split<<<dim3(2, 16), 256, 0, stream>>>(xn, wk, kb, nullptr, N_TOK, 256, 1024, 256);
    gemm_split<<<dim3(2, 16), 256, 0, stream>>>(xn, wv, vb, nullptr, N_TOK, 256, 1024, 256);
    // 3. RoPE
    rope_kernel<<<(N_TOK * NH * 32) / 256, 256, 0, stream>>>(qb, cs, sn, NH);
    rope_kernel<<<(N_TOK * NKV * 32) / 256, 256, 0, stream>>>(kb, cs, sn, NKV);
    // 4. attention (4 lanes per q-row, 512 blocks)
    attn_fwd<<<dim3(SEQ / 64, NH, 2), 256, 0, stream>>>(qb, kb, vb, attn);
    // 5. output projection + residual -> d_out holds x1 (split-bf16, fp32-grade)
    gemm_split<<<dim3(8, 16), 256, 0, stream>>>(attn, wo, out, x, N_TOK, 1024, 1024, 1024);
    // 6. rmsnorm (ffn)
    rmsnorm_kernel<<<N_TOK, 256, 0, stream>>>(out, w_nf, xn2);
    // 7-10. routing
    init_counts<<<1, 64, 0, stream>>>(counts, pos);
    router_kernel<<<N_TOK / 4, 256, 0, stream>>>(xn2, rw, rb, top_idx, top_w, counts);
    offsets_kernel<<<1, 64, 0, stream>>>(counts, offs);
    fill_kernel<<<N_TOK / 256, 256, 0, stream>>>(top_idx, top_w, offs, pos, assign_token, assign_w);
    // 11. gate/up + silu (MFMA bf16)
    moe_gateup<<<dim3(HID / 64, 16, NEXP), 256, 0, stream>>>(xn2, wg, wu, assign_token, offs, counts, hbuf);
    // 12. down proj + scatter-add into d_out (MFMA bf16)
    moe_down<<<dim3(DIMM / 128, 16, NEXP), 256, 0, stream>>>(hbuf, wd, assign_token, assign_w, offs, counts, out);
}

// Round 5
// 983.531 us; speedup vs baseline: 2.3742x; 1.2530x over previous
//
#include <hip/hip_runtime.h>
#include <math.h>

#define N_TOK   2048      // B*T
#define SEQ     1024
#define DIMM    1024
#define NH      16
#define NKV     4
#define HD      64
#define HID     2048
#define NEXP    8

typedef __attribute__((ext_vector_type(4))) float f32x4;
typedef __attribute__((ext_vector_type(8))) short s16x8;

__device__ __forceinline__ unsigned short f2bf(float f) {
    union { float f; unsigned u; } v; v.f = f;
    unsigned r = v.u + 0x7fffu + ((v.u >> 16) & 1u);
    return (unsigned short)(r >> 16);
}
__device__ __forceinline__ float bf2f(unsigned short h) {
    union { unsigned u; float f; } v; v.u = ((unsigned)h) << 16;
    return v.f;
}

__device__ __forceinline__ f32x4 mfma16(s16x8 a, s16x8 b, f32x4 c) {
    return __builtin_amdgcn_mfma_f32_16x16x32_bf16(a, b, c, 0, 0, 0);
}

// LDS tile row stride = 64 bf16 = 128 B; XOR-swizzle 16B slot with row&7 (T2)
__device__ __forceinline__ int lds_byte(int row, int byte_in_row, int swz_key) {
    return row * 128 + (byte_in_row ^ ((swz_key & 7) << 4));
}

// load a 16B MFMA fragment (8 bf16) for logical row `row`, k-slice ks (0/1)
__device__ __forceinline__ s16x8 ldfrag(const char* base, int row, int ks, int lane) {
    int b = lds_byte(row, ks * 64 + ((lane >> 4) * 16), row);
    return *(const s16x8*)(base + b);
}

// ---------------------------------------------------------------- rmsnorm
__global__ __launch_bounds__(256) void rmsnorm_kernel(const float* __restrict__ x,
    const float* __restrict__ w, float* __restrict__ out)
{
    int row = blockIdx.x;
    const float4* xr = reinterpret_cast<const float4*>(x + (size_t)row * DIMM);
    const float4* wr = reinterpret_cast<const float4*>(w);
    float4 v = xr[threadIdx.x];
    float ss = v.x*v.x + v.y*v.y + v.z*v.z + v.w*v.w;
#pragma unroll
    for (int off = 32; off; off >>= 1) ss += __shfl_xor(ss, off);
    __shared__ float red[4];
    int wid = threadIdx.x >> 6, lane = threadIdx.x & 63;
    if (lane == 0) red[wid] = ss;
    __syncthreads();
    float tot = red[0] + red[1] + red[2] + red[3];
    float inv = rsqrtf(tot * (1.0f/DIMM) + 1e-6f);
    float4 ww = wr[threadIdx.x];
    float4 o;
    o.x = ww.x * v.x * inv;
    o.y = ww.y * v.y * inv;
    o.z = ww.z * v.z * inv;
    o.w = ww.w * v.w * inv;
    reinterpret_cast<float4*>(out + (size_t)row * DIMM)[threadIdx.x] = o;
}

// ---------------------------------------------------------------- split-bf16 MFMA GEMM (fp32-grade accuracy)
// C[M,N] = A[M,K] @ B[N,K]^T (+R).  acc += Ah*Bh + Ah*Bl + Al*Bh
// BM=128, BN=128, BK=64, 256 thr = 4 waves (2x2), wave tile 64x64
__global__ __launch_bounds__(256) void gemm_split(const float* __restrict__ A,
    const float* __restrict__ B, float* __restrict__ C, const float* __restrict__ R,
    int M, int N, int K, int ldc)
{
    __shared__ __align__(16) char Ah[128 * 128];
    __shared__ __align__(16) char Al[128 * 128];
    __shared__ __align__(16) char Bh[128 * 128];
    __shared__ __align__(16) char Bl[128 * 128];
    int tid = threadIdx.x;
    int m0 = blockIdx.y * 128, n0 = blockIdx.x * 128;
    int lane = tid & 63, wv = tid >> 6;
    int wm = wv >> 1, wn = wv & 1;
    int c4 = tid & 15, r0 = tid >> 4;

    f32x4 acc[4][4];
#pragma unroll
    for (int i = 0; i < 4; i++)
#pragma unroll
        for (int j = 0; j < 4; j++) acc[i][j] = f32x4{0.f, 0.f, 0.f, 0.f};

    for (int k0 = 0; k0 < K; k0 += 64) {
#pragma unroll
        for (int i = 0; i < 8; ++i) {
            int r = r0 + i * 16;
            float4 va = *(const float4*)(A + (size_t)(m0 + r) * K + k0 + c4 * 4);
            float4 vb = *(const float4*)(B + (size_t)(n0 + r) * K + k0 + c4 * 4);
            ushort4 ah, al, bh, bl;
            ah.x = f2bf(va.x); ah.y = f2bf(va.y); ah.z = f2bf(va.z); ah.w = f2bf(va.w);
            al.x = f2bf(va.x - bf2f(ah.x)); al.y = f2bf(va.y - bf2f(ah.y));
            al.z = f2bf(va.z - bf2f(ah.z)); al.w = f2bf(va.w - bf2f(ah.w));
            bh.x = f2bf(vb.x); bh.y = f2bf(vb.y); bh.z = f2bf(vb.z); bh.w = f2bf(vb.w);
            bl.x = f2bf(vb.x - bf2f(bh.x)); bl.y = f2bf(vb.y - bf2f(bh.y));
            bl.z = f2bf(vb.z - bf2f(bh.z)); bl.w = f2bf(vb.w - bf2f(bh.w));
            int byte = lds_byte(r, c4 * 8, r);
            *(ushort4*)(Ah + byte) = ah;
            *(ushort4*)(Al + byte) = al;
            *(ushort4*)(Bh + byte) = bh;
            *(ushort4*)(Bl + byte) = bl;
        }
        __syncthreads();
#pragma unroll
        for (int ks = 0; ks < 2; ++ks) {
            s16x8 afh[4], afl[4], bfh[4], bfl[4];
#pragma unroll
            for (int mi = 0; mi < 4; mi++) {
                int row = wm * 64 + mi * 16 + (lane & 15);
                afh[mi] = ldfrag(Ah, row, ks, lane);
                afl[mi] = ldfrag(Al, row, ks, lane);
            }
#pragma unroll
            for (int nj = 0; nj < 4; nj++) {
                int row = wn * 64 + nj * 16 + (lane & 15);
                bfh[nj] = ldfrag(Bh, row, ks, lane);
                bfl[nj] = ldfrag(Bl, row, ks, lane);
            }
#pragma unroll
            for (int mi = 0; mi < 4; mi++)
#pragma unroll
                for (int nj = 0; nj < 4; nj++) {
                    acc[mi][nj] = mfma16(afl[mi], bfh[nj], acc[mi][nj]);
                    acc[mi][nj] = mfma16(afh[mi], bfl[nj], acc[mi][nj]);
                    acc[mi][nj] = mfma16(afh[mi], bfh[nj], acc[mi][nj]);
                }
        }
        __syncthreads();
    }
#pragma unroll
    for (int mi = 0; mi < 4; mi++)
#pragma unroll
        for (int nj = 0; nj < 4; nj++)
#pragma unroll
            for (int r = 0; r < 4; r++) {
                int m = m0 + wm * 64 + mi * 16 + (lane >> 4) * 4 + r;
                int n = n0 + wn * 64 + nj * 16 + (lane & 15);
                float v = acc[mi][nj][r];
                if (R) v += R[(size_t)m * ldc + n];
                C[(size_t)m * ldc + n] = v;
            }
}

// ---------------------------------------------------------------- RoPE (in place)
__global__ __launch_bounds__(256) void rope_kernel(float* __restrict__ buf,
    const float* __restrict__ cs, const float* __restrict__ sn, int nheads)
{
    int gid = blockIdx.x * 256 + threadIdx.x;
    int total = N_TOK * nheads * 32;
    if (gid >= total) return;
    int i = gid & 31;
    int h = (gid >> 5) % nheads;
    int n = gid / (32 * nheads);
    int t = n & (SEQ - 1);
    float* p = buf + (size_t)n * (nheads * HD) + h * HD + 2 * i;
    float xe = p[0], xo = p[1];
    float c = cs[t * 32 + i], s = sn[t * 32 + i];
    p[0] = xe * c - xo * s;
    p[1] = xe * s + xo * c;
}

// ---------------------------------------------------------------- V transpose: vb[N_TOK][256] -> vbt[256][N_TOK]
__global__ __launch_bounds__(256) void transpose_v(const float* __restrict__ vb,
    float* __restrict__ vbt)
{
    __shared__ float t[64][65];
    int bx = blockIdx.x;  // token tile (32)
    int by = blockIdx.y;  // dv tile (4)
    int tid = threadIdx.x;
    int c4 = tid & 15, r0 = tid >> 4;
#pragma unroll
    for (int i = 0; i < 4; i++) {
        int row = r0 + i * 16;   // token within tile
        float4 vv = *(const float4*)(vb + (size_t)(bx * 64 + row) * (NKV * HD) + by * 64 + c4 * 4);
        t[c4 * 4 + 0][row] = vv.x;
        t[c4 * 4 + 1][row] = vv.y;
        t[c4 * 4 + 2][row] = vv.z;
        t[c4 * 4 + 3][row] = vv.w;
    }
    __syncthreads();
#pragma unroll
    for (int i = 0; i < 4; i++) {
        int drow = r0 + i * 16;  // dv within tile
        float4 vv;
        vv.x = t[drow][c4 * 4 + 0];
        vv.y = t[drow][c4 * 4 + 1];
        vv.z = t[drow][c4 * 4 + 2];
        vv.w = t[drow][c4 * 4 + 3];
        *(float4*)(vbt + (size_t)(by * 64 + drow) * N_TOK + bx * 64 + c4 * 4) = vv;
    }
}

// ---------------------------------------------------------------- MFMA flash attention (split-bf16, fp32-grade)
// block = (qt, h, b); 4 waves, wave w owns q rows qt*64 + w*16 .. +16
__global__ __launch_bounds__(256) void attn_mfma(const float* __restrict__ q,
    const float* __restrict__ k, const float* __restrict__ vt, float* __restrict__ out)
{
    int b = blockIdx.z, h = blockIdx.y;
    int qt = (gridDim.x - 1) - blockIdx.x;   // heavy q-tiles dispatch first
    int kvh = h >> 2;
    int tid = threadIdx.x;
    int lane = tid & 63, wv = tid >> 6;
    int q0 = qt * 64;
    int c4 = tid & 15, r0 = tid >> 4;

    __shared__ __align__(16) char Qh[64 * 128], Ql[64 * 128];
    __shared__ __align__(16) char Kh[64 * 128], Kl[64 * 128];
    __shared__ __align__(16) char Vh[64 * 128], Vl[64 * 128];
    __shared__ __align__(16) char Ph[4][16 * 128], Pl[4][16 * 128];

    // ---- stage Q (once)
#pragma unroll
    for (int i = 0; i < 4; i++) {
        int row = r0 + i * 16;
        float4 vq = *(const float4*)(q + (size_t)(b * SEQ + q0 + row) * (NH * HD) + h * HD + c4 * 4);
        ushort4 hh, ll;
        hh.x = f2bf(vq.x); hh.y = f2bf(vq.y); hh.z = f2bf(vq.z); hh.w = f2bf(vq.w);
        ll.x = f2bf(vq.x - bf2f(hh.x)); ll.y = f2bf(vq.y - bf2f(hh.y));
        ll.z = f2bf(vq.z - bf2f(hh.z)); ll.w = f2bf(vq.w - bf2f(hh.w));
        int byte = lds_byte(row, c4 * 8, row);
        *(ushort4*)(Qh + byte) = hh;
        *(ushort4*)(Ql + byte) = ll;
    }
    __syncthreads();

    // Q fragments in registers (A-operand, wave's 16 rows)
    s16x8 aQh[2], aQl[2];
#pragma unroll
    for (int ks = 0; ks < 2; ks++) {
        aQh[ks] = ldfrag(Qh, wv * 16 + (lane & 15), ks, lane);
        aQl[ks] = ldfrag(Ql, wv * 16 + (lane & 15), ks, lane);
    }

    // online-softmax state (per lane: 4 rows)
    float m_run[4], l_run[4];
    f32x4 acc_o[4];
#pragma unroll
    for (int r = 0; r < 4; r++) { m_run[r] = -1e30f; l_run[r] = 0.f; }
#pragma unroll
    for (int nj = 0; nj < 4; nj++) acc_o[nj] = f32x4{0.f, 0.f, 0.f, 0.f};

    for (int kt = 0; kt <= qt; kt++) {
        int kbase = kt * 64;
        __syncthreads();
        // ---- stage K tile (rows=key) and V^T tile (rows=dv)
#pragma unroll
        for (int i = 0; i < 4; i++) {
            int row = r0 + i * 16;
            float4 vk = *(const float4*)(k + (size_t)(b * SEQ + kbase + row) * (NKV * HD) + kvh * HD + c4 * 4);
            float4 vv = *(const float4*)(vt + (size_t)(kvh * HD + row) * N_TOK + b * SEQ + kbase + c4 * 4);
            ushort4 kh, kl, vh, vl;
            kh.x = f2bf(vk.x); kh.y = f2bf(vk.y); kh.z = f2bf(vk.z); kh.w = f2bf(vk.w);
            kl.x = f2bf(vk.x - bf2f(kh.x)); kl.y = f2bf(vk.y - bf2f(kh.y));
            kl.z = f2bf(vk.z - bf2f(kh.z)); kl.w = f2bf(vk.w - bf2f(kh.w));
            vh.x = f2bf(vv.x); vh.y = f2bf(vv.y); vh.z = f2bf(vv.z); vh.w = f2bf(vv.w);
            vl.x = f2bf(vv.x - bf2f(vh.x)); vl.y = f2bf(vv.y - bf2f(vh.y));
            vl.z = f2bf(vv.z - bf2f(vh.z)); vl.w = f2bf(vv.w - bf2f(vh.w));
            int byte = lds_byte(row, c4 * 8, row);
            *(ushort4*)(Kh + byte) = kh;
            *(ushort4*)(Kl + byte) = kl;
            *(ushort4*)(Vh + byte) = vh;
            *(ushort4*)(Vl + byte) = vl;
        }
        __syncthreads();

        // ---- S = Q @ K^T (split, fp32-grade)
        f32x4 sacc[4];
#pragma unroll
        for (int nj = 0; nj < 4; nj++) sacc[nj] = f32x4{0.f, 0.f, 0.f, 0.f};
#pragma unroll
        for (int ks = 0; ks < 2; ks++) {
#pragma unroll
            for (int nj = 0; nj < 4; nj++) {
                s16x8 bKh = ldfrag(Kh, nj * 16 + (lane & 15), ks, lane);
                s16x8 bKl = ldfrag(Kl, nj * 16 + (lane & 15), ks, lane);
                sacc[nj] = mfma16(aQl[ks], bKh, sacc[nj]);
                sacc[nj] = mfma16(aQh[ks], bKl, sacc[nj]);
                sacc[nj] = mfma16(aQh[ks], bKh, sacc[nj]);
            }
        }

        // ---- scale + causal mask (diagonal tile only)
        float sv[4][4];   // [nj][r]
#pragma unroll
        for (int nj = 0; nj < 4; nj++)
#pragma unroll
            for (int r = 0; r < 4; r++) {
                float s = sacc[nj][r] * 0.125f;
                if (kt == qt) {
                    int row_loc = wv * 16 + (lane >> 4) * 4 + r;
                    int col_loc = nj * 16 + (lane & 15);
                    if (col_loc > row_loc) s = -1e30f;
                }
                sv[nj][r] = s;
            }

        // ---- online softmax update (per row r)
        float p[4][4];
#pragma unroll
        for (int r = 0; r < 4; r++) {
            float mx = fmaxf(fmaxf(sv[0][r], sv[1][r]), fmaxf(sv[2][r], sv[3][r]));
            mx = fmaxf(mx, __shfl_xor(mx, 1));
            mx = fmaxf(mx, __shfl_xor(mx, 2));
            mx = fmaxf(mx, __shfl_xor(mx, 4));
            mx = fmaxf(mx, __shfl_xor(mx, 8));
            float m_new = fmaxf(m_run[r], mx);
            float corr = __expf(m_run[r] - m_new);
            float ps = 0.f;
#pragma unroll
            for (int nj = 0; nj < 4; nj++) {
                float pv = __expf(sv[nj][r] - m_new);
                p[nj][r] = pv;
                ps += pv;
            }
            ps += __shfl_xor(ps, 1);
            ps += __shfl_xor(ps, 2);
            ps += __shfl_xor(ps, 4);
            ps += __shfl_xor(ps, 8);
            l_run[r] = l_run[r] * corr + ps;
            m_run[r] = m_new;
#pragma unroll
            for (int nj = 0; nj < 4; nj++) acc_o[nj][r] *= corr;
        }

        // ---- write P (split) to wave-private LDS in A-source layout
        char* phb = Ph[wv];
        char* plb = Pl[wv];
#pragma unroll
        for (int nj = 0; nj < 4; nj++)
#pragma unroll
            for (int r = 0; r < 4; r++) {
                int row = (lane >> 4) * 4 + r;
                int col = nj * 16 + (lane & 15);
                unsigned short hh = f2bf(p[nj][r]);
                unsigned short ll = f2bf(p[nj][r] - bf2f(hh));
                int byte = lds_byte(row, col * 2, row);
                *(unsigned short*)(phb + byte) = hh;
                *(unsigned short*)(plb + byte) = ll;
            }

        // ---- O += P @ V (split)
#pragma unroll
        for (int ks = 0; ks < 2; ks++) {
            s16x8 aPh = ldfrag(phb, lane & 15, ks, lane);
            s16x8 aPl = ldfrag(plb, lane & 15, ks, lane);
#pragma unroll
            for (int nj = 0; nj < 4; nj++) {
                s16x8 bVh = ldfrag(Vh, nj * 16 + (lane & 15), ks, lane);
                s16x8 bVl = ldfrag(Vl, nj * 16 + (lane & 15), ks, lane);
                acc_o[nj] = mfma16(aPl, bVh, acc_o[nj]);
                acc_o[nj] = mfma16(aPh, bVl, acc_o[nj]);
                acc_o[nj] = mfma16(aPh, bVh, acc_o[nj]);
            }
        }
    }

    // ---- epilogue: O / l
#pragma unroll
    for (int r = 0; r < 4; r++) {
        int row_glob = q0 + wv * 16 + (lane >> 4) * 4 + r;
        float inv = 1.f / l_run[r];
#pragma unroll
        for (int nj = 0; nj < 4; nj++) {
            int dv = nj * 16 + (lane & 15);
            out[(size_t)(b * SEQ + row_glob) * (NH * HD) + h * HD + dv] = acc_o[nj][r] * inv;
        }
    }
}

// ---------------------------------------------------------------- routing
__global__ void init_counts(int* counts, int* pos)
{
    int t = threadIdx.x;
    if (t < NEXP) { counts[t] = 0; pos[t] = 0; }
}

__global__ __launch_bounds__(256) void router_kernel(const float* __restrict__ xn2,
    const float* __restrict__ rw, const float* __restrict__ rb,
    int* __restrict__ top_idx, float* __restrict__ top_w, int* __restrict__ counts)
{
    int wid = threadIdx.x >> 6, lane = threadIdx.x & 63;
    int n = blockIdx.x * 4 + wid;
    if (n >= N_TOK) return;
    const float* xr = xn2 + (size_t)n * DIMM;
    float lg[NEXP];
#pragma unroll
    for (int e = 0; e < NEXP; e++) {
        float p = 0.f;
        for (int d = lane; d < DIMM; d += 64) p += xr[d] * rw[e * DIMM + d];
#pragma unroll
        for (int off = 32; off; off >>= 1) p += __shfl_xor(p, off);
        lg[e] = p + rb[e];
    }
    if (lane == 0) {
        float m = lg[0];
#pragma unroll
        for (int e = 1; e < NEXP; e++) m = fmaxf(m, lg[e]);
        float pe[NEXP], s = 0.f;
#pragma unroll
        for (int e = 0; e < NEXP; e++) { pe[e] = __expf(lg[e] - m); s += pe[e]; }
        int i1 = 0; float v1 = pe[0];
#pragma unroll
        for (int e = 1; e < NEXP; e++) if (pe[e] > v1) { v1 = pe[e]; i1 = e; }
        int i2 = -1; float v2 = -1.f;
#pragma unroll
        for (int e = 0; e < NEXP; e++) if (e != i1 && pe[e] > v2) { v2 = pe[e]; i2 = e; }
        v1 /= s; v2 /= s;
        float den = v1 + v2 + 1e-9f;
        top_idx[2 * n] = i1; top_idx[2 * n + 1] = i2;
        top_w[2 * n] = v1 / den; top_w[2 * n + 1] = v2 / den;
        atomicAdd(&counts[i1], 1);
        atomicAdd(&counts[i2], 1);
    }
}

__global__ void offsets_kernel(const int* counts, int* offs)
{
    if (threadIdx.x == 0) {
        int s = 0;
        for (int e = 0; e < NEXP; e++) { offs[e] = s; s += counts[e]; }
    }
}

__global__ __launch_bounds__(256) void fill_kernel(const int* __restrict__ top_idx,
    const float* __restrict__ top_w, const int* __restrict__ offs, int* __restrict__ pos,
    int* __restrict__ assign_token, float* __restrict__ assign_w)
{
    int n = blockIdx.x * 256 + threadIdx.x;
    if (n >= N_TOK) return;
#pragma unroll
    for (int s = 0; s < 2; s++) {
        int e = top_idx[2 * n + s];
        int p = atomicAdd(&pos[e], 1);
        int r = offs[e] + p;
        assign_token[r] = n;
        assign_w[r] = top_w[2 * n + s];
    }
}

// ---------------------------------------------------------------- MoE gate/up, MFMA, fused silu
// BM=128 tokens, BN=64 cols of BOTH gate and up, BK=64. 4 waves 2x2, wave tile 64x32 (per matrix)
__global__ __launch_bounds__(256) void moe_gateup(const float* __restrict__ xn2,
    const float* __restrict__ wg, const float* __restrict__ wu,
    const int* __restrict__ assign_token, const int* __restrict__ offs,
    const int* __restrict__ counts, float* __restrict__ hbuf)
{
    int e = blockIdx.z;
    int cnt = counts[e];
    int t0 = blockIdx.y * 128;
    if (t0 >= cnt) return;
    int base = offs[e];
    int h0 = blockIdx.x * 64;
    __shared__ __align__(16) char As[128 * 128];
    __shared__ __align__(16) char Gs[64 * 128];
    __shared__ __align__(16) char Us[64 * 128];
    __shared__ int toks[128];
    int tid = threadIdx.x;
    if (tid < 128) {
        int a = t0 + tid;
        toks[tid] = (a < cnt) ? assign_token[base + a] : -1;
    }
    __syncthreads();
    int lane = tid & 63, wv = tid >> 6;
    int wm = wv >> 1, wn = wv & 1;
    int c4 = tid & 15, r0 = tid >> 4;

    f32x4 accg[4][2], accu[4][2];
#pragma unroll
    for (int i = 0; i < 4; i++)
#pragma unroll
        for (int j = 0; j < 2; j++) { accg[i][j] = f32x4{0,0,0,0}; accu[i][j] = f32x4{0,0,0,0}; }

    const float* wge = wg + (size_t)e * HID * DIMM;
    const float* wue = wu + (size_t)e * HID * DIMM;

    for (int k0 = 0; k0 < DIMM; k0 += 64) {
        // A tile: 128 rows (gathered tokens)
#pragma unroll
        for (int i = 0; i < 8; ++i) {
            int r = r0 + i * 16;
            int tok = toks[r];
            float4 va = (tok >= 0) ? *(const float4*)(xn2 + (size_t)tok * DIMM + k0 + c4 * 4)
                                   : float4{0.f, 0.f, 0.f, 0.f};
            ushort4 ba;
            ba.x = f2bf(va.x); ba.y = f2bf(va.y); ba.z = f2bf(va.z); ba.w = f2bf(va.w);
            *(ushort4*)(As + lds_byte(r, c4 * 8, r)) = ba;
        }
        // B tiles: 64 rows each of gate and up
#pragma unroll
        for (int i = 0; i < 4; ++i) {
            int r = r0 + i * 16;
            float4 vg = *(const float4*)(wge + (size_t)(h0 + r) * DIMM + k0 + c4 * 4);
            float4 vu = *(const float4*)(wue + (size_t)(h0 + r) * DIMM + k0 + c4 * 4);
            ushort4 bg, bu;
            bg.x = f2bf(vg.x); bg.y = f2bf(vg.y); bg.z = f2bf(vg.z); bg.w = f2bf(vg.w);
            bu.x = f2bf(vu.x); bu.y = f2bf(vu.y); bu.z = f2bf(vu.z); bu.w = f2bf(vu.w);
            int byte = lds_byte(r, c4 * 8, r);
            *(ushort4*)(Gs + byte) = bg;
            *(ushort4*)(Us + byte) = bu;
        }
        __syncthreads();
#pragma unroll
        for (int ks = 0; ks < 2; ++ks) {
            s16x8 af[4], gf[2], uf[2];
#pragma unroll
            for (int mi = 0; mi < 4; mi++) af[mi] = ldfrag(As, wm * 64 + mi * 16 + (lane & 15), ks, lane);
#pragma unroll
            for (int nj = 0; nj < 2; nj++) {
                int row = wn * 32 + nj * 16 + (lane & 15);
                gf[nj] = ldfrag(Gs, row, ks, lane);
                uf[nj] = ldfrag(Us, row, ks, lane);
            }
#pragma unroll
            for (int mi = 0; mi < 4; mi++)
#pragma unroll
                for (int nj = 0; nj < 2; nj++) {
                    accg[mi][nj] = mfma16(af[mi], gf[nj], accg[mi][nj]);
                    accu[mi][nj] = mfma16(af[mi], uf[nj], accu[mi][nj]);
                }
        }
        __syncthreads();
    }
#pragma unroll
    for (int mi = 0; mi < 4; mi++)
#pragma unroll
        for (int nj = 0; nj < 2; nj++)
#pragma unroll
            for (int r = 0; r < 4; r++) {
                int row = wm * 64 + mi * 16 + (lane >> 4) * 4 + r;
                if (t0 + row < cnt) {
                    int col = wn * 32 + nj * 16 + (lane & 15);
                    float g = accg[mi][nj][r], u = accu[mi][nj][r];
                    float hh = (g / (1.f + __expf(-g))) * u;
                    hbuf[(size_t)(base + t0 + row) * HID + h0 + col] = hh;
                }
            }
}

// ---------------------------------------------------------------- MoE down proj, MFMA, weighted atomic scatter
// BM=128 slots, BN=128 out-dims, BK=64
__global__ __launch_bounds__(256) void moe_down(const float* __restrict__ hbuf,
    const float* __restrict__ wd, const int* __restrict__ assign_token,
    const float* __restrict__ assign_w, const int* __restrict__ offs,
    const int* __restrict__ counts, float* __restrict__ out)
{
    int e = blockIdx.z;
    int cnt = counts[e];
    int t0 = blockIdx.y * 128;
    if (t0 >= cnt) return;
    int base = offs[e];
    int d0 = blockIdx.x * 128;
    __shared__ __align__(16) char As[128 * 128];
    __shared__ __align__(16) char Bs[128 * 128];
    __shared__ int toks[128];
    __shared__ float rw_[128];
    int tid = threadIdx.x;
    if (tid < 128) {
        int a = t0 + tid;
        toks[tid] = (a < cnt) ? assign_token[base + a] : -1;
        rw_[tid] = (a < cnt) ? assign_w[base + a] : 0.f;
    }
    __syncthreads();
    int lane = tid & 63, wv = tid >> 6;
    int wm = wv >> 1, wn = wv & 1;
    int c4 = tid & 15, r0 = tid >> 4;

    f32x4 acc[4][4];
#pragma unroll
    for (int i = 0; i < 4; i++)
#pragma unroll
        for (int j = 0; j < 4; j++) acc[i][j] = f32x4{0,0,0,0};

    const float* wde = wd + (size_t)e * DIMM * HID;

    for (int k0 = 0; k0 < HID; k0 += 64) {
#pragma unroll
        for (int i = 0; i < 8; ++i) {
            int r = r0 + i * 16;
            float4 va = (t0 + r < cnt) ? *(const float4*)(hbuf + (size_t)(base + t0 + r) * HID + k0 + c4 * 4)
                                       : float4{0.f, 0.f, 0.f, 0.f};
            float4 vb = *(const float4*)(wde + (size_t)(d0 + r) * HID + k0 + c4 * 4);
            ushort4 ba, bb;
            ba.x = f2bf(va.x); ba.y = f2bf(va.y); ba.z = f2bf(va.z); ba.w = f2bf(va.w);
            bb.x = f2bf(vb.x); bb.y = f2bf(vb.y); bb.z = f2bf(vb.z); bb.w = f2bf(vb.w);
            int byte = lds_byte(r, c4 * 8, r);
            *(ushort4*)(As + byte) = ba;
            *(ushort4*)(Bs + byte) = bb;
        }
        __syncthreads();
#pragma unroll
        for (int ks = 0; ks < 2; ++ks) {
            s16x8 af[4], bf[4];
#pragma unroll
            for (int mi = 0; mi < 4; mi++) af[mi] = ldfrag(As, wm * 64 + mi * 16 + (lane & 15), ks, lane);
#pragma unroll
            for (int nj = 0; nj < 4; nj++) bf[nj] = ldfrag(Bs, wn * 64 + nj * 16 + (lane & 15), ks, lane);
#pragma unroll
            for (int mi = 0; mi < 4; mi++)
#pragma unroll
                for (int nj = 0; nj < 4; nj++)
                    acc[mi][nj] = mfma16(af[mi], bf[nj], acc[mi][nj]);
        }
        __syncthreads();
    }
#pragma unroll
    for (int mi = 0; mi < 4; mi++)
#pragma unroll
        for (int r = 0; r < 4; r++) {
            int row = wm * 64 + mi * 16 + (lane >> 4) * 4 + r;
            if (t0 + row < cnt) {
                int tok = toks[row];
                float w = rw_[row];
#pragma unroll
                for (int nj = 0; nj < 4; nj++) {
                    int col = d0 + wn * 64 + nj * 16 + (lane & 15);
                    atomicAdd(&out[(size_t)tok * DIMM + col], acc[mi][nj][r] * w);
                }
            }
        }
}

// ---------------------------------------------------------------- launch
extern "C" void kernel_launch(void* const* d_in, const int* in_sizes, int n_in,
                              void* d_out, int out_size, void* d_ws, size_t ws_size,
                              hipStream_t stream)
{
    const float* x      = (const float*)d_in[0];
    const float* cs     = (const float*)d_in[1];
    const float* sn     = (const float*)d_in[2];
    const float* w_na   = (const float*)d_in[3];
    const float* wq     = (const float*)d_in[4];
    const float* wk     = (const float*)d_in[5];
    const float* wv     = (const float*)d_in[6];
    const float* wo     = (const float*)d_in[7];
    const float* w_nf   = (const float*)d_in[8];
    const float* rw     = (const float*)d_in[9];
    const float* rb     = (const float*)d_in[10];
    const float* wg     = (const float*)d_in[11];
    const float* wu     = (const float*)d_in[12];
    const float* wd     = (const float*)d_in[13];
    float* out = (float*)d_out;

    float* wsf  = (float*)d_ws;
    float* xn   = wsf;                              // 2M
    float* qb   = wsf + (size_t)2 * 1024 * 1024;    // 2M
    float* kb   = wsf + (size_t)4 * 1024 * 1024;    // 512K
    float* vb   = kb + 512 * 1024;                  // 512K
    float* attn = wsf + (size_t)5 * 1024 * 1024;    // 2M
    float* xn2  = wsf + (size_t)7 * 1024 * 1024;    // 2M
    float* hbuf = wsf + (size_t)9 * 1024 * 1024;    // 8M
    float* vbt  = hbuf;                             // reuse: consumed before moe_gateup writes hbuf
    float* tail = wsf + (size_t)17 * 1024 * 1024;
    int*   top_idx      = (int*)tail;               // 4096
    float* top_w        = tail + 4096;              // 4096
    int*   counts       = (int*)(tail + 8192);      // 8
    int*   offs         = (int*)(tail + 8192) + 8;  // 8
    int*   pos          = (int*)(tail + 8192) + 16; // 8
    int*   assign_token = (int*)(tail + 8192) + 32; // 4096
    float* assign_w     = tail + 8192 + 32 + 4096;  // 4096

    // 1. rmsnorm (attn)
    rmsnorm_kernel<<<N_TOK, 256, 0, stream>>>(x, w_na, xn);
    // 2. q/k/v projections (split-bf16 MFMA, fp32-grade — feeds routing)
    gemm_split<<<dim3(8, 16), 256, 0, stream>>>(xn, wq, qb, nullptr, N_TOK, 1024, 1024, 1024);
    gemm_split<<<dim3(2, 16), 256, 0, stream>>>(xn, wk, kb, nullptr, N_TOK, 256, 1024, 256);
    gemm_split<<<dim3(2, 16), 256, 0, stream>>>(xn, wv, vb, nullptr, N_TOK, 256, 1024, 256);
    // 3. RoPE on q/k; transpose v
    rope_kernel<<<(N_TOK * NH * 32) / 256, 256, 0, stream>>>(qb, cs, sn, NH);
    rope_kernel<<<(N_TOK * NKV * 32) / 256, 256, 0, stream>>>(kb, cs, sn, NKV);
    transpose_v<<<dim3(N_TOK / 64, (NKV * HD) / 64), 256, 0, stream>>>(vb, vbt);
    // 4. attention (MFMA flash, split-bf16)
    attn_mfma<<<dim3(SEQ / 64, NH, 2), 256, 0, stream>>>(qb, kb, vbt, attn);
    // 5. output projection + residual -> d_out holds x1 (split-bf16, fp32-grade)
    gemm_split<<<dim3(8, 16), 256, 0, stream>>>(attn, wo, out, x, N_TOK, 1024, 1024, 1024);
    // 6. rmsnorm (ffn)
    rmsnorm_kernel<<<N_TOK, 256, 0, stream>>>(out, w_nf, xn2);
    // 7-10. routing
    init_counts<<<1, 64, 0, stream>>>(counts, pos);
    router_kernel<<<N_TOK / 4, 256, 0, stream>>>(xn2, rw, rb, top_idx, top_w, counts);
    offsets_kernel<<<1, 64, 0, stream>>>(counts, offs);
    fill_kernel<<<N_TOK / 256, 256, 0, stream>>>(top_idx, top_w, offs, pos, assign_token, assign_w);
    // 11. gate/up + silu (MFMA bf16)
    moe_gateup<<<dim3(HID / 64, 16, NEXP), 256, 0, stream>>>(xn2, wg, wu, assign_token, offs, counts, hbuf);
    // 12. down proj + scatter-add into d_out (MFMA bf16)
    moe_down<<<dim3(DIMM / 128, 16, NEXP), 256, 0, stream>>>(hbuf, wd, assign_token, assign_w, offs, counts, out);
}

// Round 6
// 873.938 us; speedup vs baseline: 2.6719x; 1.1254x over previous
//
#include <hip/hip_runtime.h>
#include <math.h>

#define N_TOK   2048      // B*T
#define SEQ     1024
#define DIMM    1024
#define NH      16
#define NKV     4
#define HD      64
#define HID     2048
#define NEXP    8

typedef __attribute__((ext_vector_type(4))) float f32x4;
typedef __attribute__((ext_vector_type(8))) short s16x8;
typedef unsigned short u16;

__device__ __forceinline__ u16 f2bf(float f) {
    union { float f; unsigned u; } v; v.f = f;
    unsigned r = v.u + 0x7fffu + ((v.u >> 16) & 1u);
    return (u16)(r >> 16);
}
__device__ __forceinline__ float bf2f(u16 h) {
    union { unsigned u; float f; } v; v.u = ((unsigned)h) << 16;
    return v.f;
}

__device__ __forceinline__ f32x4 mfma16(s16x8 a, s16x8 b, f32x4 c) {
    return __builtin_amdgcn_mfma_f32_16x16x32_bf16(a, b, c, 0, 0, 0);
}

// LDS tile row stride = 64 bf16 = 128 B; XOR-swizzle 16B slot with row&7 (T2)
__device__ __forceinline__ int lds_byte(int row, int byte_in_row, int swz_key) {
    return row * 128 + (byte_in_row ^ ((swz_key & 7) << 4));
}

// load a 16B MFMA fragment (8 bf16) for logical row `row`, k-slice ks (0/1)
__device__ __forceinline__ s16x8 ldfrag(const char* base, int row, int ks, int lane) {
    int b = lds_byte(row, ks * 64 + ((lane >> 4) * 16), row);
    return *(const s16x8*)(base + b);
}

// async 16B global -> LDS (wave-uniform LDS base + lane*16)
__device__ __forceinline__ void gload16(const void* g, void* l) {
    __builtin_amdgcn_global_load_lds(
        (const __attribute__((address_space(1))) void*)g,
        (__attribute__((address_space(3))) void*)l, 16, 0, 0);
}

// ---------------------------------------------------------------- fp32 -> bf16 bulk convert
__global__ __launch_bounds__(256) void cvt_bf16(const float* __restrict__ in,
    u16* __restrict__ out, int n4)
{
    int i = blockIdx.x * 256 + threadIdx.x;
    int stride = gridDim.x * 256;
    for (; i < n4; i += stride) {
        float4 v = reinterpret_cast<const float4*>(in)[i];
        ushort4 o;
        o.x = f2bf(v.x); o.y = f2bf(v.y); o.z = f2bf(v.z); o.w = f2bf(v.w);
        reinterpret_cast<ushort4*>(out)[i] = o;
    }
}

// ---------------------------------------------------------------- rmsnorm (fp32 out)
__global__ __launch_bounds__(256) void rmsnorm_kernel(const float* __restrict__ x,
    const float* __restrict__ w, float* __restrict__ out)
{
    int row = blockIdx.x;
    const float4* xr = reinterpret_cast<const float4*>(x + (size_t)row * DIMM);
    const float4* wr = reinterpret_cast<const float4*>(w);
    float4 v = xr[threadIdx.x];
    float ss = v.x*v.x + v.y*v.y + v.z*v.z + v.w*v.w;
#pragma unroll
    for (int off = 32; off; off >>= 1) ss += __shfl_xor(ss, off);
    __shared__ float red[4];
    int wid = threadIdx.x >> 6, lane = threadIdx.x & 63;
    if (lane == 0) red[wid] = ss;
    __syncthreads();
    float tot = red[0] + red[1] + red[2] + red[3];
    float inv = rsqrtf(tot * (1.0f/DIMM) + 1e-6f);
    float4 ww = wr[threadIdx.x];
    float4 o;
    o.x = ww.x * v.x * inv;
    o.y = ww.y * v.y * inv;
    o.z = ww.z * v.z * inv;
    o.w = ww.w * v.w * inv;
    reinterpret_cast<float4*>(out + (size_t)row * DIMM)[threadIdx.x] = o;
}

// ---------------------------------------------------------------- rmsnorm (fp32 + bf16 out)
__global__ __launch_bounds__(256) void rmsnorm_dual(const float* __restrict__ x,
    const float* __restrict__ w, float* __restrict__ out, u16* __restrict__ outb)
{
    int row = blockIdx.x;
    const float4* xr = reinterpret_cast<const float4*>(x + (size_t)row * DIMM);
    const float4* wr = reinterpret_cast<const float4*>(w);
    float4 v = xr[threadIdx.x];
    float ss = v.x*v.x + v.y*v.y + v.z*v.z + v.w*v.w;
#pragma unroll
    for (int off = 32; off; off >>= 1) ss += __shfl_xor(ss, off);
    __shared__ float red[4];
    int wid = threadIdx.x >> 6, lane = threadIdx.x & 63;
    if (lane == 0) red[wid] = ss;
    __syncthreads();
    float tot = red[0] + red[1] + red[2] + red[3];
    float inv = rsqrtf(tot * (1.0f/DIMM) + 1e-6f);
    float4 ww = wr[threadIdx.x];
    float4 o;
    o.x = ww.x * v.x * inv;
    o.y = ww.y * v.y * inv;
    o.z = ww.z * v.z * inv;
    o.w = ww.w * v.w * inv;
    reinterpret_cast<float4*>(out + (size_t)row * DIMM)[threadIdx.x] = o;
    ushort4 ob;
    ob.x = f2bf(o.x); ob.y = f2bf(o.y); ob.z = f2bf(o.z); ob.w = f2bf(o.w);
    reinterpret_cast<ushort4*>(outb + (size_t)row * DIMM)[threadIdx.x] = ob;
}

// ---------------------------------------------------------------- split-bf16 MFMA GEMM (fp32-grade accuracy)
// C[M,N] = A[M,K] @ B[N,K]^T (+R).  acc += Ah*Bh + Ah*Bl + Al*Bh
__global__ __launch_bounds__(256) void gemm_split(const float* __restrict__ A,
    const float* __restrict__ B, float* __restrict__ C, const float* __restrict__ R,
    int M, int N, int K, int ldc)
{
    __shared__ __align__(16) char Ah[128 * 128];
    __shared__ __align__(16) char Al[128 * 128];
    __shared__ __align__(16) char Bh[128 * 128];
    __shared__ __align__(16) char Bl[128 * 128];
    int tid = threadIdx.x;
    int m0 = blockIdx.y * 128, n0 = blockIdx.x * 128;
    int lane = tid & 63, wv = tid >> 6;
    int wm = wv >> 1, wn = wv & 1;
    int c4 = tid & 15, r0 = tid >> 4;

    f32x4 acc[4][4];
#pragma unroll
    for (int i = 0; i < 4; i++)
#pragma unroll
        for (int j = 0; j < 4; j++) acc[i][j] = f32x4{0.f, 0.f, 0.f, 0.f};

    for (int k0 = 0; k0 < K; k0 += 64) {
#pragma unroll
        for (int i = 0; i < 8; ++i) {
            int r = r0 + i * 16;
            float4 va = *(const float4*)(A + (size_t)(m0 + r) * K + k0 + c4 * 4);
            float4 vb = *(const float4*)(B + (size_t)(n0 + r) * K + k0 + c4 * 4);
            ushort4 ah, al, bh, bl;
            ah.x = f2bf(va.x); ah.y = f2bf(va.y); ah.z = f2bf(va.z); ah.w = f2bf(va.w);
            al.x = f2bf(va.x - bf2f(ah.x)); al.y = f2bf(va.y - bf2f(ah.y));
            al.z = f2bf(va.z - bf2f(ah.z)); al.w = f2bf(va.w - bf2f(ah.w));
            bh.x = f2bf(vb.x); bh.y = f2bf(vb.y); bh.z = f2bf(vb.z); bh.w = f2bf(vb.w);
            bl.x = f2bf(vb.x - bf2f(bh.x)); bl.y = f2bf(vb.y - bf2f(bh.y));
            bl.z = f2bf(vb.z - bf2f(bh.z)); bl.w = f2bf(vb.w - bf2f(bh.w));
            int byte = lds_byte(r, c4 * 8, r);
            *(ushort4*)(Ah + byte) = ah;
            *(ushort4*)(Al + byte) = al;
            *(ushort4*)(Bh + byte) = bh;
            *(ushort4*)(Bl + byte) = bl;
        }
        __syncthreads();
#pragma unroll
        for (int ks = 0; ks < 2; ++ks) {
            s16x8 afh[4], afl[4], bfh[4], bfl[4];
#pragma unroll
            for (int mi = 0; mi < 4; mi++) {
                int row = wm * 64 + mi * 16 + (lane & 15);
                afh[mi] = ldfrag(Ah, row, ks, lane);
                afl[mi] = ldfrag(Al, row, ks, lane);
            }
#pragma unroll
            for (int nj = 0; nj < 4; nj++) {
                int row = wn * 64 + nj * 16 + (lane & 15);
                bfh[nj] = ldfrag(Bh, row, ks, lane);
                bfl[nj] = ldfrag(Bl, row, ks, lane);
            }
#pragma unroll
            for (int mi = 0; mi < 4; mi++)
#pragma unroll
                for (int nj = 0; nj < 4; nj++) {
                    acc[mi][nj] = mfma16(afl[mi], bfh[nj], acc[mi][nj]);
                    acc[mi][nj] = mfma16(afh[mi], bfl[nj], acc[mi][nj]);
                    acc[mi][nj] = mfma16(afh[mi], bfh[nj], acc[mi][nj]);
                }
        }
        __syncthreads();
    }
#pragma unroll
    for (int mi = 0; mi < 4; mi++)
#pragma unroll
        for (int nj = 0; nj < 4; nj++)
#pragma unroll
            for (int r = 0; r < 4; r++) {
                int m = m0 + wm * 64 + mi * 16 + (lane >> 4) * 4 + r;
                int n = n0 + wn * 64 + nj * 16 + (lane & 15);
                float v = acc[mi][nj][r];
                if (R) v += R[(size_t)m * ldc + n];
                C[(size_t)m * ldc + n] = v;
            }
}

// ---------------------------------------------------------------- RoPE (in place)
__global__ __launch_bounds__(256) void rope_kernel(float* __restrict__ buf,
    const float* __restrict__ cs, const float* __restrict__ sn, int nheads)
{
    int gid = blockIdx.x * 256 + threadIdx.x;
    int total = N_TOK * nheads * 32;
    if (gid >= total) return;
    int i = gid & 31;
    int h = (gid >> 5) % nheads;
    int n = gid / (32 * nheads);
    int t = n & (SEQ - 1);
    float* p = buf + (size_t)n * (nheads * HD) + h * HD + 2 * i;
    float xe = p[0], xo = p[1];
    float c = cs[t * 32 + i], s = sn[t * 32 + i];
    p[0] = xe * c - xo * s;
    p[1] = xe * s + xo * c;
}

// ---------------------------------------------------------------- V transpose: vb[N_TOK][256] -> vbt[256][N_TOK]
__global__ __launch_bounds__(256) void transpose_v(const float* __restrict__ vb,
    float* __restrict__ vbt)
{
    __shared__ float t[64][65];
    int bx = blockIdx.x;
    int by = blockIdx.y;
    int tid = threadIdx.x;
    int c4 = tid & 15, r0 = tid >> 4;
#pragma unroll
    for (int i = 0; i < 4; i++) {
        int row = r0 + i * 16;
        float4 vv = *(const float4*)(vb + (size_t)(bx * 64 + row) * (NKV * HD) + by * 64 + c4 * 4);
        t[c4 * 4 + 0][row] = vv.x;
        t[c4 * 4 + 1][row] = vv.y;
        t[c4 * 4 + 2][row] = vv.z;
        t[c4 * 4 + 3][row] = vv.w;
    }
    __syncthreads();
#pragma unroll
    for (int i = 0; i < 4; i++) {
        int drow = r0 + i * 16;
        float4 vv;
        vv.x = t[drow][c4 * 4 + 0];
        vv.y = t[drow][c4 * 4 + 1];
        vv.z = t[drow][c4 * 4 + 2];
        vv.w = t[drow][c4 * 4 + 3];
        *(float4*)(vbt + (size_t)(by * 64 + drow) * N_TOK + bx * 64 + c4 * 4) = vv;
    }
}

// ---------------------------------------------------------------- MFMA flash attention (split-bf16, fp32-grade)
__global__ __launch_bounds__(256) void attn_mfma(const float* __restrict__ q,
    const float* __restrict__ k, const float* __restrict__ vt, float* __restrict__ out)
{
    int b = blockIdx.z, h = blockIdx.y;
    int qt = (gridDim.x - 1) - blockIdx.x;
    int kvh = h >> 2;
    int tid = threadIdx.x;
    int lane = tid & 63, wv = tid >> 6;
    int q0 = qt * 64;
    int c4 = tid & 15, r0 = tid >> 4;

    __shared__ __align__(16) char Qh[64 * 128], Ql[64 * 128];
    __shared__ __align__(16) char Kh[64 * 128], Kl[64 * 128];
    __shared__ __align__(16) char Vh[64 * 128], Vl[64 * 128];
    __shared__ __align__(16) char Ph[4][16 * 128], Pl[4][16 * 128];

#pragma unroll
    for (int i = 0; i < 4; i++) {
        int row = r0 + i * 16;
        float4 vq = *(const float4*)(q + (size_t)(b * SEQ + q0 + row) * (NH * HD) + h * HD + c4 * 4);
        ushort4 hh, ll;
        hh.x = f2bf(vq.x); hh.y = f2bf(vq.y); hh.z = f2bf(vq.z); hh.w = f2bf(vq.w);
        ll.x = f2bf(vq.x - bf2f(hh.x)); ll.y = f2bf(vq.y - bf2f(hh.y));
        ll.z = f2bf(vq.z - bf2f(hh.z)); ll.w = f2bf(vq.w - bf2f(hh.w));
        int byte = lds_byte(row, c4 * 8, row);
        *(ushort4*)(Qh + byte) = hh;
        *(ushort4*)(Ql + byte) = ll;
    }
    __syncthreads();

    s16x8 aQh[2], aQl[2];
#pragma unroll
    for (int ks = 0; ks < 2; ks++) {
        aQh[ks] = ldfrag(Qh, wv * 16 + (lane & 15), ks, lane);
        aQl[ks] = ldfrag(Ql, wv * 16 + (lane & 15), ks, lane);
    }

    float m_run[4], l_run[4];
    f32x4 acc_o[4];
#pragma unroll
    for (int r = 0; r < 4; r++) { m_run[r] = -1e30f; l_run[r] = 0.f; }
#pragma unroll
    for (int nj = 0; nj < 4; nj++) acc_o[nj] = f32x4{0.f, 0.f, 0.f, 0.f};

    for (int kt = 0; kt <= qt; kt++) {
        int kbase = kt * 64;
        __syncthreads();
#pragma unroll
        for (int i = 0; i < 4; i++) {
            int row = r0 + i * 16;
            float4 vk = *(const float4*)(k + (size_t)(b * SEQ + kbase + row) * (NKV * HD) + kvh * HD + c4 * 4);
            float4 vv = *(const float4*)(vt + (size_t)(kvh * HD + row) * N_TOK + b * SEQ + kbase + c4 * 4);
            ushort4 kh, kl, vh, vl;
            kh.x = f2bf(vk.x); kh.y = f2bf(vk.y); kh.z = f2bf(vk.z); kh.w = f2bf(vk.w);
            kl.x = f2bf(vk.x - bf2f(kh.x)); kl.y = f2bf(vk.y - bf2f(kh.y));
            kl.z = f2bf(vk.z - bf2f(kh.z)); kl.w = f2bf(vk.w - bf2f(kh.w));
            vh.x = f2bf(vv.x); vh.y = f2bf(vv.y); vh.z = f2bf(vv.z); vh.w = f2bf(vv.w);
            vl.x = f2bf(vv.x - bf2f(vh.x)); vl.y = f2bf(vv.y - bf2f(vh.y));
            vl.z = f2bf(vv.z - bf2f(vh.z)); vl.w = f2bf(vv.w - bf2f(vh.w));
            int byte = lds_byte(row, c4 * 8, row);
            *(ushort4*)(Kh + byte) = kh;
            *(ushort4*)(Kl + byte) = kl;
            *(ushort4*)(Vh + byte) = vh;
            *(ushort4*)(Vl + byte) = vl;
        }
        __syncthreads();

        f32x4 sacc[4];
#pragma unroll
        for (int nj = 0; nj < 4; nj++) sacc[nj] = f32x4{0.f, 0.f, 0.f, 0.f};
#pragma unroll
        for (int ks = 0; ks < 2; ks++) {
#pragma unroll
            for (int nj = 0; nj < 4; nj++) {
                s16x8 bKh = ldfrag(Kh, nj * 16 + (lane & 15), ks, lane);
                s16x8 bKl = ldfrag(Kl, nj * 16 + (lane & 15), ks, lane);
                sacc[nj] = mfma16(aQl[ks], bKh, sacc[nj]);
                sacc[nj] = mfma16(aQh[ks], bKl, sacc[nj]);
                sacc[nj] = mfma16(aQh[ks], bKh, sacc[nj]);
            }
        }

        float sv[4][4];
#pragma unroll
        for (int nj = 0; nj < 4; nj++)
#pragma unroll
            for (int r = 0; r < 4; r++) {
                float s = sacc[nj][r] * 0.125f;
                if (kt == qt) {
                    int row_loc = wv * 16 + (lane >> 4) * 4 + r;
                    int col_loc = nj * 16 + (lane & 15);
                    if (col_loc > row_loc) s = -1e30f;
                }
                sv[nj][r] = s;
            }

        float p[4][4];
#pragma unroll
        for (int r = 0; r < 4; r++) {
            float mx = fmaxf(fmaxf(sv[0][r], sv[1][r]), fmaxf(sv[2][r], sv[3][r]));
            mx = fmaxf(mx, __shfl_xor(mx, 1));
            mx = fmaxf(mx, __shfl_xor(mx, 2));
            mx = fmaxf(mx, __shfl_xor(mx, 4));
            mx = fmaxf(mx, __shfl_xor(mx, 8));
            float m_new = fmaxf(m_run[r], mx);
            float corr = __expf(m_run[r] - m_new);
            float ps = 0.f;
#pragma unroll
            for (int nj = 0; nj < 4; nj++) {
                float pv = __expf(sv[nj][r] - m_new);
                p[nj][r] = pv;
                ps += pv;
            }
            ps += __shfl_xor(ps, 1);
            ps += __shfl_xor(ps, 2);
            ps += __shfl_xor(ps, 4);
            ps += __shfl_xor(ps, 8);
            l_run[r] = l_run[r] * corr + ps;
            m_run[r] = m_new;
#pragma unroll
            for (int nj = 0; nj < 4; nj++) acc_o[nj][r] *= corr;
        }

        char* phb = Ph[wv];
        char* plb = Pl[wv];
#pragma unroll
        for (int nj = 0; nj < 4; nj++)
#pragma unroll
            for (int r = 0; r < 4; r++) {
                int row = (lane >> 4) * 4 + r;
                int col = nj * 16 + (lane & 15);
                u16 hh = f2bf(p[nj][r]);
                u16 ll = f2bf(p[nj][r] - bf2f(hh));
                int byte = lds_byte(row, col * 2, row);
                *(u16*)(phb + byte) = hh;
                *(u16*)(plb + byte) = ll;
            }

#pragma unroll
        for (int ks = 0; ks < 2; ks++) {
            s16x8 aPh = ldfrag(phb, lane & 15, ks, lane);
            s16x8 aPl = ldfrag(plb, lane & 15, ks, lane);
#pragma unroll
            for (int nj = 0; nj < 4; nj++) {
                s16x8 bVh = ldfrag(Vh, nj * 16 + (lane & 15), ks, lane);
                s16x8 bVl = ldfrag(Vl, nj * 16 + (lane & 15), ks, lane);
                acc_o[nj] = mfma16(aPl, bVh, acc_o[nj]);
                acc_o[nj] = mfma16(aPh, bVl, acc_o[nj]);
                acc_o[nj] = mfma16(aPh, bVh, acc_o[nj]);
            }
        }
    }

#pragma unroll
    for (int r = 0; r < 4; r++) {
        int row_glob = q0 + wv * 16 + (lane >> 4) * 4 + r;
        float inv = 1.f / l_run[r];
#pragma unroll
        for (int nj = 0; nj < 4; nj++) {
            int dv = nj * 16 + (lane & 15);
            out[(size_t)(b * SEQ + row_glob) * (NH * HD) + h * HD + dv] = acc_o[nj][r] * inv;
        }
    }
}

// ---------------------------------------------------------------- routing
__global__ void init_counts(int* counts, int* pos)
{
    int t = threadIdx.x;
    if (t < NEXP) { counts[t] = 0; pos[t] = 0; }
}

__global__ __launch_bounds__(256) void router_kernel(const float* __restrict__ xn2,
    const float* __restrict__ rw, const float* __restrict__ rb,
    int* __restrict__ top_idx, float* __restrict__ top_w, int* __restrict__ counts)
{
    int wid = threadIdx.x >> 6, lane = threadIdx.x & 63;
    int n = blockIdx.x * 4 + wid;
    if (n >= N_TOK) return;
    const float* xr = xn2 + (size_t)n * DIMM;
    float lg[NEXP];
#pragma unroll
    for (int e = 0; e < NEXP; e++) {
        float p = 0.f;
        for (int d = lane; d < DIMM; d += 64) p += xr[d] * rw[e * DIMM + d];
#pragma unroll
        for (int off = 32; off; off >>= 1) p += __shfl_xor(p, off);
        lg[e] = p + rb[e];
    }
    if (lane == 0) {
        float m = lg[0];
#pragma unroll
        for (int e = 1; e < NEXP; e++) m = fmaxf(m, lg[e]);
        float pe[NEXP], s = 0.f;
#pragma unroll
        for (int e = 0; e < NEXP; e++) { pe[e] = __expf(lg[e] - m); s += pe[e]; }
        int i1 = 0; float v1 = pe[0];
#pragma unroll
        for (int e = 1; e < NEXP; e++) if (pe[e] > v1) { v1 = pe[e]; i1 = e; }
        int i2 = -1; float v2 = -1.f;
#pragma unroll
        for (int e = 0; e < NEXP; e++) if (e != i1 && pe[e] > v2) { v2 = pe[e]; i2 = e; }
        v1 /= s; v2 /= s;
        float den = v1 + v2 + 1e-9f;
        top_idx[2 * n] = i1; top_idx[2 * n + 1] = i2;
        top_w[2 * n] = v1 / den; top_w[2 * n + 1] = v2 / den;
        atomicAdd(&counts[i1], 1);
        atomicAdd(&counts[i2], 1);
    }
}

__global__ void offsets_kernel(const int* counts, int* offs)
{
    if (threadIdx.x == 0) {
        int s = 0;
        for (int e = 0; e < NEXP; e++) { offs[e] = s; s += counts[e]; }
    }
}

__global__ __launch_bounds__(256) void fill_kernel(const int* __restrict__ top_idx,
    const float* __restrict__ top_w, const int* __restrict__ offs, int* __restrict__ pos,
    int* __restrict__ assign_token, float* __restrict__ assign_w)
{
    int n = blockIdx.x * 256 + threadIdx.x;
    if (n >= N_TOK) return;
#pragma unroll
    for (int s = 0; s < 2; s++) {
        int e = top_idx[2 * n + s];
        int p = atomicAdd(&pos[e], 1);
        int r = offs[e] + p;
        assign_token[r] = n;
        assign_w[r] = top_w[2 * n + s];
    }
}

// ---------------------------------------------------------------- MoE gate/up v2: bf16 inputs, global_load_lds staging
// BM=128 tokens, BN=64 (both G and U), BK=64; 4 waves 2x2
__global__ __launch_bounds__(256) void moe_gateup2(const u16* __restrict__ xb,
    const u16* __restrict__ wgb, const u16* __restrict__ wub,
    const int* __restrict__ assign_token, const int* __restrict__ offs,
    const int* __restrict__ counts, u16* __restrict__ hbufb)
{
    int e = blockIdx.z;
    int cnt = counts[e];
    int t0 = blockIdx.y * 128;
    if (t0 >= cnt) return;
    int base = offs[e];
    int h0 = blockIdx.x * 64;
    __shared__ __align__(16) u16 As[128 * 64];
    __shared__ __align__(16) u16 Gs[64 * 64];
    __shared__ __align__(16) u16 Us[64 * 64];
    __shared__ int toks[128];
    int tid = threadIdx.x;
    if (tid < 128) {
        int a = t0 + tid;
        toks[tid] = (a < cnt) ? assign_token[base + a] : 0;  // pad with token 0; rows masked at epilogue
    }
    __syncthreads();
    int lane = tid & 63, wv = tid >> 6;
    int wm = wv >> 1, wn = wv & 1;
    int sr = lane >> 3, sc = lane & 7;

    // per-lane fixed staging rows
    int tokr[4];
#pragma unroll
    for (int i = 0; i < 4; i++) tokr[i] = toks[wv * 32 + i * 8 + sr];

    const u16* wge = wgb + (size_t)e * HID * DIMM;
    const u16* wue = wub + (size_t)e * HID * DIMM;

    f32x4 accg[4][2], accu[4][2];
#pragma unroll
    for (int i = 0; i < 4; i++)
#pragma unroll
        for (int j = 0; j < 2; j++) { accg[i][j] = f32x4{0,0,0,0}; accu[i][j] = f32x4{0,0,0,0}; }

    for (int k0 = 0; k0 < DIMM; k0 += 64) {
        // A: 16 chunks of 1KB; wave w stages chunks w*4..w*4+3 (rows w*32..w*32+31)
#pragma unroll
        for (int i = 0; i < 4; i++) {
            int row = wv * 32 + i * 8 + sr;
            int c = sc ^ (row & 7);
            gload16(xb + (size_t)tokr[i] * DIMM + k0 + c * 8, (void*)(As + (wv * 4 + i) * 512));
        }
        // G/U: 8 chunks each; wave w stages chunks w*2, w*2+1 (rows w*16..w*16+15)
#pragma unroll
        for (int i = 0; i < 2; i++) {
            int row = wv * 16 + i * 8 + sr;
            int c = sc ^ (row & 7);
            gload16(wge + (size_t)(h0 + row) * DIMM + k0 + c * 8, (void*)(Gs + (wv * 2 + i) * 512));
            gload16(wue + (size_t)(h0 + row) * DIMM + k0 + c * 8, (void*)(Us + (wv * 2 + i) * 512));
        }
        __syncthreads();
#pragma unroll
        for (int ks = 0; ks < 2; ++ks) {
            s16x8 af[4], gf[2], uf[2];
#pragma unroll
            for (int mi = 0; mi < 4; mi++)
                af[mi] = ldfrag((const char*)As, wm * 64 + mi * 16 + (lane & 15), ks, lane);
#pragma unroll
            for (int nj = 0; nj < 2; nj++) {
                int row = wn * 32 + nj * 16 + (lane & 15);
                gf[nj] = ldfrag((const char*)Gs, row, ks, lane);
                uf[nj] = ldfrag((const char*)Us, row, ks, lane);
            }
#pragma unroll
            for (int mi = 0; mi < 4; mi++)
#pragma unroll
                for (int nj = 0; nj < 2; nj++) {
                    accg[mi][nj] = mfma16(af[mi], gf[nj], accg[mi][nj]);
                    accu[mi][nj] = mfma16(af[mi], uf[nj], accu[mi][nj]);
                }
        }
        __syncthreads();
    }
#pragma unroll
    for (int mi = 0; mi < 4; mi++)
#pragma unroll
        for (int nj = 0; nj < 2; nj++)
#pragma unroll
            for (int r = 0; r < 4; r++) {
                int row = wm * 64 + mi * 16 + (lane >> 4) * 4 + r;
                if (t0 + row < cnt) {
                    int col = wn * 32 + nj * 16 + (lane & 15);
                    float g = accg[mi][nj][r], u = accu[mi][nj][r];
                    float hh = (g / (1.f + __expf(-g))) * u;
                    hbufb[(size_t)(base + t0 + row) * HID + h0 + col] = f2bf(hh);
                }
            }
}

// ---------------------------------------------------------------- MoE down v2: bf16 inputs, global_load_lds staging
// BM=128 slots, BN=128 dims, BK=64
__global__ __launch_bounds__(256) void moe_down2(const u16* __restrict__ hbufb,
    const u16* __restrict__ wdb, const int* __restrict__ assign_token,
    const float* __restrict__ assign_w, const int* __restrict__ offs,
    const int* __restrict__ counts, float* __restrict__ out)
{
    int e = blockIdx.z;
    int cnt = counts[e];
    int t0 = blockIdx.y * 128;
    if (t0 >= cnt) return;
    int base = offs[e];
    int d0 = blockIdx.x * 128;
    __shared__ __align__(16) u16 As[128 * 64];
    __shared__ __align__(16) u16 Bs[128 * 64];
    __shared__ int toks[128];
    __shared__ float rw_[128];
    int tid = threadIdx.x;
    if (tid < 128) {
        int a = t0 + tid;
        toks[tid] = (a < cnt) ? assign_token[base + a] : 0;
        rw_[tid] = (a < cnt) ? assign_w[base + a] : 0.f;
    }
    __syncthreads();
    int lane = tid & 63, wv = tid >> 6;
    int wm = wv >> 1, wn = wv & 1;
    int sr = lane >> 3, sc = lane & 7;

    const u16* wde = wdb + (size_t)e * DIMM * HID;

    f32x4 acc[4][4];
#pragma unroll
    for (int i = 0; i < 4; i++)
#pragma unroll
        for (int j = 0; j < 4; j++) acc[i][j] = f32x4{0,0,0,0};

    for (int k0 = 0; k0 < HID; k0 += 64) {
#pragma unroll
        for (int i = 0; i < 4; i++) {
            int row = wv * 32 + i * 8 + sr;
            int c = sc ^ (row & 7);
            gload16(hbufb + (size_t)(base + t0 + row) * HID + k0 + c * 8, (void*)(As + (wv * 4 + i) * 512));
            gload16(wde + (size_t)(d0 + row) * HID + k0 + c * 8, (void*)(Bs + (wv * 4 + i) * 512));
        }
        __syncthreads();
#pragma unroll
        for (int ks = 0; ks < 2; ++ks) {
            s16x8 af[4], bf[4];
#pragma unroll
            for (int mi = 0; mi < 4; mi++)
                af[mi] = ldfrag((const char*)As, wm * 64 + mi * 16 + (lane & 15), ks, lane);
#pragma unroll
            for (int nj = 0; nj < 4; nj++)
                bf[nj] = ldfrag((const char*)Bs, wn * 64 + nj * 16 + (lane & 15), ks, lane);
#pragma unroll
            for (int mi = 0; mi < 4; mi++)
#pragma unroll
                for (int nj = 0; nj < 4; nj++)
                    acc[mi][nj] = mfma16(af[mi], bf[nj], acc[mi][nj]);
        }
        __syncthreads();
    }
#pragma unroll
    for (int mi = 0; mi < 4; mi++)
#pragma unroll
        for (int r = 0; r < 4; r++) {
            int row = wm * 64 + mi * 16 + (lane >> 4) * 4 + r;
            if (t0 + row < cnt) {
                int tok = toks[row];
                float w = rw_[row];
#pragma unroll
                for (int nj = 0; nj < 4; nj++) {
                    int col = d0 + wn * 64 + nj * 16 + (lane & 15);
                    atomicAdd(&out[(size_t)tok * DIMM + col], acc[mi][nj][r] * w);
                }
            }
        }
}

// ---------------------------------------------------------------- legacy MoE kernels (fallback if ws too small)
__global__ __launch_bounds__(256) void moe_gateup(const float* __restrict__ xn2,
    const float* __restrict__ wg, const float* __restrict__ wu,
    const int* __restrict__ assign_token, const int* __restrict__ offs,
    const int* __restrict__ counts, float* __restrict__ hbuf)
{
    int e = blockIdx.z;
    int cnt = counts[e];
    int t0 = blockIdx.y * 128;
    if (t0 >= cnt) return;
    int base = offs[e];
    int h0 = blockIdx.x * 64;
    __shared__ __align__(16) char As[128 * 128];
    __shared__ __align__(16) char Gs[64 * 128];
    __shared__ __align__(16) char Us[64 * 128];
    __shared__ int toks[128];
    int tid = threadIdx.x;
    if (tid < 128) {
        int a = t0 + tid;
        toks[tid] = (a < cnt) ? assign_token[base + a] : -1;
    }
    __syncthreads();
    int lane = tid & 63, wv = tid >> 6;
    int wm = wv >> 1, wn = wv & 1;
    int c4 = tid & 15, r0 = tid >> 4;

    f32x4 accg[4][2], accu[4][2];
#pragma unroll
    for (int i = 0; i < 4; i++)
#pragma unroll
        for (int j = 0; j < 2; j++) { accg[i][j] = f32x4{0,0,0,0}; accu[i][j] = f32x4{0,0,0,0}; }

    const float* wge = wg + (size_t)e * HID * DIMM;
    const float* wue = wu + (size_t)e * HID * DIMM;

    for (int k0 = 0; k0 < DIMM; k0 += 64) {
#pragma unroll
        for (int i = 0; i < 8; ++i) {
            int r = r0 + i * 16;
            int tok = toks[r];
            float4 va = (tok >= 0) ? *(const float4*)(xn2 + (size_t)tok * DIMM + k0 + c4 * 4)
                                   : float4{0.f, 0.f, 0.f, 0.f};
            ushort4 ba;
            ba.x = f2bf(va.x); ba.y = f2bf(va.y); ba.z = f2bf(va.z); ba.w = f2bf(va.w);
            *(ushort4*)(As + lds_byte(r, c4 * 8, r)) = ba;
        }
#pragma unroll
        for (int i = 0; i < 4; ++i) {
            int r = r0 + i * 16;
            float4 vg = *(const float4*)(wge + (size_t)(h0 + r) * DIMM + k0 + c4 * 4);
            float4 vu = *(const float4*)(wue + (size_t)(h0 + r) * DIMM + k0 + c4 * 4);
            ushort4 bg, bu;
            bg.x = f2bf(vg.x); bg.y = f2bf(vg.y); bg.z = f2bf(vg.z); bg.w = f2bf(vg.w);
            bu.x = f2bf(vu.x); bu.y = f2bf(vu.y); bu.z = f2bf(vu.z); bu.w = f2bf(vu.w);
            int byte = lds_byte(r, c4 * 8, r);
            *(ushort4*)(Gs + byte) = bg;
            *(ushort4*)(Us + byte) = bu;
        }
        __syncthreads();
#pragma unroll
        for (int ks = 0; ks < 2; ++ks) {
            s16x8 af[4], gf[2], uf[2];
#pragma unroll
            for (int mi = 0; mi < 4; mi++) af[mi] = ldfrag(As, wm * 64 + mi * 16 + (lane & 15), ks, lane);
#pragma unroll
            for (int nj = 0; nj < 2; nj++) {
                int row = wn * 32 + nj * 16 + (lane & 15);
                gf[nj] = ldfrag(Gs, row, ks, lane);
                uf[nj] = ldfrag(Us, row, ks, lane);
            }
#pragma unroll
            for (int mi = 0; mi < 4; mi++)
#pragma unroll
                for (int nj = 0; nj < 2; nj++) {
                    accg[mi][nj] = mfma16(af[mi], gf[nj], accg[mi][nj]);
                    accu[mi][nj] = mfma16(af[mi], uf[nj], accu[mi][nj]);
                }
        }
        __syncthreads();
    }
#pragma unroll
    for (int mi = 0; mi < 4; mi++)
#pragma unroll
        for (int nj = 0; nj < 2; nj++)
#pragma unroll
            for (int r = 0; r < 4; r++) {
                int row = wm * 64 + mi * 16 + (lane >> 4) * 4 + r;
                if (t0 + row < cnt) {
                    int col = wn * 32 + nj * 16 + (lane & 15);
                    float g = accg[mi][nj][r], u = accu[mi][nj][r];
                    float hh = (g / (1.f + __expf(-g))) * u;
                    hbuf[(size_t)(base + t0 + row) * HID + h0 + col] = hh;
                }
            }
}

__global__ __launch_bounds__(256) void moe_down(const float* __restrict__ hbuf,
    const float* __restrict__ wd, const int* __restrict__ assign_token,
    const float* __restrict__ assign_w, const int* __restrict__ offs,
    const int* __restrict__ counts, float* __restrict__ out)
{
    int e = blockIdx.z;
    int cnt = counts[e];
    int t0 = blockIdx.y * 128;
    if (t0 >= cnt) return;
    int base = offs[e];
    int d0 = blockIdx.x * 128;
    __shared__ __align__(16) char As[128 * 128];
    __shared__ __align__(16) char Bs[128 * 128];
    __shared__ int toks[128];
    __shared__ float rw_[128];
    int tid = threadIdx.x;
    if (tid < 128) {
        int a = t0 + tid;
        toks[tid] = (a < cnt) ? assign_token[base + a] : -1;
        rw_[tid] = (a < cnt) ? assign_w[base + a] : 0.f;
    }
    __syncthreads();
    int lane = tid & 63, wv = tid >> 6;
    int wm = wv >> 1, wn = wv & 1;
    int c4 = tid & 15, r0 = tid >> 4;

    f32x4 acc[4][4];
#pragma unroll
    for (int i = 0; i < 4; i++)
#pragma unroll
        for (int j = 0; j < 4; j++) acc[i][j] = f32x4{0,0,0,0};

    const float* wde = wd + (size_t)e * DIMM * HID;

    for (int k0 = 0; k0 < HID; k0 += 64) {
#pragma unroll
        for (int i = 0; i < 8; ++i) {
            int r = r0 + i * 16;
            float4 va = (t0 + r < cnt) ? *(const float4*)(hbuf + (size_t)(base + t0 + r) * HID + k0 + c4 * 4)
                                       : float4{0.f, 0.f, 0.f, 0.f};
            float4 vb = *(const float4*)(wde + (size_t)(d0 + r) * HID + k0 + c4 * 4);
            ushort4 ba, bb;
            ba.x = f2bf(va.x); ba.y = f2bf(va.y); ba.z = f2bf(va.z); ba.w = f2bf(va.w);
            bb.x = f2bf(vb.x); bb.y = f2bf(vb.y); bb.z = f2bf(vb.z); bb.w = f2bf(vb.w);
            int byte = lds_byte(r, c4 * 8, r);
            *(ushort4*)(As + byte) = ba;
            *(ushort4*)(Bs + byte) = bb;
        }
        __syncthreads();
#pragma unroll
        for (int ks = 0; ks < 2; ++ks) {
            s16x8 af[4], bf[4];
#pragma unroll
            for (int mi = 0; mi < 4; mi++) af[mi] = ldfrag(As, wm * 64 + mi * 16 + (lane & 15), ks, lane);
#pragma unroll
            for (int nj = 0; nj < 4; nj++) bf[nj] = ldfrag(Bs, wn * 64 + nj * 16 + (lane & 15), ks, lane);
#pragma unroll
            for (int mi = 0; mi < 4; mi++)
#pragma unroll
                for (int nj = 0; nj < 4; nj++)
                    acc[mi][nj] = mfma16(af[mi], bf[nj], acc[mi][nj]);
        }
        __syncthreads();
    }
#pragma unroll
    for (int mi = 0; mi < 4; mi++)
#pragma unroll
        for (int r = 0; r < 4; r++) {
            int row = wm * 64 + mi * 16 + (lane >> 4) * 4 + r;
            if (t0 + row < cnt) {
                int tok = toks[row];
                float w = rw_[row];
#pragma unroll
                for (int nj = 0; nj < 4; nj++) {
                    int col = d0 + wn * 64 + nj * 16 + (lane & 15);
                    atomicAdd(&out[(size_t)tok * DIMM + col], acc[mi][nj][r] * w);
                }
            }
        }
}

// ---------------------------------------------------------------- launch
extern "C" void kernel_launch(void* const* d_in, const int* in_sizes, int n_in,
                              void* d_out, int out_size, void* d_ws, size_t ws_size,
                              hipStream_t stream)
{
    const float* x      = (const float*)d_in[0];
    const float* cs     = (const float*)d_in[1];
    const float* sn     = (const float*)d_in[2];
    const float* w_na   = (const float*)d_in[3];
    const float* wq     = (const float*)d_in[4];
    const float* wk     = (const float*)d_in[5];
    const float* wv     = (const float*)d_in[6];
    const float* wo     = (const float*)d_in[7];
    const float* w_nf   = (const float*)d_in[8];
    const float* rw     = (const float*)d_in[9];
    const float* rb     = (const float*)d_in[10];
    const float* wg     = (const float*)d_in[11];
    const float* wu     = (const float*)d_in[12];
    const float* wd     = (const float*)d_in[13];
    float* out = (float*)d_out;

    const size_t F = 1024 * 1024;
    float* wsf = (float*)d_ws;
    bool big = ws_size >= (size_t)40 * F * sizeof(float);   // ~168 MB

    if (big) {
        float* xn   = wsf;                 // 0..2F
        float* qb   = wsf + 2 * F;         // 2..4F
        float* kb   = wsf + 4 * F;         // 4..4.5F
        float* vb   = wsf + 4 * F + F / 2; // 4.5..5F
        float* attn = wsf + 5 * F;         // 5..7F
        float* xn2  = wsf + 7 * F;         // 7..9F
        float* vbt  = wsf + 9 * F;         // 9..9.5F
        float* tail = wsf + 9 * F + F / 2; // 9.5..10F
        u16* xn2b   = (u16*)(wsf + 10 * F);  // 2M u16 -> 10..11F
        u16* hbufb  = (u16*)(wsf + 11 * F);  // 8M u16 -> 11..15F
        u16* wgb    = (u16*)(wsf + 15 * F);  // 16M u16 -> 15..23F
        u16* wub    = (u16*)(wsf + 23 * F);  // 23..31F
        u16* wdb    = (u16*)(wsf + 31 * F);  // 31..39F
        int*   top_idx      = (int*)tail;
        float* top_w        = tail + 4096;
        int*   counts       = (int*)(tail + 8192);
        int*   offs         = (int*)(tail + 8192) + 8;
        int*   pos          = (int*)(tail + 8192) + 16;
        int*   assign_token = (int*)(tail + 8192) + 32;
        float* assign_w     = tail + 8192 + 32 + 4096;

        // 0. weight conversions (fp32 -> bf16)
        cvt_bf16<<<2048, 256, 0, stream>>>(wg, wgb, 4 * (int)F);
        cvt_bf16<<<2048, 256, 0, stream>>>(wu, wub, 4 * (int)F);
        cvt_bf16<<<2048, 256, 0, stream>>>(wd, wdb, 4 * (int)F);
        // 1. rmsnorm (attn)
        rmsnorm_kernel<<<N_TOK, 256, 0, stream>>>(x, w_na, xn);
        // 2. projections (split-bf16, fp32-grade)
        gemm_split<<<dim3(8, 16), 256, 0, stream>>>(xn, wq, qb, nullptr, N_TOK, 1024, 1024, 1024);
        gemm_split<<<dim3(2, 16), 256, 0, stream>>>(xn, wk, kb, nullptr, N_TOK, 256, 1024, 256);
        gemm_split<<<dim3(2, 16), 256, 0, stream>>>(xn, wv, vb, nullptr, N_TOK, 256, 1024, 256);
        // 3. RoPE + V transpose
        rope_kernel<<<(N_TOK * NH * 32) / 256, 256, 0, stream>>>(qb, cs, sn, NH);
        rope_kernel<<<(N_TOK * NKV * 32) / 256, 256, 0, stream>>>(kb, cs, sn, NKV);
        transpose_v<<<dim3(N_TOK / 64, (NKV * HD) / 64), 256, 0, stream>>>(vb, vbt);
        // 4. attention (MFMA flash)
        attn_mfma<<<dim3(SEQ / 64, NH, 2), 256, 0, stream>>>(qb, kb, vbt, attn);
        // 5. output projection + residual
        gemm_split<<<dim3(8, 16), 256, 0, stream>>>(attn, wo, out, x, N_TOK, 1024, 1024, 1024);
        // 6. rmsnorm (ffn) -> fp32 (router) + bf16 (MoE A)
        rmsnorm_dual<<<N_TOK, 256, 0, stream>>>(out, w_nf, xn2, xn2b);
        // 7-10. routing
        init_counts<<<1, 64, 0, stream>>>(counts, pos);
        router_kernel<<<N_TOK / 4, 256, 0, stream>>>(xn2, rw, rb, top_idx, top_w, counts);
        offsets_kernel<<<1, 64, 0, stream>>>(counts, offs);
        fill_kernel<<<N_TOK / 256, 256, 0, stream>>>(top_idx, top_w, offs, pos, assign_token, assign_w);
        // 11-12. MoE (bf16 + global_load_lds)
        moe_gateup2<<<dim3(HID / 64, 16, NEXP), 256, 0, stream>>>(xn2b, wgb, wub, assign_token, offs, counts, hbufb);
        moe_down2<<<dim3(DIMM / 128, 16, NEXP), 256, 0, stream>>>(hbufb, wdb, assign_token, assign_w, offs, counts, out);
    } else {
        // fallback: round-5 layout and kernels
        float* xn   = wsf;
        float* qb   = wsf + 2 * F;
        float* kb   = wsf + 4 * F;
        float* vb   = kb + F / 2;
        float* attn = wsf + 5 * F;
        float* xn2  = wsf + 7 * F;
        float* hbuf = wsf + 9 * F;
        float* vbt  = hbuf;
        float* tail = wsf + 17 * F;
        int*   top_idx      = (int*)tail;
        float* top_w        = tail + 4096;
        int*   counts       = (int*)(tail + 8192);
        int*   offs         = (int*)(tail + 8192) + 8;
        int*   pos          = (int*)(tail + 8192) + 16;
        int*   assign_token = (int*)(tail + 8192) + 32;
        float* assign_w     = tail + 8192 + 32 + 4096;

        rmsnorm_kernel<<<N_TOK, 256, 0, stream>>>(x, w_na, xn);
        gemm_split<<<dim3(8, 16), 256, 0, stream>>>(xn, wq, qb, nullptr, N_TOK, 1024, 1024, 1024);
        gemm_split<<<dim3(2, 16), 256, 0, stream>>>(xn, wk, kb, nullptr, N_TOK, 256, 1024, 256);
        gemm_split<<<dim3(2, 16), 256, 0, stream>>>(xn, wv, vb, nullptr, N_TOK, 256, 1024, 256);
        rope_kernel<<<(N_TOK * NH * 32) / 256, 256, 0, stream>>>(qb, cs, sn, NH);
        rope_kernel<<<(N_TOK * NKV * 32) / 256, 256, 0, stream>>>(kb, cs, sn, NKV);
        transpose_v<<<dim3(N_TOK / 64, (NKV * HD) / 64), 256, 0, stream>>>(vb, vbt);
        attn_mfma<<<dim3(SEQ / 64, NH, 2), 256, 0, stream>>>(qb, kb, vbt, attn);
        gemm_split<<<dim3(8, 16), 256, 0, stream>>>(attn, wo, out, x, N_TOK, 1024, 1024, 1024);
        rmsnorm_kernel<<<N_TOK, 256, 0, stream>>>(out, w_nf, xn2);
        init_counts<<<1, 64, 0, stream>>>(counts, pos);
        router_kernel<<<N_TOK / 4, 256, 0, stream>>>(xn2, rw, rb, top_idx, top_w, counts);
        offsets_kernel<<<1, 64, 0, stream>>>(counts, offs);
        fill_kernel<<<N_TOK / 256, 256, 0, stream>>>(top_idx, top_w, offs, pos, assign_token, assign_w);
        moe_gateup<<<dim3(HID / 64, 16, NEXP), 256, 0, stream>>>(xn2, wg, wu, assign_token, offs, counts, hbuf);
        moe_down<<<dim3(DIMM / 128, 16, NEXP), 256, 0, stream>>>(hbuf, wd, assign_token, assign_w, offs, counts, out);
    }
}

// Round 7
// 453.882 us; speedup vs baseline: 5.1448x; 1.9255x over previous
//
#include <hip/hip_runtime.h>
#include <math.h>

#define N_TOK   2048      // B*T
#define SEQ     1024
#define DIMM    1024
#define NH      16
#define NKV     4
#define HD      64
#define HID     2048
#define NEXP    8
#define QKVW    1536      // fused q|k|v row width

typedef __attribute__((ext_vector_type(4))) float f32x4;
typedef __attribute__((ext_vector_type(8))) short s16x8;
typedef unsigned short u16;

__device__ __forceinline__ u16 f2bf(float f) {
    union { float f; unsigned u; } v; v.f = f;
    unsigned r = v.u + 0x7fffu + ((v.u >> 16) & 1u);
    return (u16)(r >> 16);
}
__device__ __forceinline__ float bf2f(u16 h) {
    union { unsigned u; float f; } v; v.u = ((unsigned)h) << 16;
    return v.f;
}

__device__ __forceinline__ f32x4 mfma16(s16x8 a, s16x8 b, f32x4 c) {
    return __builtin_amdgcn_mfma_f32_16x16x32_bf16(a, b, c, 0, 0, 0);
}

// LDS tile row stride = 64 bf16 = 128 B; XOR-swizzle 16B slot with row&7 (T2)
__device__ __forceinline__ int lds_byte(int row, int byte_in_row, int swz_key) {
    return row * 128 + (byte_in_row ^ ((swz_key & 7) << 4));
}

// load a 16B MFMA fragment (8 bf16) for logical row `row`, k-slice ks (0/1)
__device__ __forceinline__ s16x8 ldfrag(const char* base, int row, int ks, int lane) {
    int b = lds_byte(row, ks * 64 + ((lane >> 4) * 16), row);
    return *(const s16x8*)(base + b);
}

// async 16B global -> LDS (wave-uniform LDS base + lane*16)
__device__ __forceinline__ void gload16(const void* g, void* l) {
    __builtin_amdgcn_global_load_lds(
        (const __attribute__((address_space(1))) void*)g,
        (__attribute__((address_space(3))) void*)l, 16, 0, 0);
}

// ---------------------------------------------------------------- fp32 -> bf16 bulk convert
__global__ __launch_bounds__(256) void cvt_bf16(const float* __restrict__ in,
    u16* __restrict__ out, int n4)
{
    int i = blockIdx.x * 256 + threadIdx.x;
    int stride = gridDim.x * 256;
    for (; i < n4; i += stride) {
        float4 v = reinterpret_cast<const float4*>(in)[i];
        ushort4 o;
        o.x = f2bf(v.x); o.y = f2bf(v.y); o.z = f2bf(v.z); o.w = f2bf(v.w);
        reinterpret_cast<ushort4*>(out)[i] = o;
    }
}

// ---------------------------------------------------------------- fp32 -> bf16 hi/lo split convert
__global__ __launch_bounds__(256) void cvt_split(const float* __restrict__ in,
    u16* __restrict__ hi, u16* __restrict__ lo, int n4)
{
    int i = blockIdx.x * 256 + threadIdx.x;
    int stride = gridDim.x * 256;
    for (; i < n4; i += stride) {
        float4 v = reinterpret_cast<const float4*>(in)[i];
        ushort4 h, l;
        h.x = f2bf(v.x); h.y = f2bf(v.y); h.z = f2bf(v.z); h.w = f2bf(v.w);
        l.x = f2bf(v.x - bf2f(h.x)); l.y = f2bf(v.y - bf2f(h.y));
        l.z = f2bf(v.z - bf2f(h.z)); l.w = f2bf(v.w - bf2f(h.w));
        reinterpret_cast<ushort4*>(hi)[i] = h;
        reinterpret_cast<ushort4*>(lo)[i] = l;
    }
}

// ---------------------------------------------------------------- rmsnorm -> bf16 hi/lo
__global__ __launch_bounds__(256) void rmsnorm_split(const float* __restrict__ x,
    const float* __restrict__ w, u16* __restrict__ oh, u16* __restrict__ ol)
{
    int row = blockIdx.x;
    const float4* xr = reinterpret_cast<const float4*>(x + (size_t)row * DIMM);
    const float4* wr = reinterpret_cast<const float4*>(w);
    float4 v = xr[threadIdx.x];
    float ss = v.x*v.x + v.y*v.y + v.z*v.z + v.w*v.w;
#pragma unroll
    for (int off = 32; off; off >>= 1) ss += __shfl_xor(ss, off);
    __shared__ float red[4];
    int wid = threadIdx.x >> 6, lane = threadIdx.x & 63;
    if (lane == 0) red[wid] = ss;
    __syncthreads();
    float tot = red[0] + red[1] + red[2] + red[3];
    float inv = rsqrtf(tot * (1.0f/DIMM) + 1e-6f);
    float4 ww = wr[threadIdx.x];
    float4 o;
    o.x = ww.x * v.x * inv;
    o.y = ww.y * v.y * inv;
    o.z = ww.z * v.z * inv;
    o.w = ww.w * v.w * inv;
    ushort4 h, l;
    h.x = f2bf(o.x); h.y = f2bf(o.y); h.z = f2bf(o.z); h.w = f2bf(o.w);
    l.x = f2bf(o.x - bf2f(h.x)); l.y = f2bf(o.y - bf2f(h.y));
    l.z = f2bf(o.z - bf2f(h.z)); l.w = f2bf(o.w - bf2f(h.w));
    reinterpret_cast<ushort4*>(oh + (size_t)row * DIMM)[threadIdx.x] = h;
    reinterpret_cast<ushort4*>(ol + (size_t)row * DIMM)[threadIdx.x] = l;
}

// ---------------------------------------------------------------- rmsnorm (fp32 + bf16 out)
__global__ __launch_bounds__(256) void rmsnorm_dual(const float* __restrict__ x,
    const float* __restrict__ w, float* __restrict__ out, u16* __restrict__ outb)
{
    int row = blockIdx.x;
    const float4* xr = reinterpret_cast<const float4*>(x + (size_t)row * DIMM);
    const float4* wr = reinterpret_cast<const float4*>(w);
    float4 v = xr[threadIdx.x];
    float ss = v.x*v.x + v.y*v.y + v.z*v.z + v.w*v.w;
#pragma unroll
    for (int off = 32; off; off >>= 1) ss += __shfl_xor(ss, off);
    __shared__ float red[4];
    int wid = threadIdx.x >> 6, lane = threadIdx.x & 63;
    if (lane == 0) red[wid] = ss;
    __syncthreads();
    float tot = red[0] + red[1] + red[2] + red[3];
    float inv = rsqrtf(tot * (1.0f/DIMM) + 1e-6f);
    float4 ww = wr[threadIdx.x];
    float4 o;
    o.x = ww.x * v.x * inv;
    o.y = ww.y * v.y * inv;
    o.z = ww.z * v.z * inv;
    o.w = ww.w * v.w * inv;
    reinterpret_cast<float4*>(out + (size_t)row * DIMM)[threadIdx.x] = o;
    ushort4 ob;
    ob.x = f2bf(o.x); ob.y = f2bf(o.y); ob.z = f2bf(o.z); ob.w = f2bf(o.w);
    reinterpret_cast<ushort4*>(outb + (size_t)row * DIMM)[threadIdx.x] = ob;
}

// ---------------------------------------------------------------- split-bf16 GEMM, pre-split inputs, gload staging
// C[M,N] = A[M,K] @ B[N,K]^T (+R).  A,B given as bf16 hi/lo pairs.
// BM=128, BN=64, BK=64; 4 waves 2x2 (wave tile 64x32); LDS 48 KB
__global__ __launch_bounds__(256) void gemm_bs(const u16* __restrict__ Ah_,
    const u16* __restrict__ Al_, const u16* __restrict__ Bh_, const u16* __restrict__ Bl_,
    float* __restrict__ C, const float* __restrict__ R, int M, int N, int K, int ldc)
{
    __shared__ __align__(16) u16 Ah[128 * 64], Al[128 * 64];
    __shared__ __align__(16) u16 Bh[64 * 64],  Bl[64 * 64];
    int tid = threadIdx.x;
    int m0 = blockIdx.y * 128, n0 = blockIdx.x * 64;
    int lane = tid & 63, wv = tid >> 6;
    int wm = wv >> 1, wn = wv & 1;
    int sr = lane >> 3, sc = lane & 7;

    f32x4 acc[4][2];
#pragma unroll
    for (int i = 0; i < 4; i++)
#pragma unroll
        for (int j = 0; j < 2; j++) acc[i][j] = f32x4{0.f, 0.f, 0.f, 0.f};

    for (int k0 = 0; k0 < K; k0 += 64) {
#pragma unroll
        for (int i = 0; i < 4; i++) {
            int row = wv * 32 + i * 8 + sr;
            int c = sc ^ (row & 7);
            size_t g = (size_t)(m0 + row) * K + k0 + c * 8;
            gload16(Ah_ + g, (void*)(Ah + (wv * 4 + i) * 512));
            gload16(Al_ + g, (void*)(Al + (wv * 4 + i) * 512));
        }
#pragma unroll
        for (int i = 0; i < 2; i++) {
            int row = wv * 16 + i * 8 + sr;
            int c = sc ^ (row & 7);
            size_t g = (size_t)(n0 + row) * K + k0 + c * 8;
            gload16(Bh_ + g, (void*)(Bh + (wv * 2 + i) * 512));
            gload16(Bl_ + g, (void*)(Bl + (wv * 2 + i) * 512));
        }
        __syncthreads();
#pragma unroll
        for (int ks = 0; ks < 2; ++ks) {
            s16x8 afh[4], afl[4], bfh[2], bfl[2];
#pragma unroll
            for (int mi = 0; mi < 4; mi++) {
                int row = wm * 64 + mi * 16 + (lane & 15);
                afh[mi] = ldfrag((const char*)Ah, row, ks, lane);
                afl[mi] = ldfrag((const char*)Al, row, ks, lane);
            }
#pragma unroll
            for (int nj = 0; nj < 2; nj++) {
                int row = wn * 32 + nj * 16 + (lane & 15);
                bfh[nj] = ldfrag((const char*)Bh, row, ks, lane);
                bfl[nj] = ldfrag((const char*)Bl, row, ks, lane);
            }
#pragma unroll
            for (int mi = 0; mi < 4; mi++)
#pragma unroll
                for (int nj = 0; nj < 2; nj++) {
                    acc[mi][nj] = mfma16(afl[mi], bfh[nj], acc[mi][nj]);
                    acc[mi][nj] = mfma16(afh[mi], bfl[nj], acc[mi][nj]);
                    acc[mi][nj] = mfma16(afh[mi], bfh[nj], acc[mi][nj]);
                }
        }
        __syncthreads();
    }
#pragma unroll
    for (int mi = 0; mi < 4; mi++)
#pragma unroll
        for (int nj = 0; nj < 2; nj++)
#pragma unroll
            for (int r = 0; r < 4; r++) {
                int m = m0 + wm * 64 + mi * 16 + (lane >> 4) * 4 + r;
                int n = n0 + wn * 32 + nj * 16 + (lane & 15);
                float v = acc[mi][nj][r];
                if (R) v += R[(size_t)m * ldc + n];
                C[(size_t)m * ldc + n] = v;
            }
}

// ---------------------------------------------------------------- RoPE (in place, strided)
__global__ __launch_bounds__(256) void rope_kernel(float* __restrict__ buf,
    const float* __restrict__ cs, const float* __restrict__ sn, int nheads,
    int row_stride, int base_col)
{
    int gid = blockIdx.x * 256 + threadIdx.x;
    int total = N_TOK * nheads * 32;
    if (gid >= total) return;
    int i = gid & 31;
    int h = (gid >> 5) % nheads;
    int n = gid / (32 * nheads);
    int t = n & (SEQ - 1);
    float* p = buf + (size_t)n * row_stride + base_col + h * HD + 2 * i;
    float xe = p[0], xo = p[1];
    float c = cs[t * 32 + i], s = sn[t * 32 + i];
    p[0] = xe * c - xo * s;
    p[1] = xe * s + xo * c;
}

// ---------------------------------------------------------------- V transpose: v[N_TOK][256] (strided) -> vbt[256][N_TOK]
__global__ __launch_bounds__(256) void transpose_v(const float* __restrict__ vsrc,
    float* __restrict__ vbt, int row_stride, int base_col)
{
    __shared__ float t[64][65];
    int bx = blockIdx.x;
    int by = blockIdx.y;
    int tid = threadIdx.x;
    int c4 = tid & 15, r0 = tid >> 4;
#pragma unroll
    for (int i = 0; i < 4; i++) {
        int row = r0 + i * 16;
        float4 vv = *(const float4*)(vsrc + (size_t)(bx * 64 + row) * row_stride + base_col + by * 64 + c4 * 4);
        t[c4 * 4 + 0][row] = vv.x;
        t[c4 * 4 + 1][row] = vv.y;
        t[c4 * 4 + 2][row] = vv.z;
        t[c4 * 4 + 3][row] = vv.w;
    }
    __syncthreads();
#pragma unroll
    for (int i = 0; i < 4; i++) {
        int drow = r0 + i * 16;
        float4 vv;
        vv.x = t[drow][c4 * 4 + 0];
        vv.y = t[drow][c4 * 4 + 1];
        vv.z = t[drow][c4 * 4 + 2];
        vv.w = t[drow][c4 * 4 + 3];
        *(float4*)(vbt + (size_t)(by * 64 + drow) * N_TOK + bx * 64 + c4 * 4) = vv;
    }
}

// ---------------------------------------------------------------- MFMA flash attention (split-bf16, fp32-grade)
// q at qkv[row][h*64], k at qkv[row][1024 + kvh*64]; output written as bf16 hi/lo
__global__ __launch_bounds__(256) void attn_mfma(const float* __restrict__ qkv,
    const float* __restrict__ vt, u16* __restrict__ outh, u16* __restrict__ outl)
{
    int b = blockIdx.z, h = blockIdx.y;
    int qt = (gridDim.x - 1) - blockIdx.x;
    int kvh = h >> 2;
    int tid = threadIdx.x;
    int lane = tid & 63, wv = tid >> 6;
    int q0 = qt * 64;
    int c4 = tid & 15, r0 = tid >> 4;

    __shared__ __align__(16) char Qh[64 * 128], Ql[64 * 128];
    __shared__ __align__(16) char Kh[64 * 128], Kl[64 * 128];
    __shared__ __align__(16) char Vh[64 * 128], Vl[64 * 128];
    __shared__ __align__(16) char Ph[4][16 * 128], Pl[4][16 * 128];

#pragma unroll
    for (int i = 0; i < 4; i++) {
        int row = r0 + i * 16;
        float4 vq = *(const float4*)(qkv + (size_t)(b * SEQ + q0 + row) * QKVW + h * HD + c4 * 4);
        ushort4 hh, ll;
        hh.x = f2bf(vq.x); hh.y = f2bf(vq.y); hh.z = f2bf(vq.z); hh.w = f2bf(vq.w);
        ll.x = f2bf(vq.x - bf2f(hh.x)); ll.y = f2bf(vq.y - bf2f(hh.y));
        ll.z = f2bf(vq.z - bf2f(hh.z)); ll.w = f2bf(vq.w - bf2f(hh.w));
        int byte = lds_byte(row, c4 * 8, row);
        *(ushort4*)(Qh + byte) = hh;
        *(ushort4*)(Ql + byte) = ll;
    }
    __syncthreads();

    s16x8 aQh[2], aQl[2];
#pragma unroll
    for (int ks = 0; ks < 2; ks++) {
        aQh[ks] = ldfrag(Qh, wv * 16 + (lane & 15), ks, lane);
        aQl[ks] = ldfrag(Ql, wv * 16 + (lane & 15), ks, lane);
    }

    float m_run[4], l_run[4];
    f32x4 acc_o[4];
#pragma unroll
    for (int r = 0; r < 4; r++) { m_run[r] = -1e30f; l_run[r] = 0.f; }
#pragma unroll
    for (int nj = 0; nj < 4; nj++) acc_o[nj] = f32x4{0.f, 0.f, 0.f, 0.f};

    for (int kt = 0; kt <= qt; kt++) {
        int kbase = kt * 64;
        __syncthreads();
#pragma unroll
        for (int i = 0; i < 4; i++) {
            int row = r0 + i * 16;
            float4 vk = *(const float4*)(qkv + (size_t)(b * SEQ + kbase + row) * QKVW + 1024 + kvh * HD + c4 * 4);
            float4 vv = *(const float4*)(vt + (size_t)(kvh * HD + row) * N_TOK + b * SEQ + kbase + c4 * 4);
            ushort4 kh, kl, vh, vl;
            kh.x = f2bf(vk.x); kh.y = f2bf(vk.y); kh.z = f2bf(vk.z); kh.w = f2bf(vk.w);
            kl.x = f2bf(vk.x - bf2f(kh.x)); kl.y = f2bf(vk.y - bf2f(kh.y));
            kl.z = f2bf(vk.z - bf2f(kh.z)); kl.w = f2bf(vk.w - bf2f(kh.w));
            vh.x = f2bf(vv.x); vh.y = f2bf(vv.y); vh.z = f2bf(vv.z); vh.w = f2bf(vv.w);
            vl.x = f2bf(vv.x - bf2f(vh.x)); vl.y = f2bf(vv.y - bf2f(vh.y));
            vl.z = f2bf(vv.z - bf2f(vh.z)); vl.w = f2bf(vv.w - bf2f(vh.w));
            int byte = lds_byte(row, c4 * 8, row);
            *(ushort4*)(Kh + byte) = kh;
            *(ushort4*)(Kl + byte) = kl;
            *(ushort4*)(Vh + byte) = vh;
            *(ushort4*)(Vl + byte) = vl;
        }
        __syncthreads();

        f32x4 sacc[4];
#pragma unroll
        for (int nj = 0; nj < 4; nj++) sacc[nj] = f32x4{0.f, 0.f, 0.f, 0.f};
#pragma unroll
        for (int ks = 0; ks < 2; ks++) {
#pragma unroll
            for (int nj = 0; nj < 4; nj++) {
                s16x8 bKh = ldfrag(Kh, nj * 16 + (lane & 15), ks, lane);
                s16x8 bKl = ldfrag(Kl, nj * 16 + (lane & 15), ks, lane);
                sacc[nj] = mfma16(aQl[ks], bKh, sacc[nj]);
                sacc[nj] = mfma16(aQh[ks], bKl, sacc[nj]);
                sacc[nj] = mfma16(aQh[ks], bKh, sacc[nj]);
            }
        }

        float sv[4][4];
#pragma unroll
        for (int nj = 0; nj < 4; nj++)
#pragma unroll
            for (int r = 0; r < 4; r++) {
                float s = sacc[nj][r] * 0.125f;
                if (kt == qt) {
                    int row_loc = wv * 16 + (lane >> 4) * 4 + r;
                    int col_loc = nj * 16 + (lane & 15);
                    if (col_loc > row_loc) s = -1e30f;
                }
                sv[nj][r] = s;
            }

        float p[4][4];
#pragma unroll
        for (int r = 0; r < 4; r++) {
            float mx = fmaxf(fmaxf(sv[0][r], sv[1][r]), fmaxf(sv[2][r], sv[3][r]));
            mx = fmaxf(mx, __shfl_xor(mx, 1));
            mx = fmaxf(mx, __shfl_xor(mx, 2));
            mx = fmaxf(mx, __shfl_xor(mx, 4));
            mx = fmaxf(mx, __shfl_xor(mx, 8));
            float m_new = fmaxf(m_run[r], mx);
            float corr = __expf(m_run[r] - m_new);
            float ps = 0.f;
#pragma unroll
            for (int nj = 0; nj < 4; nj++) {
                float pv = __expf(sv[nj][r] - m_new);
                p[nj][r] = pv;
                ps += pv;
            }
            ps += __shfl_xor(ps, 1);
            ps += __shfl_xor(ps, 2);
            ps += __shfl_xor(ps, 4);
            ps += __shfl_xor(ps, 8);
            l_run[r] = l_run[r] * corr + ps;
            m_run[r] = m_new;
#pragma unroll
            for (int nj = 0; nj < 4; nj++) acc_o[nj][r] *= corr;
        }

        char* phb = Ph[wv];
        char* plb = Pl[wv];
#pragma unroll
        for (int nj = 0; nj < 4; nj++)
#pragma unroll
            for (int r = 0; r < 4; r++) {
                int row = (lane >> 4) * 4 + r;
                int col = nj * 16 + (lane & 15);
                u16 hh = f2bf(p[nj][r]);
                u16 ll = f2bf(p[nj][r] - bf2f(hh));
                int byte = lds_byte(row, col * 2, row);
                *(u16*)(phb + byte) = hh;
                *(u16*)(plb + byte) = ll;
            }

#pragma unroll
        for (int ks = 0; ks < 2; ks++) {
            s16x8 aPh = ldfrag(phb, lane & 15, ks, lane);
            s16x8 aPl = ldfrag(plb, lane & 15, ks, lane);
#pragma unroll
            for (int nj = 0; nj < 4; nj++) {
                s16x8 bVh = ldfrag(Vh, nj * 16 + (lane & 15), ks, lane);
                s16x8 bVl = ldfrag(Vl, nj * 16 + (lane & 15), ks, lane);
                acc_o[nj] = mfma16(aPl, bVh, acc_o[nj]);
                acc_o[nj] = mfma16(aPh, bVl, acc_o[nj]);
                acc_o[nj] = mfma16(aPh, bVh, acc_o[nj]);
            }
        }
    }

#pragma unroll
    for (int r = 0; r < 4; r++) {
        int row_glob = q0 + wv * 16 + (lane >> 4) * 4 + r;
        float inv = 1.f / l_run[r];
#pragma unroll
        for (int nj = 0; nj < 4; nj++) {
            int dv = nj * 16 + (lane & 15);
            size_t idx = (size_t)(b * SEQ + row_glob) * (NH * HD) + h * HD + dv;
            float v = acc_o[nj][r] * inv;
            u16 hh = f2bf(v);
            outh[idx] = hh;
            outl[idx] = f2bf(v - bf2f(hh));
        }
    }
}

// ---------------------------------------------------------------- routing
__global__ void init_counts(int* counts, int* pos)
{
    int t = threadIdx.x;
    if (t < NEXP) { counts[t] = 0; pos[t] = 0; }
}

__global__ __launch_bounds__(256) void router_kernel(const float* __restrict__ xn2,
    const float* __restrict__ rw, const float* __restrict__ rb,
    int* __restrict__ top_idx, float* __restrict__ top_w, int* __restrict__ counts)
{
    int wid = threadIdx.x >> 6, lane = threadIdx.x & 63;
    int n = blockIdx.x * 4 + wid;
    if (n >= N_TOK) return;
    const float* xr = xn2 + (size_t)n * DIMM;
    float lg[NEXP];
#pragma unroll
    for (int e = 0; e < NEXP; e++) {
        float p = 0.f;
        for (int d = lane; d < DIMM; d += 64) p += xr[d] * rw[e * DIMM + d];
#pragma unroll
        for (int off = 32; off; off >>= 1) p += __shfl_xor(p, off);
        lg[e] = p + rb[e];
    }
    if (lane == 0) {
        float m = lg[0];
#pragma unroll
        for (int e = 1; e < NEXP; e++) m = fmaxf(m, lg[e]);
        float pe[NEXP], s = 0.f;
#pragma unroll
        for (int e = 0; e < NEXP; e++) { pe[e] = __expf(lg[e] - m); s += pe[e]; }
        int i1 = 0; float v1 = pe[0];
#pragma unroll
        for (int e = 1; e < NEXP; e++) if (pe[e] > v1) { v1 = pe[e]; i1 = e; }
        int i2 = -1; float v2 = -1.f;
#pragma unroll
        for (int e = 0; e < NEXP; e++) if (e != i1 && pe[e] > v2) { v2 = pe[e]; i2 = e; }
        v1 /= s; v2 /= s;
        float den = v1 + v2 + 1e-9f;
        top_idx[2 * n] = i1; top_idx[2 * n + 1] = i2;
        top_w[2 * n] = v1 / den; top_w[2 * n + 1] = v2 / den;
        atomicAdd(&counts[i1], 1);
        atomicAdd(&counts[i2], 1);
    }
}

__global__ void offsets_kernel(const int* counts, int* offs)
{
    if (threadIdx.x == 0) {
        int s = 0;
        for (int e = 0; e < NEXP; e++) { offs[e] = s; s += counts[e]; }
    }
}

__global__ __launch_bounds__(256) void fill_kernel(const int* __restrict__ top_idx,
    const float* __restrict__ top_w, const int* __restrict__ offs, int* __restrict__ pos,
    int* __restrict__ assign_token, float* __restrict__ assign_w)
{
    int n = blockIdx.x * 256 + threadIdx.x;
    if (n >= N_TOK) return;
#pragma unroll
    for (int s = 0; s < 2; s++) {
        int e = top_idx[2 * n + s];
        int p = atomicAdd(&pos[e], 1);
        int r = offs[e] + p;
        assign_token[r] = n;
        assign_w[r] = top_w[2 * n + s];
    }
}

// ---------------------------------------------------------------- MoE gate/up v2: bf16 inputs, global_load_lds staging
__global__ __launch_bounds__(256) void moe_gateup2(const u16* __restrict__ xb,
    const u16* __restrict__ wgb, const u16* __restrict__ wub,
    const int* __restrict__ assign_token, const int* __restrict__ offs,
    const int* __restrict__ counts, u16* __restrict__ hbufb)
{
    int e = blockIdx.z;
    int cnt = counts[e];
    int t0 = blockIdx.y * 128;
    if (t0 >= cnt) return;
    int base = offs[e];
    int h0 = blockIdx.x * 64;
    __shared__ __align__(16) u16 As[128 * 64];
    __shared__ __align__(16) u16 Gs[64 * 64];
    __shared__ __align__(16) u16 Us[64 * 64];
    __shared__ int toks[128];
    int tid = threadIdx.x;
    if (tid < 128) {
        int a = t0 + tid;
        toks[tid] = (a < cnt) ? assign_token[base + a] : 0;
    }
    __syncthreads();
    int lane = tid & 63, wv = tid >> 6;
    int wm = wv >> 1, wn = wv & 1;
    int sr = lane >> 3, sc = lane & 7;

    int tokr[4];
#pragma unroll
    for (int i = 0; i < 4; i++) tokr[i] = toks[wv * 32 + i * 8 + sr];

    const u16* wge = wgb + (size_t)e * HID * DIMM;
    const u16* wue = wub + (size_t)e * HID * DIMM;

    f32x4 accg[4][2], accu[4][2];
#pragma unroll
    for (int i = 0; i < 4; i++)
#pragma unroll
        for (int j = 0; j < 2; j++) { accg[i][j] = f32x4{0,0,0,0}; accu[i][j] = f32x4{0,0,0,0}; }

    for (int k0 = 0; k0 < DIMM; k0 += 64) {
#pragma unroll
        for (int i = 0; i < 4; i++) {
            int row = wv * 32 + i * 8 + sr;
            int c = sc ^ (row & 7);
            gload16(xb + (size_t)tokr[i] * DIMM + k0 + c * 8, (void*)(As + (wv * 4 + i) * 512));
        }
#pragma unroll
        for (int i = 0; i < 2; i++) {
            int row = wv * 16 + i * 8 + sr;
            int c = sc ^ (row & 7);
            gload16(wge + (size_t)(h0 + row) * DIMM + k0 + c * 8, (void*)(Gs + (wv * 2 + i) * 512));
            gload16(wue + (size_t)(h0 + row) * DIMM + k0 + c * 8, (void*)(Us + (wv * 2 + i) * 512));
        }
        __syncthreads();
#pragma unroll
        for (int ks = 0; ks < 2; ++ks) {
            s16x8 af[4], gf[2], uf[2];
#pragma unroll
            for (int mi = 0; mi < 4; mi++)
                af[mi] = ldfrag((const char*)As, wm * 64 + mi * 16 + (lane & 15), ks, lane);
#pragma unroll
            for (int nj = 0; nj < 2; nj++) {
                int row = wn * 32 + nj * 16 + (lane & 15);
                gf[nj] = ldfrag((const char*)Gs, row, ks, lane);
                uf[nj] = ldfrag((const char*)Us, row, ks, lane);
            }
#pragma unroll
            for (int mi = 0; mi < 4; mi++)
#pragma unroll
                for (int nj = 0; nj < 2; nj++) {
                    accg[mi][nj] = mfma16(af[mi], gf[nj], accg[mi][nj]);
                    accu[mi][nj] = mfma16(af[mi], uf[nj], accu[mi][nj]);
                }
        }
        __syncthreads();
    }
#pragma unroll
    for (int mi = 0; mi < 4; mi++)
#pragma unroll
        for (int nj = 0; nj < 2; nj++)
#pragma unroll
            for (int r = 0; r < 4; r++) {
                int row = wm * 64 + mi * 16 + (lane >> 4) * 4 + r;
                if (t0 + row < cnt) {
                    int col = wn * 32 + nj * 16 + (lane & 15);
                    float g = accg[mi][nj][r], u = accu[mi][nj][r];
                    float hh = (g / (1.f + __expf(-g))) * u;
                    hbufb[(size_t)(base + t0 + row) * HID + h0 + col] = f2bf(hh);
                }
            }
}

// ---------------------------------------------------------------- MoE down v2
__global__ __launch_bounds__(256) void moe_down2(const u16* __restrict__ hbufb,
    const u16* __restrict__ wdb, const int* __restrict__ assign_token,
    const float* __restrict__ assign_w, const int* __restrict__ offs,
    const int* __restrict__ counts, float* __restrict__ out)
{
    int e = blockIdx.z;
    int cnt = counts[e];
    int t0 = blockIdx.y * 128;
    if (t0 >= cnt) return;
    int base = offs[e];
    int d0 = blockIdx.x * 128;
    __shared__ __align__(16) u16 As[128 * 64];
    __shared__ __align__(16) u16 Bs[128 * 64];
    __shared__ int toks[128];
    __shared__ float rw_[128];
    int tid = threadIdx.x;
    if (tid < 128) {
        int a = t0 + tid;
        toks[tid] = (a < cnt) ? assign_token[base + a] : 0;
        rw_[tid] = (a < cnt) ? assign_w[base + a] : 0.f;
    }
    __syncthreads();
    int lane = tid & 63, wv = tid >> 6;
    int wm = wv >> 1, wn = wv & 1;
    int sr = lane >> 3, sc = lane & 7;

    const u16* wde = wdb + (size_t)e * DIMM * HID;

    f32x4 acc[4][4];
#pragma unroll
    for (int i = 0; i < 4; i++)
#pragma unroll
        for (int j = 0; j < 4; j++) acc[i][j] = f32x4{0,0,0,0};

    for (int k0 = 0; k0 < HID; k0 += 64) {
#pragma unroll
        for (int i = 0; i < 4; i++) {
            int row = wv * 32 + i * 8 + sr;
            int c = sc ^ (row & 7);
            gload16(hbufb + (size_t)(base + t0 + row) * HID + k0 + c * 8, (void*)(As + (wv * 4 + i) * 512));
            gload16(wde + (size_t)(d0 + row) * HID + k0 + c * 8, (void*)(Bs + (wv * 4 + i) * 512));
        }
        __syncthreads();
#pragma unroll
        for (int ks = 0; ks < 2; ++ks) {
            s16x8 af[4], bf[4];
#pragma unroll
            for (int mi = 0; mi < 4; mi++)
                af[mi] = ldfrag((const char*)As, wm * 64 + mi * 16 + (lane & 15), ks, lane);
#pragma unroll
            for (int nj = 0; nj < 4; nj++)
                bf[nj] = ldfrag((const char*)Bs, wn * 64 + nj * 16 + (lane & 15), ks, lane);
#pragma unroll
            for (int mi = 0; mi < 4; mi++)
#pragma unroll
                for (int nj = 0; nj < 4; nj++)
                    acc[mi][nj] = mfma16(af[mi], bf[nj], acc[mi][nj]);
        }
        __syncthreads();
    }
#pragma unroll
    for (int mi = 0; mi < 4; mi++)
#pragma unroll
        for (int r = 0; r < 4; r++) {
            int row = wm * 64 + mi * 16 + (lane >> 4) * 4 + r;
            if (t0 + row < cnt) {
                int tok = toks[row];
                float w = rw_[row];
#pragma unroll
                for (int nj = 0; nj < 4; nj++) {
                    int col = d0 + wn * 64 + nj * 16 + (lane & 15);
                    atomicAdd(&out[(size_t)tok * DIMM + col], acc[mi][nj][r] * w);
                }
            }
        }
}

// ---------------------------------------------------------------- launch
extern "C" void kernel_launch(void* const* d_in, const int* in_sizes, int n_in,
                              void* d_out, int out_size, void* d_ws, size_t ws_size,
                              hipStream_t stream)
{
    const float* x      = (const float*)d_in[0];
    const float* cs     = (const float*)d_in[1];
    const float* sn     = (const float*)d_in[2];
    const float* w_na   = (const float*)d_in[3];
    const float* wq     = (const float*)d_in[4];
    const float* wk     = (const float*)d_in[5];
    const float* wv     = (const float*)d_in[6];
    const float* wo     = (const float*)d_in[7];
    const float* w_nf   = (const float*)d_in[8];
    const float* rw     = (const float*)d_in[9];
    const float* rb     = (const float*)d_in[10];
    const float* wg     = (const float*)d_in[11];
    const float* wu     = (const float*)d_in[12];
    const float* wd     = (const float*)d_in[13];
    float* out = (float*)d_out;

    const size_t F = 1024 * 1024;
    float* wsf = (float*)d_ws;

    // layout (float units):
    float* qkvb = wsf;                         // 0..3F      [2048][1536] fp32
    float* vbt  = wsf + 3 * F;                 // 3..3.5F    [256][2048] fp32
    float* xn2  = wsf + 3 * F + F / 2;         // 3.5..5.5F
    float* tail = wsf + 5 * F + F / 2;         // 5.5..6F    routing scratch
    u16* xn2b   = (u16*)(wsf + 6 * F);         // 6..7F      2M u16
    u16* hbufb  = (u16*)(wsf + 7 * F);         // 7..11F     8M u16 (MoE h)
    u16* xnh    = (u16*)(wsf + 7 * F);         //   alias 7..8F   (dead before moe)
    u16* xnl    = (u16*)(wsf + 8 * F);         //   alias 8..9F
    u16* attnh  = (u16*)(wsf + 9 * F);         //   alias 9..10F
    u16* attnl  = (u16*)(wsf + 10 * F);        //   alias 10..11F
    u16* wgb    = (u16*)(wsf + 11 * F);        // 11..19F    16M u16
    u16* wub    = (u16*)(wsf + 19 * F);        // 19..27F
    u16* wdb    = (u16*)(wsf + 27 * F);        // 27..35F
    u16* wqkvoh = (u16*)(wsf + 35 * F);        // 35..36.25F 2.5M u16
    u16* wqkvol = (u16*)(wsf + 36 * F + F / 4);// 36.25..37.5F

    int*   top_idx      = (int*)tail;
    float* top_w        = tail + 4096;
    int*   counts       = (int*)(tail + 8192);
    int*   offs         = (int*)(tail + 8192) + 8;
    int*   pos          = (int*)(tail + 8192) + 16;
    int*   assign_token = (int*)(tail + 8192) + 32;
    float* assign_w     = tail + 8192 + 32 + 4096;

    // 0a. projection weights -> concatenated bf16 hi/lo [wq|wk|wv|wo] rows
    cvt_split<<<512, 256, 0, stream>>>(wq, wqkvoh,                wqkvol,                262144);
    cvt_split<<<256, 256, 0, stream>>>(wk, wqkvoh + 1024 * 1024,  wqkvol + 1024 * 1024,   65536);
    cvt_split<<<256, 256, 0, stream>>>(wv, wqkvoh + 1280 * 1024,  wqkvol + 1280 * 1024,   65536);
    cvt_split<<<512, 256, 0, stream>>>(wo, wqkvoh + 1536 * 1024,  wqkvol + 1536 * 1024,  262144);
    // 0b. MoE weights -> bf16
    cvt_bf16<<<2048, 256, 0, stream>>>(wg, wgb, 4 * (int)F);
    cvt_bf16<<<2048, 256, 0, stream>>>(wu, wub, 4 * (int)F);
    cvt_bf16<<<2048, 256, 0, stream>>>(wd, wdb, 4 * (int)F);
    // 1. rmsnorm (attn) -> bf16 hi/lo
    rmsnorm_split<<<N_TOK, 256, 0, stream>>>(x, w_na, xnh, xnl);
    // 2. fused qkv projection (384 blocks)
    gemm_bs<<<dim3(QKVW / 64, 16), 256, 0, stream>>>(xnh, xnl, wqkvoh, wqkvol,
                                                     qkvb, nullptr, N_TOK, QKVW, DIMM, QKVW);
    // 3. RoPE (q, k) + V transpose
    rope_kernel<<<(N_TOK * NH * 32) / 256, 256, 0, stream>>>(qkvb, cs, sn, NH, QKVW, 0);
    rope_kernel<<<(N_TOK * NKV * 32) / 256, 256, 0, stream>>>(qkvb, cs, sn, NKV, QKVW, 1024);
    transpose_v<<<dim3(N_TOK / 64, (NKV * HD) / 64), 256, 0, stream>>>(qkvb, vbt, QKVW, 1280);
    // 4. attention (MFMA flash) -> bf16 hi/lo output
    attn_mfma<<<dim3(SEQ / 64, NH, 2), 256, 0, stream>>>(qkvb, vbt, attnh, attnl);
    // 5. output projection + residual (256 blocks)
    gemm_bs<<<dim3(DIMM / 64, 16), 256, 0, stream>>>(attnh, attnl,
                                                     wqkvoh + (size_t)1536 * 1024, wqkvol + (size_t)1536 * 1024,
                                                     out, x, N_TOK, DIMM, NH * HD, DIMM);
    // 6. rmsnorm (ffn) -> fp32 (router) + bf16 (MoE A)
    rmsnorm_dual<<<N_TOK, 256, 0, stream>>>(out, w_nf, xn2, xn2b);
    // 7-10. routing
    init_counts<<<1, 64, 0, stream>>>(counts, pos);
    router_kernel<<<N_TOK / 4, 256, 0, stream>>>(xn2, rw, rb, top_idx, top_w, counts);
    offsets_kernel<<<1, 64, 0, stream>>>(counts, offs);
    fill_kernel<<<N_TOK / 256, 256, 0, stream>>>(top_idx, top_w, offs, pos, assign_token, assign_w);
    // 11-12. MoE (bf16 + global_load_lds)
    moe_gateup2<<<dim3(HID / 64, 16, NEXP), 256, 0, stream>>>(xn2b, wgb, wub, assign_token, offs, counts, hbufb);
    moe_down2<<<dim3(DIMM / 128, 16, NEXP), 256, 0, stream>>>(hbufb, wdb, assign_token, assign_w, offs, counts, out);
}

// Round 9
// 367.915 us; speedup vs baseline: 6.3469x; 1.2337x over previous
//
#include <hip/hip_runtime.h>
#include <math.h>

#define N_TOK   2048      // B*T
#define SEQ     1024
#define DIMM    1024
#define NH      16
#define NKV     4
#define HD      64
#define HID     2048
#define NEXP    8
#define QKVW    1536      // fused q|k|v row width

typedef __attribute__((ext_vector_type(4))) float f32x4;
typedef __attribute__((ext_vector_type(8))) short s16x8;
typedef unsigned short u16;

__device__ __forceinline__ u16 f2bf(float f) {
    union { float f; unsigned u; } v; v.f = f;
    unsigned r = v.u + 0x7fffu + ((v.u >> 16) & 1u);
    return (u16)(r >> 16);
}
__device__ __forceinline__ float bf2f(u16 h) {
    union { unsigned u; float f; } v; v.u = ((unsigned)h) << 16;
    return v.f;
}

__device__ __forceinline__ f32x4 mfma16(s16x8 a, s16x8 b, f32x4 c) {
    return __builtin_amdgcn_mfma_f32_16x16x32_bf16(a, b, c, 0, 0, 0);
}

// LDS tile row stride = 64 bf16 = 128 B; XOR-swizzle 16B slot with row&7 (T2)
__device__ __forceinline__ int lds_byte(int row, int byte_in_row, int swz_key) {
    return row * 128 + (byte_in_row ^ ((swz_key & 7) << 4));
}

// load a 16B MFMA fragment (8 bf16) for logical row `row`, k-slice ks (0/1)
__device__ __forceinline__ s16x8 ldfrag(const char* base, int row, int ks, int lane) {
    int b = lds_byte(row, ks * 64 + ((lane >> 4) * 16), row);
    return *(const s16x8*)(base + b);
}

// async 16B global -> LDS (wave-uniform LDS base + lane*16)
__device__ __forceinline__ void gload16(const void* g, void* l) {
    __builtin_amdgcn_global_load_lds(
        (const __attribute__((address_space(1))) void*)g,
        (__attribute__((address_space(3))) void*)l, 16, 0, 0);
}

// ---------------------------------------------------------------- merged fp32 -> bf16 convert (wg|wu|wd)
// each tensor is 8*2048*1024 = 16M floats = 4M float4  (R8 BUG: used 1M -> 3/4 garbage)
__global__ __launch_bounds__(256) void cvt3(const float* __restrict__ a,
    const float* __restrict__ b, const float* __restrict__ c,
    u16* __restrict__ oa, u16* __restrict__ ob, u16* __restrict__ oc)
{
    const int n4 = 4 << 20;   // 4M float4 per tensor
    int i = blockIdx.x * 256 + threadIdx.x;
    int stride = gridDim.x * 256;
    for (; i < 3 * n4; i += stride) {
        int seg = i >> 22, j = i & (n4 - 1);
        const float* in = (seg == 0) ? a : (seg == 1) ? b : c;
        u16* out = (seg == 0) ? oa : (seg == 1) ? ob : oc;
        float4 v = reinterpret_cast<const float4*>(in)[j];
        ushort4 o;
        o.x = f2bf(v.x); o.y = f2bf(v.y); o.z = f2bf(v.z); o.w = f2bf(v.w);
        reinterpret_cast<ushort4*>(out)[j] = o;
    }
}

// ---------------------------------------------------------------- merged fp32 -> bf16 hi/lo split (wq|wk|wv|wo)
__global__ __launch_bounds__(256) void cvt_split4(const float* __restrict__ wq,
    const float* __restrict__ wk, const float* __restrict__ wv, const float* __restrict__ wo,
    u16* __restrict__ hi, u16* __restrict__ lo)
{
    int i = blockIdx.x * 256 + threadIdx.x;
    int stride = gridDim.x * 256;
    for (; i < 655360; i += stride) {
        const float* in; int j;
        if (i < 262144)      { in = wq; j = i; }
        else if (i < 327680) { in = wk; j = i - 262144; }
        else if (i < 393216) { in = wv; j = i - 327680; }
        else                 { in = wo; j = i - 393216; }
        float4 v = reinterpret_cast<const float4*>(in)[j];
        ushort4 h, l;
        h.x = f2bf(v.x); h.y = f2bf(v.y); h.z = f2bf(v.z); h.w = f2bf(v.w);
        l.x = f2bf(v.x - bf2f(h.x)); l.y = f2bf(v.y - bf2f(h.y));
        l.z = f2bf(v.z - bf2f(h.z)); l.w = f2bf(v.w - bf2f(h.w));
        reinterpret_cast<ushort4*>(hi)[i] = h;
        reinterpret_cast<ushort4*>(lo)[i] = l;
    }
}

// ---------------------------------------------------------------- rmsnorm -> bf16 hi/lo
__global__ __launch_bounds__(256) void rmsnorm_split(const float* __restrict__ x,
    const float* __restrict__ w, u16* __restrict__ oh, u16* __restrict__ ol)
{
    int row = blockIdx.x;
    const float4* xr = reinterpret_cast<const float4*>(x + (size_t)row * DIMM);
    const float4* wr = reinterpret_cast<const float4*>(w);
    float4 v = xr[threadIdx.x];
    float ss = v.x*v.x + v.y*v.y + v.z*v.z + v.w*v.w;
#pragma unroll
    for (int off = 32; off; off >>= 1) ss += __shfl_xor(ss, off);
    __shared__ float red[4];
    int wid = threadIdx.x >> 6, lane = threadIdx.x & 63;
    if (lane == 0) red[wid] = ss;
    __syncthreads();
    float tot = red[0] + red[1] + red[2] + red[3];
    float inv = rsqrtf(tot * (1.0f/DIMM) + 1e-6f);
    float4 ww = wr[threadIdx.x];
    float4 o;
    o.x = ww.x * v.x * inv;
    o.y = ww.y * v.y * inv;
    o.z = ww.z * v.z * inv;
    o.w = ww.w * v.w * inv;
    ushort4 h, l;
    h.x = f2bf(o.x); h.y = f2bf(o.y); h.z = f2bf(o.z); h.w = f2bf(o.w);
    l.x = f2bf(o.x - bf2f(h.x)); l.y = f2bf(o.y - bf2f(h.y));
    l.z = f2bf(o.z - bf2f(h.z)); l.w = f2bf(o.w - bf2f(h.w));
    reinterpret_cast<ushort4*>(oh + (size_t)row * DIMM)[threadIdx.x] = h;
    reinterpret_cast<ushort4*>(ol + (size_t)row * DIMM)[threadIdx.x] = l;
}

// ---------------------------------------------------------------- rmsnorm + fused router logits -> bf16 + logits
__global__ __launch_bounds__(256) void rmsnorm_router(const float* __restrict__ x,
    const float* __restrict__ w, const float* __restrict__ rw, const float* __restrict__ rb,
    u16* __restrict__ outb, float* __restrict__ logits)
{
    int row = blockIdx.x;
    int tid = threadIdx.x;
    int wid = tid >> 6, lane = tid & 63;
    const float4* xr = reinterpret_cast<const float4*>(x + (size_t)row * DIMM);
    const float4* wr = reinterpret_cast<const float4*>(w);
    float4 v = xr[tid];
    float ss = v.x*v.x + v.y*v.y + v.z*v.z + v.w*v.w;
#pragma unroll
    for (int off = 32; off; off >>= 1) ss += __shfl_xor(ss, off);
    __shared__ float red[4];
    __shared__ float lred[4][NEXP];
    if (lane == 0) red[wid] = ss;
    __syncthreads();
    float tot = red[0] + red[1] + red[2] + red[3];
    float inv = rsqrtf(tot * (1.0f/DIMM) + 1e-6f);
    float4 ww = wr[tid];
    float4 o;
    o.x = ww.x * v.x * inv;
    o.y = ww.y * v.y * inv;
    o.z = ww.z * v.z * inv;
    o.w = ww.w * v.w * inv;
    ushort4 ob;
    ob.x = f2bf(o.x); ob.y = f2bf(o.y); ob.z = f2bf(o.z); ob.w = f2bf(o.w);
    reinterpret_cast<ushort4*>(outb + (size_t)row * DIMM)[tid] = ob;
    // router partials: 8 independent FMA chains (full ILP), thread covers dims [tid*4, tid*4+4)
    float acc[NEXP];
#pragma unroll
    for (int e = 0; e < NEXP; e++) {
        float4 r4 = reinterpret_cast<const float4*>(rw + (size_t)e * DIMM)[tid];
        acc[e] = o.x * r4.x + o.y * r4.y + o.z * r4.z + o.w * r4.w;
    }
#pragma unroll
    for (int e = 0; e < NEXP; e++) {
        float p = acc[e];
#pragma unroll
        for (int off = 32; off; off >>= 1) p += __shfl_xor(p, off);
        acc[e] = p;
    }
    if (lane == 0)
#pragma unroll
        for (int e = 0; e < NEXP; e++) lred[wid][e] = acc[e];
    __syncthreads();
    if (tid < NEXP)
        logits[(size_t)row * NEXP + tid] =
            lred[0][tid] + lred[1][tid] + lred[2][tid] + lred[3][tid] + rb[tid];
}

// ---------------------------------------------------------------- top-2 selection from logits
__global__ __launch_bounds__(256) void top2_kernel(const float* __restrict__ logits,
    int* __restrict__ top_idx, float* __restrict__ top_w, int* __restrict__ counts)
{
    int n = blockIdx.x * 256 + threadIdx.x;
    if (n >= N_TOK) return;
    float lg[NEXP];
#pragma unroll
    for (int e = 0; e < NEXP; e++) lg[e] = logits[(size_t)n * NEXP + e];
    float m = lg[0];
#pragma unroll
    for (int e = 1; e < NEXP; e++) m = fmaxf(m, lg[e]);
    float pe[NEXP], s = 0.f;
#pragma unroll
    for (int e = 0; e < NEXP; e++) { pe[e] = __expf(lg[e] - m); s += pe[e]; }
    int i1 = 0; float v1 = pe[0];
#pragma unroll
    for (int e = 1; e < NEXP; e++) if (pe[e] > v1) { v1 = pe[e]; i1 = e; }
    int i2 = -1; float v2 = -1.f;
#pragma unroll
    for (int e = 0; e < NEXP; e++) if (e != i1 && pe[e] > v2) { v2 = pe[e]; i2 = e; }
    v1 /= s; v2 /= s;
    float den = v1 + v2 + 1e-9f;
    top_idx[2 * n] = i1; top_idx[2 * n + 1] = i2;
    top_w[2 * n] = v1 / den; top_w[2 * n + 1] = v2 / den;
    atomicAdd(&counts[i1], 1);
    atomicAdd(&counts[i2], 1);
}

// ---------------------------------------------------------------- split-bf16 GEMM, pre-split inputs, gload staging
// C[M,N] = A[M,K] @ B[N,K]^T (+R).  A,B given as bf16 hi/lo pairs.
// BM=128, BN=64, BK=64; 4 waves 2x2 (wave tile 64x32); LDS 48 KB
__global__ __launch_bounds__(256) void gemm_bs(const u16* __restrict__ Ah_,
    const u16* __restrict__ Al_, const u16* __restrict__ Bh_, const u16* __restrict__ Bl_,
    float* __restrict__ C, const float* __restrict__ R, int M, int N, int K, int ldc)
{
    __shared__ __align__(16) u16 Ah[128 * 64], Al[128 * 64];
    __shared__ __align__(16) u16 Bh[64 * 64],  Bl[64 * 64];
    int tid = threadIdx.x;
    int m0 = blockIdx.y * 128, n0 = blockIdx.x * 64;
    int lane = tid & 63, wv = tid >> 6;
    int wm = wv >> 1, wn = wv & 1;
    int sr = lane >> 3, sc = lane & 7;

    f32x4 acc[4][2];
#pragma unroll
    for (int i = 0; i < 4; i++)
#pragma unroll
        for (int j = 0; j < 2; j++) acc[i][j] = f32x4{0.f, 0.f, 0.f, 0.f};

    for (int k0 = 0; k0 < K; k0 += 64) {
#pragma unroll
        for (int i = 0; i < 4; i++) {
            int row = wv * 32 + i * 8 + sr;
            int c = sc ^ (row & 7);
            size_t g = (size_t)(m0 + row) * K + k0 + c * 8;
            gload16(Ah_ + g, (void*)(Ah + (wv * 4 + i) * 512));
            gload16(Al_ + g, (void*)(Al + (wv * 4 + i) * 512));
        }
#pragma unroll
        for (int i = 0; i < 2; i++) {
            int row = wv * 16 + i * 8 + sr;
            int c = sc ^ (row & 7);
            size_t g = (size_t)(n0 + row) * K + k0 + c * 8;
            gload16(Bh_ + g, (void*)(Bh + (wv * 2 + i) * 512));
            gload16(Bl_ + g, (void*)(Bl + (wv * 2 + i) * 512));
        }
        __syncthreads();
#pragma unroll
        for (int ks = 0; ks < 2; ++ks) {
            s16x8 afh[4], afl[4], bfh[2], bfl[2];
#pragma unroll
            for (int mi = 0; mi < 4; mi++) {
                int row = wm * 64 + mi * 16 + (lane & 15);
                afh[mi] = ldfrag((const char*)Ah, row, ks, lane);
                afl[mi] = ldfrag((const char*)Al, row, ks, lane);
            }
#pragma unroll
            for (int nj = 0; nj < 2; nj++) {
                int row = wn * 32 + nj * 16 + (lane & 15);
                bfh[nj] = ldfrag((const char*)Bh, row, ks, lane);
                bfl[nj] = ldfrag((const char*)Bl, row, ks, lane);
            }
#pragma unroll
            for (int mi = 0; mi < 4; mi++)
#pragma unroll
                for (int nj = 0; nj < 2; nj++) {
                    acc[mi][nj] = mfma16(afl[mi], bfh[nj], acc[mi][nj]);
                    acc[mi][nj] = mfma16(afh[mi], bfl[nj], acc[mi][nj]);
                    acc[mi][nj] = mfma16(afh[mi], bfh[nj], acc[mi][nj]);
                }
        }
        __syncthreads();
    }
#pragma unroll
    for (int mi = 0; mi < 4; mi++)
#pragma unroll
        for (int nj = 0; nj < 2; nj++)
#pragma unroll
            for (int r = 0; r < 4; r++) {
                int m = m0 + wm * 64 + mi * 16 + (lane >> 4) * 4 + r;
                int n = n0 + wn * 32 + nj * 16 + (lane & 15);
                float v = acc[mi][nj][r];
                if (R) v += R[(size_t)m * ldc + n];
                C[(size_t)m * ldc + n] = v;
            }
}

// ---------------------------------------------------------------- RoPE (in place, strided)
__global__ __launch_bounds__(256) void rope_kernel(float* __restrict__ buf,
    const float* __restrict__ cs, const float* __restrict__ sn, int nheads,
    int row_stride, int base_col)
{
    int gid = blockIdx.x * 256 + threadIdx.x;
    int total = N_TOK * nheads * 32;
    if (gid >= total) return;
    int i = gid & 31;
    int h = (gid >> 5) % nheads;
    int n = gid / (32 * nheads);
    int t = n & (SEQ - 1);
    float* p = buf + (size_t)n * row_stride + base_col + h * HD + 2 * i;
    float xe = p[0], xo = p[1];
    float c = cs[t * 32 + i], s = sn[t * 32 + i];
    p[0] = xe * c - xo * s;
    p[1] = xe * s + xo * c;
}

// ---------------------------------------------------------------- V transpose: v[N_TOK][256] (strided) -> vbt[256][N_TOK]
__global__ __launch_bounds__(256) void transpose_v(const float* __restrict__ vsrc,
    float* __restrict__ vbt, int row_stride, int base_col)
{
    __shared__ float t[64][65];
    int bx = blockIdx.x;
    int by = blockIdx.y;
    int tid = threadIdx.x;
    int c4 = tid & 15, r0 = tid >> 4;
#pragma unroll
    for (int i = 0; i < 4; i++) {
        int row = r0 + i * 16;
        float4 vv = *(const float4*)(vsrc + (size_t)(bx * 64 + row) * row_stride + base_col + by * 64 + c4 * 4);
        t[c4 * 4 + 0][row] = vv.x;
        t[c4 * 4 + 1][row] = vv.y;
        t[c4 * 4 + 2][row] = vv.z;
        t[c4 * 4 + 3][row] = vv.w;
    }
    __syncthreads();
#pragma unroll
    for (int i = 0; i < 4; i++) {
        int drow = r0 + i * 16;
        float4 vv;
        vv.x = t[drow][c4 * 4 + 0];
        vv.y = t[drow][c4 * 4 + 1];
        vv.z = t[drow][c4 * 4 + 2];
        vv.w = t[drow][c4 * 4 + 3];
        *(float4*)(vbt + (size_t)(by * 64 + drow) * N_TOK + bx * 64 + c4 * 4) = vv;
    }
}

// ---------------------------------------------------------------- MFMA flash attention (split-bf16, fp32-grade)
// q at qkv[row][h*64], k at qkv[row][1024 + kvh*64]; output written as bf16 hi/lo
__global__ __launch_bounds__(256) void attn_mfma(const float* __restrict__ qkv,
    const float* __restrict__ vt, u16* __restrict__ outh, u16* __restrict__ outl)
{
    int b = blockIdx.z, h = blockIdx.y;
    int qt = (gridDim.x - 1) - blockIdx.x;
    int kvh = h >> 2;
    int tid = threadIdx.x;
    int lane = tid & 63, wv = tid >> 6;
    int q0 = qt * 64;
    int c4 = tid & 15, r0 = tid >> 4;

    __shared__ __align__(16) char Qh[64 * 128], Ql[64 * 128];
    __shared__ __align__(16) char Kh[64 * 128], Kl[64 * 128];
    __shared__ __align__(16) char Vh[64 * 128], Vl[64 * 128];
    __shared__ __align__(16) char Ph[4][16 * 128], Pl[4][16 * 128];

#pragma unroll
    for (int i = 0; i < 4; i++) {
        int row = r0 + i * 16;
        float4 vq = *(const float4*)(qkv + (size_t)(b * SEQ + q0 + row) * QKVW + h * HD + c4 * 4);
        ushort4 hh, ll;
        hh.x = f2bf(vq.x); hh.y = f2bf(vq.y); hh.z = f2bf(vq.z); hh.w = f2bf(vq.w);
        ll.x = f2bf(vq.x - bf2f(hh.x)); ll.y = f2bf(vq.y - bf2f(hh.y));
        ll.z = f2bf(vq.z - bf2f(hh.z)); ll.w = f2bf(vq.w - bf2f(hh.w));
        int byte = lds_byte(row, c4 * 8, row);
        *(ushort4*)(Qh + byte) = hh;
        *(ushort4*)(Ql + byte) = ll;
    }
    __syncthreads();

    s16x8 aQh[2], aQl[2];
#pragma unroll
    for (int ks = 0; ks < 2; ks++) {
        aQh[ks] = ldfrag(Qh, wv * 16 + (lane & 15), ks, lane);
        aQl[ks] = ldfrag(Ql, wv * 16 + (lane & 15), ks, lane);
    }

    float m_run[4], l_run[4];
    f32x4 acc_o[4];
#pragma unroll
    for (int r = 0; r < 4; r++) { m_run[r] = -1e30f; l_run[r] = 0.f; }
#pragma unroll
    for (int nj = 0; nj < 4; nj++) acc_o[nj] = f32x4{0.f, 0.f, 0.f, 0.f};

    for (int kt = 0; kt <= qt; kt++) {
        int kbase = kt * 64;
        __syncthreads();
#pragma unroll
        for (int i = 0; i < 4; i++) {
            int row = r0 + i * 16;
            float4 vk = *(const float4*)(qkv + (size_t)(b * SEQ + kbase + row) * QKVW + 1024 + kvh * HD + c4 * 4);
            float4 vv = *(const float4*)(vt + (size_t)(kvh * HD + row) * N_TOK + b * SEQ + kbase + c4 * 4);
            ushort4 kh, kl, vh, vl;
            kh.x = f2bf(vk.x); kh.y = f2bf(vk.y); kh.z = f2bf(vk.z); kh.w = f2bf(vk.w);
            kl.x = f2bf(vk.x - bf2f(kh.x)); kl.y = f2bf(vk.y - bf2f(kh.y));
            kl.z = f2bf(vk.z - bf2f(kh.z)); kl.w = f2bf(vk.w - bf2f(kh.w));
            vh.x = f2bf(vv.x); vh.y = f2bf(vv.y); vh.z = f2bf(vv.z); vh.w = f2bf(vv.w);
            vl.x = f2bf(vv.x - bf2f(vh.x)); vl.y = f2bf(vv.y - bf2f(vh.y));
            vl.z = f2bf(vv.z - bf2f(vh.z)); vl.w = f2bf(vv.w - bf2f(vh.w));
            int byte = lds_byte(row, c4 * 8, row);
            *(ushort4*)(Kh + byte) = kh;
            *(ushort4*)(Kl + byte) = kl;
            *(ushort4*)(Vh + byte) = vh;
            *(ushort4*)(Vl + byte) = vl;
        }
        __syncthreads();

        f32x4 sacc[4];
#pragma unroll
        for (int nj = 0; nj < 4; nj++) sacc[nj] = f32x4{0.f, 0.f, 0.f, 0.f};
#pragma unroll
        for (int ks = 0; ks < 2; ks++) {
#pragma unroll
            for (int nj = 0; nj < 4; nj++) {
                s16x8 bKh = ldfrag(Kh, nj * 16 + (lane & 15), ks, lane);
                s16x8 bKl = ldfrag(Kl, nj * 16 + (lane & 15), ks, lane);
                sacc[nj] = mfma16(aQl[ks], bKh, sacc[nj]);
                sacc[nj] = mfma16(aQh[ks], bKl, sacc[nj]);
                sacc[nj] = mfma16(aQh[ks], bKh, sacc[nj]);
            }
        }

        float sv[4][4];
#pragma unroll
        for (int nj = 0; nj < 4; nj++)
#pragma unroll
            for (int r = 0; r < 4; r++) {
                float s = sacc[nj][r] * 0.125f;
                if (kt == qt) {
                    int row_loc = wv * 16 + (lane >> 4) * 4 + r;
                    int col_loc = nj * 16 + (lane & 15);
                    if (col_loc > row_loc) s = -1e30f;
                }
                sv[nj][r] = s;
            }

        float p[4][4];
#pragma unroll
        for (int r = 0; r < 4; r++) {
            float mx = fmaxf(fmaxf(sv[0][r], sv[1][r]), fmaxf(sv[2][r], sv[3][r]));
            mx = fmaxf(mx, __shfl_xor(mx, 1));
            mx = fmaxf(mx, __shfl_xor(mx, 2));
            mx = fmaxf(mx, __shfl_xor(mx, 4));
            mx = fmaxf(mx, __shfl_xor(mx, 8));
            float m_new = fmaxf(m_run[r], mx);
            float corr = __expf(m_run[r] - m_new);
            float ps = 0.f;
#pragma unroll
            for (int nj = 0; nj < 4; nj++) {
                float pv = __expf(sv[nj][r] - m_new);
                p[nj][r] = pv;
                ps += pv;
            }
            ps += __shfl_xor(ps, 1);
            ps += __shfl_xor(ps, 2);
            ps += __shfl_xor(ps, 4);
            ps += __shfl_xor(ps, 8);
            l_run[r] = l_run[r] * corr + ps;
            m_run[r] = m_new;
#pragma unroll
            for (int nj = 0; nj < 4; nj++) acc_o[nj][r] *= corr;
        }

        char* phb = Ph[wv];
        char* plb = Pl[wv];
#pragma unroll
        for (int nj = 0; nj < 4; nj++)
#pragma unroll
            for (int r = 0; r < 4; r++) {
                int row = (lane >> 4) * 4 + r;
                int col = nj * 16 + (lane & 15);
                u16 hh = f2bf(p[nj][r]);
                u16 ll = f2bf(p[nj][r] - bf2f(hh));
                int byte = lds_byte(row, col * 2, row);
                *(u16*)(phb + byte) = hh;
                *(u16*)(plb + byte) = ll;
            }

#pragma unroll
        for (int ks = 0; ks < 2; ks++) {
            s16x8 aPh = ldfrag(phb, lane & 15, ks, lane);
            s16x8 aPl = ldfrag(plb, lane & 15, ks, lane);
#pragma unroll
            for (int nj = 0; nj < 4; nj++) {
                s16x8 bVh = ldfrag(Vh, nj * 16 + (lane & 15), ks, lane);
                s16x8 bVl = ldfrag(Vl, nj * 16 + (lane & 15), ks, lane);
                acc_o[nj] = mfma16(aPl, bVh, acc_o[nj]);
                acc_o[nj] = mfma16(aPh, bVl, acc_o[nj]);
                acc_o[nj] = mfma16(aPh, bVh, acc_o[nj]);
            }
        }
    }

#pragma unroll
    for (int r = 0; r < 4; r++) {
        int row_glob = q0 + wv * 16 + (lane >> 4) * 4 + r;
        float inv = 1.f / l_run[r];
#pragma unroll
        for (int nj = 0; nj < 4; nj++) {
            int dv = nj * 16 + (lane & 15);
            size_t idx = (size_t)(b * SEQ + row_glob) * (NH * HD) + h * HD + dv;
            float v = acc_o[nj][r] * inv;
            u16 hh = f2bf(v);
            outh[idx] = hh;
            outl[idx] = f2bf(v - bf2f(hh));
        }
    }
}

// ---------------------------------------------------------------- routing helpers
__global__ void init_counts(int* counts, int* pos)
{
    int t = threadIdx.x;
    if (t < NEXP) { counts[t] = 0; pos[t] = 0; }
}

__global__ void offsets_kernel(const int* counts, int* offs)
{
    if (threadIdx.x == 0) {
        int s = 0;
        for (int e = 0; e < NEXP; e++) { offs[e] = s; s += counts[e]; }
    }
}

__global__ __launch_bounds__(256) void fill_kernel(const int* __restrict__ top_idx,
    const float* __restrict__ top_w, const int* __restrict__ offs, int* __restrict__ pos,
    int* __restrict__ assign_token, float* __restrict__ assign_w)
{
    int n = blockIdx.x * 256 + threadIdx.x;
    if (n >= N_TOK) return;
#pragma unroll
    for (int s = 0; s < 2; s++) {
        int e = top_idx[2 * n + s];
        int p = atomicAdd(&pos[e], 1);
        int r = offs[e] + p;
        assign_token[r] = n;
        assign_w[r] = top_w[2 * n + s];
    }
}

// ---------------------------------------------------------------- MoE gate/up v2: bf16 inputs, global_load_lds staging
__global__ __launch_bounds__(256) void moe_gateup2(const u16* __restrict__ xb,
    const u16* __restrict__ wgb, const u16* __restrict__ wub,
    const int* __restrict__ assign_token, const int* __restrict__ offs,
    const int* __restrict__ counts, u16* __restrict__ hbufb)
{
    int e = blockIdx.z;
    int cnt = counts[e];
    int t0 = blockIdx.y * 128;
    if (t0 >= cnt) return;
    int base = offs[e];
    int h0 = blockIdx.x * 64;
    __shared__ __align__(16) u16 As[128 * 64];
    __shared__ __align__(16) u16 Gs[64 * 64];
    __shared__ __align__(16) u16 Us[64 * 64];
    __shared__ int toks[128];
    int tid = threadIdx.x;
    if (tid < 128) {
        int a = t0 + tid;
        toks[tid] = (a < cnt) ? assign_token[base + a] : 0;
    }
    __syncthreads();
    int lane = tid & 63, wv = tid >> 6;
    int wm = wv >> 1, wn = wv & 1;
    int sr = lane >> 3, sc = lane & 7;

    int tokr[4];
#pragma unroll
    for (int i = 0; i < 4; i++) tokr[i] = toks[wv * 32 + i * 8 + sr];

    const u16* wge = wgb + (size_t)e * HID * DIMM;
    const u16* wue = wub + (size_t)e * HID * DIMM;

    f32x4 accg[4][2], accu[4][2];
#pragma unroll
    for (int i = 0; i < 4; i++)
#pragma unroll
        for (int j = 0; j < 2; j++) { accg[i][j] = f32x4{0,0,0,0}; accu[i][j] = f32x4{0,0,0,0}; }

    for (int k0 = 0; k0 < DIMM; k0 += 64) {
#pragma unroll
        for (int i = 0; i < 4; i++) {
            int row = wv * 32 + i * 8 + sr;
            int c = sc ^ (row & 7);
            gload16(xb + (size_t)tokr[i] * DIMM + k0 + c * 8, (void*)(As + (wv * 4 + i) * 512));
        }
#pragma unroll
        for (int i = 0; i < 2; i++) {
            int row = wv * 16 + i * 8 + sr;
            int c = sc ^ (row & 7);
            gload16(wge + (size_t)(h0 + row) * DIMM + k0 + c * 8, (void*)(Gs + (wv * 2 + i) * 512));
            gload16(wue + (size_t)(h0 + row) * DIMM + k0 + c * 8, (void*)(Us + (wv * 2 + i) * 512));
        }
        __syncthreads();
#pragma unroll
        for (int ks = 0; ks < 2; ++ks) {
            s16x8 af[4], gf[2], uf[2];
#pragma unroll
            for (int mi = 0; mi < 4; mi++)
                af[mi] = ldfrag((const char*)As, wm * 64 + mi * 16 + (lane & 15), ks, lane);
#pragma unroll
            for (int nj = 0; nj < 2; nj++) {
                int row = wn * 32 + nj * 16 + (lane & 15);
                gf[nj] = ldfrag((const char*)Gs, row, ks, lane);
                uf[nj] = ldfrag((const char*)Us, row, ks, lane);
            }
#pragma unroll
            for (int mi = 0; mi < 4; mi++)
#pragma unroll
                for (int nj = 0; nj < 2; nj++) {
                    accg[mi][nj] = mfma16(af[mi], gf[nj], accg[mi][nj]);
                    accu[mi][nj] = mfma16(af[mi], uf[nj], accu[mi][nj]);
                }
        }
        __syncthreads();
    }
#pragma unroll
    for (int mi = 0; mi < 4; mi++)
#pragma unroll
        for (int nj = 0; nj < 2; nj++)
#pragma unroll
            for (int r = 0; r < 4; r++) {
                int row = wm * 64 + mi * 16 + (lane >> 4) * 4 + r;
                if (t0 + row < cnt) {
                    int col = wn * 32 + nj * 16 + (lane & 15);
                    float g = accg[mi][nj][r], u = accu[mi][nj][r];
                    float hh = (g / (1.f + __expf(-g))) * u;
                    hbufb[(size_t)(base + t0 + row) * HID + h0 + col] = f2bf(hh);
                }
            }
}

// ---------------------------------------------------------------- MoE down v2
__global__ __launch_bounds__(256) void moe_down2(const u16* __restrict__ hbufb,
    const u16* __restrict__ wdb, const int* __restrict__ assign_token,
    const float* __restrict__ assign_w, const int* __restrict__ offs,
    const int* __restrict__ counts, float* __restrict__ out)
{
    int e = blockIdx.z;
    int cnt = counts[e];
    int t0 = blockIdx.y * 128;
    if (t0 >= cnt) return;
    int base = offs[e];
    int d0 = blockIdx.x * 128;
    __shared__ __align__(16) u16 As[128 * 64];
    __shared__ __align__(16) u16 Bs[128 * 64];
    __shared__ int toks[128];
    __shared__ float rw_[128];
    int tid = threadIdx.x;
    if (tid < 128) {
        int a = t0 + tid;
        toks[tid] = (a < cnt) ? assign_token[base + a] : 0;
        rw_[tid] = (a < cnt) ? assign_w[base + a] : 0.f;
    }
    __syncthreads();
    int lane = tid & 63, wv = tid >> 6;
    int wm = wv >> 1, wn = wv & 1;
    int sr = lane >> 3, sc = lane & 7;

    const u16* wde = wdb + (size_t)e * DIMM * HID;

    f32x4 acc[4][4];
#pragma unroll
    for (int i = 0; i < 4; i++)
#pragma unroll
        for (int j = 0; j < 4; j++) acc[i][j] = f32x4{0,0,0,0};

    for (int k0 = 0; k0 < HID; k0 += 64) {
#pragma unroll
        for (int i = 0; i < 4; i++) {
            int row = wv * 32 + i * 8 + sr;
            int c = sc ^ (row & 7);
            gload16(hbufb + (size_t)(base + t0 + row) * HID + k0 + c * 8, (void*)(As + (wv * 4 + i) * 512));
            gload16(wde + (size_t)(d0 + row) * HID + k0 + c * 8, (void*)(Bs + (wv * 4 + i) * 512));
        }
        __syncthreads();
#pragma unroll
        for (int ks = 0; ks < 2; ++ks) {
            s16x8 af[4], bf[4];
#pragma unroll
            for (int mi = 0; mi < 4; mi++)
                af[mi] = ldfrag((const char*)As, wm * 64 + mi * 16 + (lane & 15), ks, lane);
#pragma unroll
            for (int nj = 0; nj < 4; nj++)
                bf[nj] = ldfrag((const char*)Bs, wn * 64 + nj * 16 + (lane & 15), ks, lane);
#pragma unroll
            for (int mi = 0; mi < 4; mi++)
#pragma unroll
                for (int nj = 0; nj < 4; nj++)
                    acc[mi][nj] = mfma16(af[mi], bf[nj], acc[mi][nj]);
        }
        __syncthreads();
    }
#pragma unroll
    for (int mi = 0; mi < 4; mi++)
#pragma unroll
        for (int r = 0; r < 4; r++) {
            int row = wm * 64 + mi * 16 + (lane >> 4) * 4 + r;
            if (t0 + row < cnt) {
                int tok = toks[row];
                float w = rw_[row];
#pragma unroll
                for (int nj = 0; nj < 4; nj++) {
                    int col = d0 + wn * 64 + nj * 16 + (lane & 15);
                    atomicAdd(&out[(size_t)tok * DIMM + col], acc[mi][nj][r] * w);
                }
            }
        }
}

// ---------------------------------------------------------------- launch
extern "C" void kernel_launch(void* const* d_in, const int* in_sizes, int n_in,
                              void* d_out, int out_size, void* d_ws, size_t ws_size,
                              hipStream_t stream)
{
    const float* x      = (const float*)d_in[0];
    const float* cs     = (const float*)d_in[1];
    const float* sn     = (const float*)d_in[2];
    const float* w_na   = (const float*)d_in[3];
    const float* wq     = (const float*)d_in[4];
    const float* wk     = (const float*)d_in[5];
    const float* wv     = (const float*)d_in[6];
    const float* wo     = (const float*)d_in[7];
    const float* w_nf   = (const float*)d_in[8];
    const float* rw     = (const float*)d_in[9];
    const float* rb     = (const float*)d_in[10];
    const float* wg     = (const float*)d_in[11];
    const float* wu     = (const float*)d_in[12];
    const float* wd     = (const float*)d_in[13];
    float* out = (float*)d_out;

    const size_t F = 1024 * 1024;
    float* wsf = (float*)d_ws;

    // layout (float units):
    float* qkvb = wsf;                         // 0..3F      [2048][1536] fp32
    float* vbt  = wsf + 3 * F;                 // 3..3.5F    [256][2048] fp32
    float* tail = wsf + 5 * F + F / 2;         // 5.5..6F    routing scratch
    u16* xn2b   = (u16*)(wsf + 6 * F);         // 6..7F      2M u16
    u16* hbufb  = (u16*)(wsf + 7 * F);         // 7..11F     8M u16 (MoE h)
    u16* xnh    = (u16*)(wsf + 7 * F);         //   alias 7..8F   (dead before moe)
    u16* xnl    = (u16*)(wsf + 8 * F);         //   alias 8..9F
    u16* attnh  = (u16*)(wsf + 9 * F);         //   alias 9..10F
    u16* attnl  = (u16*)(wsf + 10 * F);        //   alias 10..11F
    u16* wgb    = (u16*)(wsf + 11 * F);        // 11..19F    16M u16
    u16* wub    = (u16*)(wsf + 19 * F);        // 19..27F
    u16* wdb    = (u16*)(wsf + 27 * F);        // 27..35F
    u16* wqkvoh = (u16*)(wsf + 35 * F);        // 35..36.25F 2.5M u16
    u16* wqkvol = (u16*)(wsf + 36 * F + F / 4);// 36.25..37.5F

    int*   top_idx      = (int*)tail;                     // 4096
    float* top_w        = tail + 4096;                    // 4096
    int*   counts       = (int*)(tail + 8192);            // 8
    int*   offs         = (int*)(tail + 8192) + 8;        // 8
    int*   pos          = (int*)(tail + 8192) + 16;       // 8
    int*   assign_token = (int*)(tail + 8192) + 32;       // 4096
    float* assign_w     = tail + 8192 + 32 + 4096;        // 4096
    float* logits       = tail + 8192 + 32 + 8192;        // 16384

    // 0. weight conversions (merged launches)
    cvt_split4<<<1024, 256, 0, stream>>>(wq, wk, wv, wo, wqkvoh, wqkvol);
    cvt3<<<2048, 256, 0, stream>>>(wg, wu, wd, wgb, wub, wdb);
    // 1. rmsnorm (attn) -> bf16 hi/lo
    rmsnorm_split<<<N_TOK, 256, 0, stream>>>(x, w_na, xnh, xnl);
    // 2. fused qkv projection (384 blocks)
    gemm_bs<<<dim3(QKVW / 64, 16), 256, 0, stream>>>(xnh, xnl, wqkvoh, wqkvol,
                                                     qkvb, nullptr, N_TOK, QKVW, DIMM, QKVW);
    // 3. RoPE (q, k) + V transpose
    rope_kernel<<<(N_TOK * NH * 32) / 256, 256, 0, stream>>>(qkvb, cs, sn, NH, QKVW, 0);
    rope_kernel<<<(N_TOK * NKV * 32) / 256, 256, 0, stream>>>(qkvb, cs, sn, NKV, QKVW, 1024);
    transpose_v<<<dim3(N_TOK / 64, (NKV * HD) / 64), 256, 0, stream>>>(qkvb, vbt, QKVW, 1280);
    // 4. attention (MFMA flash) -> bf16 hi/lo output
    attn_mfma<<<dim3(SEQ / 64, NH, 2), 256, 0, stream>>>(qkvb, vbt, attnh, attnl);
    // 5. output projection + residual (256 blocks)
    gemm_bs<<<dim3(DIMM / 64, 16), 256, 0, stream>>>(attnh, attnl,
                                                     wqkvoh + (size_t)1536 * 1024, wqkvol + (size_t)1536 * 1024,
                                                     out, x, N_TOK, DIMM, NH * HD, DIMM);
    // 6. rmsnorm (ffn) fused with router logits -> bf16 MoE operand + logits
    rmsnorm_router<<<N_TOK, 256, 0, stream>>>(out, w_nf, rw, rb, xn2b, logits);
    // 7-10. routing
    init_counts<<<1, 64, 0, stream>>>(counts, pos);
    top2_kernel<<<N_TOK / 256, 256, 0, stream>>>(logits, top_idx, top_w, counts);
    offsets_kernel<<<1, 64, 0, stream>>>(counts, offs);
    fill_kernel<<<N_TOK / 256, 256, 0, stream>>>(top_idx, top_w, offs, pos, assign_token, assign_w);
    // 11-12. MoE (bf16 + global_load_lds)
    moe_gateup2<<<dim3(HID / 64, 16, NEXP), 256, 0, stream>>>(xn2b, wgb, wub, assign_token, offs, counts, hbufb);
    moe_down2<<<dim3(DIMM / 128, 16, NEXP), 256, 0, stream>>>(hbufb, wdb, assign_token, assign_w, offs, counts, out);
}